// Round 1
// baseline (6740.878 us; speedup 1.0000x reference)
//
#include <hip/hip_runtime.h>
#include <hip/hip_fp16.h>

// AGCRN: B=32 T=12 N=1024 C=2 D=16 H=64 K=2 OUT=12
// Layout convention for activations: (n, b, f) node-major so A@X is a dense GEMM.
// Layer0: C=2, F=66 (pad to LD=68 so B*LD=2176 is a multiple of 64), KI=132
// Layer1: C=64, F=128=LD, KI=256

// ---------------- A = softmax(relu(E E^T)), row-wise ----------------
__global__ __launch_bounds__(256) void compute_A_kernel(const float* __restrict__ E,
                                                        float* __restrict__ A) {
  int n = blockIdx.x;
  int tid = threadIdx.x;
  __shared__ float red[256];
  float en[16];
#pragma unroll
  for (int d = 0; d < 16; ++d) en[d] = E[n * 16 + d];
  float v[4];
#pragma unroll
  for (int q = 0; q < 4; ++q) {
    int m = tid + q * 256;
    const float* Em = E + m * 16;
    float dot = 0.f;
#pragma unroll
    for (int d = 0; d < 16; ++d) dot += en[d] * Em[d];
    v[q] = fmaxf(dot, 0.f);
  }
  float mx = fmaxf(fmaxf(v[0], v[1]), fmaxf(v[2], v[3]));
  red[tid] = mx; __syncthreads();
  for (int s = 128; s > 0; s >>= 1) { if (tid < s) red[tid] = fmaxf(red[tid], red[tid + s]); __syncthreads(); }
  mx = red[0];
  __syncthreads();
  float e[4], sum = 0.f;
#pragma unroll
  for (int q = 0; q < 4; ++q) { e[q] = expf(v[q] - mx); sum += e[q]; }
  red[tid] = sum; __syncthreads();
  for (int s = 128; s > 0; s >>= 1) { if (tid < s) red[tid] += red[tid + s]; __syncthreads(); }
  float inv = 1.f / red[0];
#pragma unroll
  for (int q = 0; q < 4; ++q) A[(size_t)n * 1024 + tid + q * 256] = e[q] * inv;
}

// ---------------- W[n, j] = sum_d E[n,d] * pool[d, j], fp16 out ----------------
__global__ void make_w_kernel(const float* __restrict__ E, const float* __restrict__ pool,
                              __half* __restrict__ W, int J) {
  int J4 = J >> 2;
  size_t tid = (size_t)blockIdx.x * 256 + threadIdx.x;
  size_t total = (size_t)1024 * J4;
  if (tid >= total) return;
  int n = (int)(tid / J4);
  int j = (int)(tid % J4) * 4;
  const float* En = E + n * 16;
  float a0 = 0.f, a1 = 0.f, a2 = 0.f, a3 = 0.f;
#pragma unroll
  for (int d = 0; d < 16; ++d) {
    float e = En[d];
    const float4 p = *(const float4*)(pool + (size_t)d * J + j);
    a0 += e * p.x; a1 += e * p.y; a2 += e * p.z; a3 += e * p.w;
  }
  __half2* o = (__half2*)(W + (size_t)n * J + j);
  o[0] = __floats2half2_rn(a0, a1);
  o[1] = __floats2half2_rn(a2, a3);
}

// ---------------- per-node bias: Bout[n,o] = sum_d E[n,d] pool[d,o] ----------------
__global__ void make_b_kernel(const float* __restrict__ E, const float* __restrict__ pool,
                              float* __restrict__ Bout, int O) {
  int tid = blockIdx.x * 256 + threadIdx.x;
  if (tid >= 1024 * O) return;
  int n = tid / O, o = tid % O;
  const float* En = E + n * 16;
  float a = 0.f;
#pragma unroll
  for (int d = 0; d < 16; ++d) a += En[d] * pool[d * O + o];
  Bout[tid] = a;
}

__global__ void zero_kernel(float* __restrict__ p, int count) {
  int i = blockIdx.x * 256 + threadIdx.x;
  if (i < count) p[i] = 0.f;
}

// ---------------- build layer inputs ----------------
__global__ void build_inp0_kernel(const float* __restrict__ src, const float* __restrict__ h1,
                                  float* __restrict__ inp, int t) {
  int idx = blockIdx.x * 256 + threadIdx.x;
  if (idx >= 1024 * 32 * 68) return;
  int f = idx % 68; int nb = idx / 68; int b = nb & 31; int n = nb >> 5;
  float v;
  if (f < 2)       v = src[((size_t)(b * 12 + t) * 1024 + n) * 2 + f];
  else if (f < 66) v = h1[(size_t)nb * 64 + f - 2];
  else             v = 0.f;  // pad cols 66,67 so Nc=2176 is GEMM-tile friendly
  inp[idx] = v;
}

__global__ void build_inp1_kernel(const float* __restrict__ h1, const float* __restrict__ h2,
                                  float* __restrict__ inp) {
  int idx = blockIdx.x * 256 + threadIdx.x;
  if (idx >= 1024 * 32 * 128) return;
  int f = idx & 127; int nb = idx >> 7;
  inp[idx] = (f < 64) ? h1[(size_t)nb * 64 + f] : h2[(size_t)nb * 64 + f - 64];
}

// ---------------- Y[1024 x Nc] = A[1024x1024] @ X[1024 x Nc], fp32 ----------------
// tile 128(rows) x 64(cols), Ktile 16, 256 threads, 8x4 per thread
__global__ __launch_bounds__(256) void gemm_kernel(const float* __restrict__ A,
                                                   const float* __restrict__ X,
                                                   float* __restrict__ Y, int Nc) {
  __shared__ float As[16][132];
  __shared__ float Xs[16][68];
  int tid = threadIdx.x;
  int row0 = blockIdx.y * 128, col0 = blockIdx.x * 64;
  int tx = tid & 15, ty = tid >> 4;
  float acc[8][4] = {};
  for (int k0 = 0; k0 < 1024; k0 += 16) {
    {
      int r = tid >> 2, c = (tid & 3) * 4;
#pragma unroll
      for (int half = 0; half < 2; ++half) {
        int rr = r + half * 64;
        const float4 av = *(const float4*)(A + (size_t)(row0 + rr) * 1024 + k0 + c);
        As[c + 0][rr] = av.x; As[c + 1][rr] = av.y; As[c + 2][rr] = av.z; As[c + 3][rr] = av.w;
      }
      int kr = tid >> 4, cc = (tid & 15) * 4;
      *(float4*)&Xs[kr][cc] = *(const float4*)(X + (size_t)(k0 + kr) * Nc + col0 + cc);
    }
    __syncthreads();
#pragma unroll
    for (int kk = 0; kk < 16; ++kk) {
      float a[8], b[4];
#pragma unroll
      for (int j = 0; j < 8; ++j) a[j] = As[kk][ty * 8 + j];
#pragma unroll
      for (int i = 0; i < 4; ++i) b[i] = Xs[kk][tx * 4 + i];
#pragma unroll
      for (int j = 0; j < 8; ++j)
#pragma unroll
        for (int i = 0; i < 4; ++i) acc[j][i] += a[j] * b[i];
    }
    __syncthreads();
  }
#pragma unroll
  for (int j = 0; j < 8; ++j) {
    int row = row0 + ty * 8 + j;
    *(float4*)(Y + (size_t)row * Nc + col0 + tx * 4) =
        make_float4(acc[j][0], acc[j][1], acc[j][2], acc[j][3]);
  }
}

// ---------------- gate: zr = sigmoid(Xn @ Wg[n] + Bg[n]); zh = z*h; store r ----------------
// Xn[b, k*F+f] = k==0 ? inp[n,b,f] : Ainp[n,b,f].  O = 128.
template <int KI, int F, int LD>
__global__ __launch_bounds__(256) void gate_kernel(
    const float* __restrict__ inp, const float* __restrict__ Ainp,
    const __half* __restrict__ W, const float* __restrict__ Bg,
    const float* __restrict__ h, float* __restrict__ zh, float* __restrict__ rbuf) {
  int n = blockIdx.x;
  __shared__ float Xs[32 * KI];
  const float* inp_n = inp + (size_t)n * 32 * LD;
  const float* Ainp_n = Ainp + (size_t)n * 32 * LD;
  for (int i = threadIdx.x; i < 32 * F; i += 256) {
    int b = i / F, f = i - b * F;
    Xs[b * KI + f]     = inp_n[b * LD + f];
    Xs[b * KI + F + f] = Ainp_n[b * LD + f];
  }
  __syncthreads();
  int o0 = (threadIdx.x & 31) * 4;
  int b0 = (threadIdx.x >> 5) * 4;
  float acc[4][4] = {};
  const __half* Wn = W + (size_t)n * KI * 128 + o0;
#pragma unroll 4
  for (int ki = 0; ki < KI; ++ki) {
    const __half2* wp = (const __half2*)(Wn + (size_t)ki * 128);
    float2 w01 = __half22float2(wp[0]);
    float2 w23 = __half22float2(wp[1]);
#pragma unroll
    for (int j = 0; j < 4; ++j) {
      float x = Xs[(b0 + j) * KI + ki];
      acc[j][0] += x * w01.x; acc[j][1] += x * w01.y;
      acc[j][2] += x * w23.x; acc[j][3] += x * w23.y;
    }
  }
  const float* Bn = Bg + n * 128;
#pragma unroll
  for (int j = 0; j < 4; ++j) {
    int b = b0 + j;
    size_t base = ((size_t)n * 32 + b) * 64;
#pragma unroll
    for (int i = 0; i < 4; ++i) {
      int o = o0 + i;
      float s = 1.f / (1.f + __expf(-(acc[j][i] + Bn[o])));
      if (o < 64) zh[base + o] = s * h[base + o];   // z * state
      else        rbuf[base + o - 64] = s;          // r
    }
  }
}

// ---------------- upd: hc = tanh(Xc @ Wu[n] + Bu[n]); h = r*h + (1-r)*hc ----------------
// Xc[b, k*F+f] = f<C ? (inp|Ainp)[n,b,f] : (zh|Azh)[n,b,f-C].  O = 64.
template <int KI, int F, int LD, int C>
__global__ __launch_bounds__(128) void upd_kernel(
    const float* __restrict__ inp, const float* __restrict__ Ainp,
    const float* __restrict__ zh, const float* __restrict__ Azh,
    const __half* __restrict__ W, const float* __restrict__ Bu,
    const float* __restrict__ rbuf, float* __restrict__ h) {
  int n = blockIdx.x;
  __shared__ float Xs[32 * KI];
  const float* inp_n = inp + (size_t)n * 32 * LD;
  const float* Ainp_n = Ainp + (size_t)n * 32 * LD;
  const float* zh_n = zh + (size_t)n * 32 * 64;
  const float* Azh_n = Azh + (size_t)n * 32 * 64;
  for (int i = threadIdx.x; i < 32 * F; i += 128) {
    int b = i / F, f = i - b * F;
    float v0, v1;
    if (f < C) { v0 = inp_n[b * LD + f];      v1 = Ainp_n[b * LD + f]; }
    else       { v0 = zh_n[b * 64 + f - C];   v1 = Azh_n[b * 64 + f - C]; }
    Xs[b * KI + f]     = v0;
    Xs[b * KI + F + f] = v1;
  }
  __syncthreads();
  int o0 = (threadIdx.x & 15) * 4;
  int b0 = (threadIdx.x >> 4) * 4;
  float acc[4][4] = {};
  const __half* Wn = W + (size_t)n * KI * 64 + o0;
#pragma unroll 4
  for (int ki = 0; ki < KI; ++ki) {
    const __half2* wp = (const __half2*)(Wn + (size_t)ki * 64);
    float2 w01 = __half22float2(wp[0]);
    float2 w23 = __half22float2(wp[1]);
#pragma unroll
    for (int j = 0; j < 4; ++j) {
      float x = Xs[(b0 + j) * KI + ki];
      acc[j][0] += x * w01.x; acc[j][1] += x * w01.y;
      acc[j][2] += x * w23.x; acc[j][3] += x * w23.y;
    }
  }
  const float* Bn = Bu + n * 64;
#pragma unroll
  for (int j = 0; j < 4; ++j) {
    int b = b0 + j;
    size_t base = ((size_t)n * 32 + b) * 64;
#pragma unroll
    for (int i = 0; i < 4; ++i) {
      int o = o0 + i;
      float x = acc[j][i] + Bn[o];
      x = fminf(fmaxf(x, -30.f), 30.f);
      float e = __expf(2.f * x);
      float hc = (e - 1.f) / (e + 1.f);   // tanh
      float rr = rbuf[base + o];
      float hold = h[base + o];
      h[base + o] = rr * hold + (1.f - rr) * hc;
    }
  }
}

// ---------------- out[b,o,n] = h2[n,b,:] . conv_w[o,:] + conv_b[o] ----------------
__global__ void final_conv_kernel(const float* __restrict__ h2, const float* __restrict__ cw,
                                  const float* __restrict__ cb, float* __restrict__ out) {
  int tid = blockIdx.x * 256 + threadIdx.x;
  if (tid >= 32 * 1024) return;
  int n = tid & 1023, b = tid >> 10;
  const float* hp = h2 + ((size_t)n * 32 + b) * 64;
  float hv[64];
#pragma unroll
  for (int i = 0; i < 64; ++i) hv[i] = hp[i];
#pragma unroll
  for (int o = 0; o < 12; ++o) {
    float acc = cb[o];
#pragma unroll
    for (int i = 0; i < 64; ++i) acc += hv[i] * cw[o * 64 + i];
    out[((size_t)b * 12 + o) * 1024 + n] = acc;
  }
}

extern "C" void kernel_launch(void* const* d_in, const int* in_sizes, int n_in,
                              void* d_out, int out_size, void* d_ws, size_t ws_size,
                              hipStream_t stream) {
  const float* src = (const float*)d_in[0];
  const float* E   = (const float*)d_in[1];
  const float* gw0 = (const float*)d_in[2];
  const float* gb0 = (const float*)d_in[3];
  const float* uw0 = (const float*)d_in[4];
  const float* ub0 = (const float*)d_in[5];
  const float* gw1 = (const float*)d_in[6];
  const float* gb1 = (const float*)d_in[7];
  const float* uw1 = (const float*)d_in[8];
  const float* ub1 = (const float*)d_in[9];
  const float* cw  = (const float*)d_in[10];
  const float* cb  = (const float*)d_in[11];
  float* out = (float*)d_out;
  (void)in_sizes; (void)n_in; (void)out_size; (void)ws_size;

  char* base = (char*)d_ws;
  size_t off = 0;
  auto alloc = [&](size_t bytes) -> void* {
    void* p = base + off; off += (bytes + 511) & ~(size_t)511; return p;
  };
  float*  A    = (float*) alloc((size_t)1024 * 1024 * 4);          //  4.2 MB
  __half* Wg0  = (__half*)alloc((size_t)1024 * 132 * 128 * 2);     // 34.6 MB
  __half* Wu0  = (__half*)alloc((size_t)1024 * 132 * 64 * 2);      // 17.3 MB
  __half* Wg1  = (__half*)alloc((size_t)1024 * 256 * 128 * 2);     // 67.1 MB
  __half* Wu1  = (__half*)alloc((size_t)1024 * 256 * 64 * 2);      // 33.6 MB
  float*  Bg0  = (float*) alloc((size_t)1024 * 128 * 4);
  float*  Bu0  = (float*) alloc((size_t)1024 * 64 * 4);
  float*  Bg1  = (float*) alloc((size_t)1024 * 128 * 4);
  float*  Bu1  = (float*) alloc((size_t)1024 * 64 * 4);
  float*  inp  = (float*) alloc((size_t)1024 * 32 * 128 * 4);      // 16.8 MB
  float*  Ainp = (float*) alloc((size_t)1024 * 32 * 128 * 4);      // 16.8 MB
  float*  zh   = (float*) alloc((size_t)1024 * 32 * 64 * 4);       //  8.4 MB
  float*  Azh  = (float*) alloc((size_t)1024 * 32 * 64 * 4);
  float*  rbuf = (float*) alloc((size_t)1024 * 32 * 64 * 4);
  float*  h1   = (float*) alloc((size_t)1024 * 32 * 64 * 4);       // h1,h2 contiguous
  float*  h2   = (float*) alloc((size_t)1024 * 32 * 64 * 4);
  // total ~235 MB

  // ---- prelude (same every call; graph-safe) ----
  compute_A_kernel<<<1024, 256, 0, stream>>>(E, A);
  auto mw = [&](const float* pool, __half* W, int J) {
    size_t total = (size_t)1024 * (J / 4);
    make_w_kernel<<<(int)((total + 255) / 256), 256, 0, stream>>>(E, pool, W, J);
  };
  mw(gw0, Wg0, 2 * 66 * 128);
  mw(uw0, Wu0, 2 * 66 * 64);
  mw(gw1, Wg1, 2 * 128 * 128);
  mw(uw1, Wu1, 2 * 128 * 64);
  auto mb = [&](const float* pool, float* Bo, int O) {
    make_b_kernel<<<(1024 * O + 255) / 256, 256, 0, stream>>>(E, pool, Bo, O);
  };
  mb(gb0, Bg0, 128); mb(ub0, Bu0, 64); mb(gb1, Bg1, 128); mb(ub1, Bu1, 64);
  zero_kernel<<<(2 * 1024 * 32 * 64 + 255) / 256, 256, 0, stream>>>(h1, 2 * 1024 * 32 * 64);

  // ---- 12 GRU steps, layers interleaved (avoids materializing h1 sequence) ----
  for (int t = 0; t < 12; ++t) {
    // layer 0 (C=2, F=66, LD=68, KI=132)
    build_inp0_kernel<<<(1024 * 32 * 68 + 255) / 256, 256, 0, stream>>>(src, h1, inp, t);
    gemm_kernel<<<dim3(2176 / 64, 8), 256, 0, stream>>>(A, inp, Ainp, 2176);
    gate_kernel<132, 66, 68><<<1024, 256, 0, stream>>>(inp, Ainp, Wg0, Bg0, h1, zh, rbuf);
    gemm_kernel<<<dim3(2048 / 64, 8), 256, 0, stream>>>(A, zh, Azh, 2048);
    upd_kernel<132, 66, 68, 2><<<1024, 128, 0, stream>>>(inp, Ainp, zh, Azh, Wu0, Bu0, rbuf, h1);
    // layer 1 (C=64, F=128, LD=128, KI=256)
    build_inp1_kernel<<<(1024 * 32 * 128 + 255) / 256, 256, 0, stream>>>(h1, h2, inp);
    gemm_kernel<<<dim3(4096 / 64, 8), 256, 0, stream>>>(A, inp, Ainp, 4096);
    gate_kernel<256, 128, 128><<<1024, 256, 0, stream>>>(inp, Ainp, Wg1, Bg1, h2, zh, rbuf);
    gemm_kernel<<<dim3(2048 / 64, 8), 256, 0, stream>>>(A, zh, Azh, 2048);
    upd_kernel<256, 128, 128, 64><<<1024, 128, 0, stream>>>(inp, Ainp, zh, Azh, Wu1, Bu1, rbuf, h2);
  }

  final_conv_kernel<<<(32 * 1024 + 255) / 256, 256, 0, stream>>>(h2, cw, cb, out);
}

// Round 2
// 3291.249 us; speedup vs baseline: 2.0481x; 2.0481x over previous
//
#include <hip/hip_runtime.h>
#include <hip/hip_fp16.h>

// AGCRN: B=32 T=12 N=1024 C=2 D=16 H=64 K=2 OUT=12
// Activations node-major: X[m(node)][c=(b,f)].  A@X via fp16 MFMA needs
// B-operand K-contiguous => transpose X -> Xt[c][m] (fp16) per GEMM.
// Layer0: C=2, F=66, LD=68 (Nc=2176), KI=132.  Layer1: F=128=LD (Nc=4096), KI=256.

typedef _Float16 f16x8 __attribute__((ext_vector_type(8)));
typedef float f32x4 __attribute__((ext_vector_type(4)));

// ---------------- A = softmax(relu(E E^T)) -> fp16 ----------------
__global__ __launch_bounds__(256) void compute_A_kernel(const float* __restrict__ E,
                                                        __half* __restrict__ Ah) {
  int n = blockIdx.x;
  int tid = threadIdx.x;
  __shared__ float red[256];
  float en[16];
#pragma unroll
  for (int d = 0; d < 16; ++d) en[d] = E[n * 16 + d];
  float v[4];
#pragma unroll
  for (int q = 0; q < 4; ++q) {
    int m = tid + q * 256;
    const float* Em = E + m * 16;
    float dot = 0.f;
#pragma unroll
    for (int d = 0; d < 16; ++d) dot += en[d] * Em[d];
    v[q] = fmaxf(dot, 0.f);
  }
  float mx = fmaxf(fmaxf(v[0], v[1]), fmaxf(v[2], v[3]));
  red[tid] = mx; __syncthreads();
  for (int s = 128; s > 0; s >>= 1) { if (tid < s) red[tid] = fmaxf(red[tid], red[tid + s]); __syncthreads(); }
  mx = red[0];
  __syncthreads();
  float e[4], sum = 0.f;
#pragma unroll
  for (int q = 0; q < 4; ++q) { e[q] = expf(v[q] - mx); sum += e[q]; }
  red[tid] = sum; __syncthreads();
  for (int s = 128; s > 0; s >>= 1) { if (tid < s) red[tid] += red[tid + s]; __syncthreads(); }
  float inv = 1.f / red[0];
#pragma unroll
  for (int q = 0; q < 4; ++q) Ah[(size_t)n * 1024 + tid + q * 256] = __float2half(e[q] * inv);
}

// ---------------- W[n, j] = sum_d E[n,d] * pool[d, j], fp16 out ----------------
__global__ void make_w_kernel(const float* __restrict__ E, const float* __restrict__ pool,
                              __half* __restrict__ W, int J) {
  int J4 = J >> 2;
  size_t tid = (size_t)blockIdx.x * 256 + threadIdx.x;
  size_t total = (size_t)1024 * J4;
  if (tid >= total) return;
  int n = (int)(tid / J4);
  int j = (int)(tid % J4) * 4;
  const float* En = E + n * 16;
  float a0 = 0.f, a1 = 0.f, a2 = 0.f, a3 = 0.f;
#pragma unroll
  for (int d = 0; d < 16; ++d) {
    float e = En[d];
    const float4 p = *(const float4*)(pool + (size_t)d * J + j);
    a0 += e * p.x; a1 += e * p.y; a2 += e * p.z; a3 += e * p.w;
  }
  __half2* o = (__half2*)(W + (size_t)n * J + j);
  o[0] = __floats2half2_rn(a0, a1);
  o[1] = __floats2half2_rn(a2, a3);
}

// ---------------- per-node bias ----------------
__global__ void make_b_kernel(const float* __restrict__ E, const float* __restrict__ pool,
                              float* __restrict__ Bout, int O) {
  int tid = blockIdx.x * 256 + threadIdx.x;
  if (tid >= 1024 * O) return;
  int n = tid / O, o = tid % O;
  const float* En = E + n * 16;
  float a = 0.f;
#pragma unroll
  for (int d = 0; d < 16; ++d) a += En[d] * pool[d * O + o];
  Bout[tid] = a;
}

__global__ void zero_kernel(float* __restrict__ p, int count) {
  int i = blockIdx.x * 256 + threadIdx.x;
  if (i < count) p[i] = 0.f;
}

// ---------------- build layer inputs (node-major fp32) ----------------
__global__ void build_inp0_kernel(const float* __restrict__ src, const float* __restrict__ h1,
                                  float* __restrict__ inp, int t) {
  int idx = blockIdx.x * 256 + threadIdx.x;
  if (idx >= 1024 * 32 * 68) return;
  int f = idx % 68; int nb = idx / 68; int b = nb & 31; int n = nb >> 5;
  float v;
  if (f < 2)       v = src[((size_t)(b * 12 + t) * 1024 + n) * 2 + f];
  else if (f < 66) v = h1[(size_t)nb * 64 + f - 2];
  else             v = 0.f;
  inp[idx] = v;
}

__global__ void build_inp1_kernel(const float* __restrict__ h1, const float* __restrict__ h2,
                                  float* __restrict__ inp) {
  int idx = blockIdx.x * 256 + threadIdx.x;
  if (idx >= 1024 * 32 * 128) return;
  int f = idx & 127; int nb = idx >> 7;
  inp[idx] = (f < 64) ? h1[(size_t)nb * 64 + f] : h2[(size_t)nb * 64 + f - 64];
}

// ---------------- tiled transpose: X[1024][C] fp32 -> Xt[C][1024] fp16 ----------------
__global__ __launch_bounds__(256) void transpose_kernel(const float* __restrict__ X,
                                                        __half* __restrict__ Xt, int C) {
  __shared__ float T[32][33];
  int c0 = blockIdx.x * 32;
  int r0 = blockIdx.y * 32;
  int tid = threadIdx.x;
  int tc = tid & 31, tr = tid >> 5;
#pragma unroll
  for (int rr = 0; rr < 32; rr += 8)
    T[tr + rr][tc] = X[(size_t)(r0 + tr + rr) * C + c0 + tc];
  __syncthreads();
  int cl = tid >> 3, q = (tid & 7) * 4;
  __half2 h0 = __floats2half2_rn(T[q + 0][cl], T[q + 1][cl]);
  __half2 h1 = __floats2half2_rn(T[q + 2][cl], T[q + 3][cl]);
  __half2* o = (__half2*)(Xt + (size_t)(c0 + cl) * 1024 + r0 + q);
  o[0] = h0; o[1] = h1;
}

// ---------------- Y[1024 x Nc] = Ah[1024x1024] @ X, MFMA fp16 ----------------
// Ah row-major (K-contig), Xt[c][m] row-major (K-contig). Tile 64(M) x 128(N) x 32(K).
// 4 waves: wm=wave&1 (32 rows), wn=wave>>1 (64 cols); 2x4 frags of 16x16 per wave.
__global__ __launch_bounds__(256) void gemm_mfma_kernel(const __half* __restrict__ Ahg,
                                                        const __half* __restrict__ Xtg,
                                                        float* __restrict__ Y, int Nc) {
  __shared__ __align__(16) _Float16 As[64][40];   // 32 + 8 pad
  __shared__ __align__(16) _Float16 Bs[128][40];
  const _Float16* __restrict__ Ah = (const _Float16*)Ahg;
  const _Float16* __restrict__ Xt = (const _Float16*)Xtg;
  int tid = threadIdx.x;
  int row0 = blockIdx.y * 64;    // M (output node)
  int col0 = blockIdx.x * 128;   // N (c)
  int wave = tid >> 6, lane = tid & 63;
  int wm = wave & 1, wn = wave >> 1;
  int fm = lane & 15, fg = lane >> 4;   // frag row/col index, k-group

  f32x4 acc[2][4] = {};
  int ar = tid >> 2, aq = (tid & 3) * 8;      // A staging: 64 rows x 4 chunks
  for (int k0 = 0; k0 < 1024; k0 += 32) {
    *(float4*)&As[ar][aq] = *(const float4*)(Ah + (size_t)(row0 + ar) * 1024 + k0 + aq);
#pragma unroll
    for (int u = 0; u < 2; ++u) {             // B staging: 128 rows x 4 chunks
      int idx = tid + u * 256;
      int br = idx >> 2, bq = (idx & 3) * 8;
      *(float4*)&Bs[br][bq] = *(const float4*)(Xt + (size_t)(col0 + br) * 1024 + k0 + bq);
    }
    __syncthreads();
    f16x8 af[2], bf[4];
#pragma unroll
    for (int i = 0; i < 2; ++i)
      af[i] = *(const f16x8*)&As[wm * 32 + i * 16 + fm][fg * 8];
#pragma unroll
    for (int j = 0; j < 4; ++j)
      bf[j] = *(const f16x8*)&Bs[wn * 64 + j * 16 + fm][fg * 8];
#pragma unroll
    for (int i = 0; i < 2; ++i)
#pragma unroll
      for (int j = 0; j < 4; ++j)
        acc[i][j] = __builtin_amdgcn_mfma_f32_16x16x32_f16(af[i], bf[j], acc[i][j], 0, 0, 0);
    __syncthreads();
  }
  // D: col = lane&15 (N), row = (lane>>4)*4 + reg (M)
#pragma unroll
  for (int i = 0; i < 2; ++i) {
#pragma unroll
    for (int j = 0; j < 4; ++j) {
      int col = col0 + wn * 64 + j * 16 + fm;
      int rbase = row0 + wm * 32 + i * 16 + fg * 4;
#pragma unroll
      for (int r = 0; r < 4; ++r)
        Y[(size_t)(rbase + r) * Nc + col] = acc[i][j][r];
    }
  }
}

// ---------------- gate: zr = sigmoid(Xn @ Wg[n] + Bg[n]); zh = z*h; store r ----------------
template <int KI, int F, int LD>
__global__ __launch_bounds__(256) void gate_kernel(
    const float* __restrict__ inp, const float* __restrict__ Ainp,
    const __half* __restrict__ W, const float* __restrict__ Bg,
    const float* __restrict__ h, float* __restrict__ zh, float* __restrict__ rbuf) {
  int n = blockIdx.x;
  __shared__ float Xs[32 * KI];
  const float* inp_n = inp + (size_t)n * 32 * LD;
  const float* Ainp_n = Ainp + (size_t)n * 32 * LD;
  for (int i = threadIdx.x; i < 32 * F; i += 256) {
    int b = i / F, f = i - b * F;
    Xs[b * KI + f]     = inp_n[b * LD + f];
    Xs[b * KI + F + f] = Ainp_n[b * LD + f];
  }
  __syncthreads();
  int o0 = (threadIdx.x & 31) * 4;
  int b0 = (threadIdx.x >> 5) * 4;
  float acc[4][4] = {};
  const __half* Wn = W + (size_t)n * KI * 128 + o0;
#pragma unroll 4
  for (int ki = 0; ki < KI; ++ki) {
    const __half2* wp = (const __half2*)(Wn + (size_t)ki * 128);
    float2 w01 = __half22float2(wp[0]);
    float2 w23 = __half22float2(wp[1]);
#pragma unroll
    for (int j = 0; j < 4; ++j) {
      float x = Xs[(b0 + j) * KI + ki];
      acc[j][0] += x * w01.x; acc[j][1] += x * w01.y;
      acc[j][2] += x * w23.x; acc[j][3] += x * w23.y;
    }
  }
  const float* Bn = Bg + n * 128;
#pragma unroll
  for (int j = 0; j < 4; ++j) {
    int b = b0 + j;
    size_t base = ((size_t)n * 32 + b) * 64;
#pragma unroll
    for (int i = 0; i < 4; ++i) {
      int o = o0 + i;
      float s = 1.f / (1.f + __expf(-(acc[j][i] + Bn[o])));
      if (o < 64) zh[base + o] = s * h[base + o];
      else        rbuf[base + o - 64] = s;
    }
  }
}

// ---------------- upd: hc = tanh(Xc @ Wu[n] + Bu[n]); h = r*h + (1-r)*hc ----------------
template <int KI, int F, int LD, int C>
__global__ __launch_bounds__(128) void upd_kernel(
    const float* __restrict__ inp, const float* __restrict__ Ainp,
    const float* __restrict__ zh, const float* __restrict__ Azh,
    const __half* __restrict__ W, const float* __restrict__ Bu,
    const float* __restrict__ rbuf, float* __restrict__ h) {
  int n = blockIdx.x;
  __shared__ float Xs[32 * KI];
  const float* inp_n = inp + (size_t)n * 32 * LD;
  const float* Ainp_n = Ainp + (size_t)n * 32 * LD;
  const float* zh_n = zh + (size_t)n * 32 * 64;
  const float* Azh_n = Azh + (size_t)n * 32 * 64;
  for (int i = threadIdx.x; i < 32 * F; i += 128) {
    int b = i / F, f = i - b * F;
    float v0, v1;
    if (f < C) { v0 = inp_n[b * LD + f];      v1 = Ainp_n[b * LD + f]; }
    else       { v0 = zh_n[b * 64 + f - C];   v1 = Azh_n[b * 64 + f - C]; }
    Xs[b * KI + f]     = v0;
    Xs[b * KI + F + f] = v1;
  }
  __syncthreads();
  int o0 = (threadIdx.x & 15) * 4;
  int b0 = (threadIdx.x >> 4) * 4;
  float acc[4][4] = {};
  const __half* Wn = W + (size_t)n * KI * 64 + o0;
#pragma unroll 4
  for (int ki = 0; ki < KI; ++ki) {
    const __half2* wp = (const __half2*)(Wn + (size_t)ki * 64);
    float2 w01 = __half22float2(wp[0]);
    float2 w23 = __half22float2(wp[1]);
#pragma unroll
    for (int j = 0; j < 4; ++j) {
      float x = Xs[(b0 + j) * KI + ki];
      acc[j][0] += x * w01.x; acc[j][1] += x * w01.y;
      acc[j][2] += x * w23.x; acc[j][3] += x * w23.y;
    }
  }
  const float* Bn = Bu + n * 64;
#pragma unroll
  for (int j = 0; j < 4; ++j) {
    int b = b0 + j;
    size_t base = ((size_t)n * 32 + b) * 64;
#pragma unroll
    for (int i = 0; i < 4; ++i) {
      int o = o0 + i;
      float x = acc[j][i] + Bn[o];
      x = fminf(fmaxf(x, -30.f), 30.f);
      float e = __expf(2.f * x);
      float hc = (e - 1.f) / (e + 1.f);
      float rr = rbuf[base + o];
      float hold = h[base + o];
      h[base + o] = rr * hold + (1.f - rr) * hc;
    }
  }
}

// ---------------- out[b,o,n] = h2[n,b,:] . conv_w[o,:] + conv_b[o] ----------------
__global__ void final_conv_kernel(const float* __restrict__ h2, const float* __restrict__ cw,
                                  const float* __restrict__ cb, float* __restrict__ out) {
  int tid = blockIdx.x * 256 + threadIdx.x;
  if (tid >= 32 * 1024) return;
  int n = tid & 1023, b = tid >> 10;
  const float* hp = h2 + ((size_t)n * 32 + b) * 64;
  float hv[64];
#pragma unroll
  for (int i = 0; i < 64; ++i) hv[i] = hp[i];
#pragma unroll
  for (int o = 0; o < 12; ++o) {
    float acc = cb[o];
#pragma unroll
    for (int i = 0; i < 64; ++i) acc += hv[i] * cw[o * 64 + i];
    out[((size_t)b * 12 + o) * 1024 + n] = acc;
  }
}

extern "C" void kernel_launch(void* const* d_in, const int* in_sizes, int n_in,
                              void* d_out, int out_size, void* d_ws, size_t ws_size,
                              hipStream_t stream) {
  const float* src = (const float*)d_in[0];
  const float* E   = (const float*)d_in[1];
  const float* gw0 = (const float*)d_in[2];
  const float* gb0 = (const float*)d_in[3];
  const float* uw0 = (const float*)d_in[4];
  const float* ub0 = (const float*)d_in[5];
  const float* gw1 = (const float*)d_in[6];
  const float* gb1 = (const float*)d_in[7];
  const float* uw1 = (const float*)d_in[8];
  const float* ub1 = (const float*)d_in[9];
  const float* cw  = (const float*)d_in[10];
  const float* cb  = (const float*)d_in[11];
  float* out = (float*)d_out;
  (void)in_sizes; (void)n_in; (void)out_size; (void)ws_size;

  char* base = (char*)d_ws;
  size_t off = 0;
  auto alloc = [&](size_t bytes) -> void* {
    void* p = base + off; off += (bytes + 511) & ~(size_t)511; return p;
  };
  __half* Ah   = (__half*)alloc((size_t)1024 * 1024 * 2);          //  2.1 MB
  __half* Wg0  = (__half*)alloc((size_t)1024 * 132 * 128 * 2);     // 34.6 MB
  __half* Wu0  = (__half*)alloc((size_t)1024 * 132 * 64 * 2);      // 17.3 MB
  __half* Wg1  = (__half*)alloc((size_t)1024 * 256 * 128 * 2);     // 67.1 MB
  __half* Wu1  = (__half*)alloc((size_t)1024 * 256 * 64 * 2);      // 33.6 MB
  float*  Bg0  = (float*) alloc((size_t)1024 * 128 * 4);
  float*  Bu0  = (float*) alloc((size_t)1024 * 64 * 4);
  float*  Bg1  = (float*) alloc((size_t)1024 * 128 * 4);
  float*  Bu1  = (float*) alloc((size_t)1024 * 64 * 4);
  float*  inp  = (float*) alloc((size_t)1024 * 32 * 128 * 4);      // 16.8 MB
  float*  Ainp = (float*) alloc((size_t)1024 * 32 * 128 * 4);      // 16.8 MB
  float*  zh   = (float*) alloc((size_t)1024 * 32 * 64 * 4);       //  8.4 MB
  float*  Azh  = (float*) alloc((size_t)1024 * 32 * 64 * 4);
  float*  rbuf = (float*) alloc((size_t)1024 * 32 * 64 * 4);
  float*  h1   = (float*) alloc((size_t)1024 * 32 * 64 * 4);
  float*  h2   = (float*) alloc((size_t)1024 * 32 * 64 * 4);
  __half* inpT = (__half*)alloc((size_t)4096 * 1024 * 2);          //  8.4 MB
  __half* zhT  = (__half*)alloc((size_t)2048 * 1024 * 2);          //  4.2 MB
  // total ~250 MB

  // ---- prelude ----
  compute_A_kernel<<<1024, 256, 0, stream>>>(E, Ah);
  auto mw = [&](const float* pool, __half* W, int J) {
    size_t total = (size_t)1024 * (J / 4);
    make_w_kernel<<<(int)((total + 255) / 256), 256, 0, stream>>>(E, pool, W, J);
  };
  mw(gw0, Wg0, 2 * 66 * 128);
  mw(uw0, Wu0, 2 * 66 * 64);
  mw(gw1, Wg1, 2 * 128 * 128);
  mw(uw1, Wu1, 2 * 128 * 64);
  auto mb = [&](const float* pool, float* Bo, int O) {
    make_b_kernel<<<(1024 * O + 255) / 256, 256, 0, stream>>>(E, pool, Bo, O);
  };
  mb(gb0, Bg0, 128); mb(ub0, Bu0, 64); mb(gb1, Bg1, 128); mb(ub1, Bu1, 64);
  zero_kernel<<<(2 * 1024 * 32 * 64 + 255) / 256, 256, 0, stream>>>(h1, 2 * 1024 * 32 * 64);

  auto gemm = [&](const float* X, __half* XT, float* Yo, int Nc) {
    transpose_kernel<<<dim3(Nc / 32, 32), 256, 0, stream>>>(X, XT, Nc);
    gemm_mfma_kernel<<<dim3(Nc / 128, 16), 256, 0, stream>>>(Ah, XT, Yo, Nc);
  };

  // ---- 12 GRU steps ----
  for (int t = 0; t < 12; ++t) {
    // layer 0 (C=2, F=66, LD=68, KI=132)
    build_inp0_kernel<<<(1024 * 32 * 68 + 255) / 256, 256, 0, stream>>>(src, h1, inp, t);
    gemm(inp, inpT, Ainp, 2176);
    gate_kernel<132, 66, 68><<<1024, 256, 0, stream>>>(inp, Ainp, Wg0, Bg0, h1, zh, rbuf);
    gemm(zh, zhT, Azh, 2048);
    upd_kernel<132, 66, 68, 2><<<1024, 128, 0, stream>>>(inp, Ainp, zh, Azh, Wu0, Bu0, rbuf, h1);
    // layer 1 (C=64, F=128, LD=128, KI=256)
    build_inp1_kernel<<<(1024 * 32 * 128 + 255) / 256, 256, 0, stream>>>(h1, h2, inp);
    gemm(inp, inpT, Ainp, 4096);
    gate_kernel<256, 128, 128><<<1024, 256, 0, stream>>>(inp, Ainp, Wg1, Bg1, h2, zh, rbuf);
    gemm(zh, zhT, Azh, 2048);
    upd_kernel<256, 128, 128, 64><<<1024, 128, 0, stream>>>(inp, Ainp, zh, Azh, Wu1, Bu1, rbuf, h2);
  }

  final_conv_kernel<<<(32 * 1024 + 255) / 256, 256, 0, stream>>>(h2, cw, cb, out);
}

// Round 3
// 2622.762 us; speedup vs baseline: 2.5701x; 1.2549x over previous
//
#include <hip/hip_runtime.h>
#include <hip/hip_fp16.h>

// AGCRN: B=32 T=12 N=1024 C=2 D=16 H=64 K=2 OUT=12
// Activations node-major: X[m(node)][c=(b,f)].  A@X via fp16 MFMA (Xt = transposed fp16).
// Per-node gate/upd GEMMs via MFMA with transposed weights Wt[n][o][ki] (K-contiguous).
// Layer0: F=66, LD=68, KIp=160 (Fp=80, zero-padded).  Layer1: F=128=LD, KIp=256.

typedef _Float16 f16x8 __attribute__((ext_vector_type(8)));
typedef float f32x4 __attribute__((ext_vector_type(4)));

// ---------------- A = softmax(relu(E E^T)) -> fp16 ----------------
__global__ __launch_bounds__(256) void compute_A_kernel(const float* __restrict__ E,
                                                        __half* __restrict__ Ah) {
  int n = blockIdx.x;
  int tid = threadIdx.x;
  __shared__ float red[256];
  float en[16];
#pragma unroll
  for (int d = 0; d < 16; ++d) en[d] = E[n * 16 + d];
  float v[4];
#pragma unroll
  for (int q = 0; q < 4; ++q) {
    int m = tid + q * 256;
    const float* Em = E + m * 16;
    float dot = 0.f;
#pragma unroll
    for (int d = 0; d < 16; ++d) dot += en[d] * Em[d];
    v[q] = fmaxf(dot, 0.f);
  }
  float mx = fmaxf(fmaxf(v[0], v[1]), fmaxf(v[2], v[3]));
  red[tid] = mx; __syncthreads();
  for (int s = 128; s > 0; s >>= 1) { if (tid < s) red[tid] = fmaxf(red[tid], red[tid + s]); __syncthreads(); }
  mx = red[0];
  __syncthreads();
  float e[4], sum = 0.f;
#pragma unroll
  for (int q = 0; q < 4; ++q) { e[q] = expf(v[q] - mx); sum += e[q]; }
  red[tid] = sum; __syncthreads();
  for (int s = 128; s > 0; s >>= 1) { if (tid < s) red[tid] += red[tid + s]; __syncthreads(); }
  float inv = 1.f / red[0];
#pragma unroll
  for (int q = 0; q < 4; ++q) Ah[(size_t)n * 1024 + tid + q * 256] = __float2half(e[q] * inv);
}

// ---------------- poolT[d][o][kip] = pool[d][kk][i][o], kip = kk*Fp+i, zero-padded ----------------
__global__ void pool_transpose_kernel(const float* __restrict__ pool, float* __restrict__ poolT,
                                      int F, int Fp, int O) {
  int KIp = 2 * Fp;
  int total = 16 * O * KIp;
  int t = blockIdx.x * 256 + threadIdx.x;
  if (t >= total) return;
  int kip = t % KIp;
  int rest = t / KIp;
  int o = rest % O;
  int d = rest / O;
  int kk = (kip >= Fp) ? 1 : 0;
  int i = kip - kk * Fp;
  poolT[t] = (i < F) ? pool[(((size_t)d * 2 + kk) * F + i) * O + o] : 0.f;
}

// ---------------- Wt[n][o][ki] = sum_d E[n,d] poolT[d][o][ki], fp16 ----------------
// grid (O, 16 groups of 64 nodes), block 256 (= 64 n x 4 ki-quarters)
__global__ __launch_bounds__(256) void make_wt_kernel(const float* __restrict__ E,
                                                      const float* __restrict__ poolT,
                                                      __half* __restrict__ Wt,
                                                      int O, int KIp) {
  __shared__ float pl[16 * 256];
  __shared__ float Es[64 * 17];
  int o = blockIdx.x;
  int n0 = blockIdx.y * 64;
  int q = KIp >> 2;
  for (int idx = threadIdx.x; idx < 4 * KIp; idx += 256) {  // 16*KIp floats / 4
    int d = idx / q;
    int k4 = (idx - d * q) * 4;
    float4 v = *(const float4*)(poolT + ((size_t)d * O + o) * KIp + k4);
    *(float4*)&pl[d * KIp + k4] = v;
  }
  {
    int nl = threadIdx.x >> 2, d0 = (threadIdx.x & 3) * 4;
    float4 v = *(const float4*)(E + (size_t)(n0 + nl) * 16 + d0);
    Es[nl * 17 + d0 + 0] = v.x; Es[nl * 17 + d0 + 1] = v.y;
    Es[nl * 17 + d0 + 2] = v.z; Es[nl * 17 + d0 + 3] = v.w;
  }
  __syncthreads();
  int nl = threadIdx.x & 63, kq = threadIdx.x >> 6;
  int k0 = kq * q;
  float e[16];
#pragma unroll
  for (int d = 0; d < 16; ++d) e[d] = Es[nl * 17 + d];
  __half* orow = Wt + ((size_t)(n0 + nl) * O + o) * KIp + k0;
  for (int kk = 0; kk < q; kk += 8) {
    float a[8];
#pragma unroll
    for (int j = 0; j < 8; ++j) {
      float s = 0.f;
#pragma unroll
      for (int d = 0; d < 16; ++d) s += e[d] * pl[d * KIp + k0 + kk + j];
      a[j] = s;
    }
    float4 pk;
    __half2* ph = (__half2*)&pk;
    ph[0] = __floats2half2_rn(a[0], a[1]);
    ph[1] = __floats2half2_rn(a[2], a[3]);
    ph[2] = __floats2half2_rn(a[4], a[5]);
    ph[3] = __floats2half2_rn(a[6], a[7]);
    *(float4*)(orow + kk) = pk;
  }
}

// ---------------- per-node bias ----------------
__global__ void make_b_kernel(const float* __restrict__ E, const float* __restrict__ pool,
                              float* __restrict__ Bout, int O) {
  int tid = blockIdx.x * 256 + threadIdx.x;
  if (tid >= 1024 * O) return;
  int n = tid / O, o = tid % O;
  const float* En = E + n * 16;
  float a = 0.f;
#pragma unroll
  for (int d = 0; d < 16; ++d) a += En[d] * pool[d * O + o];
  Bout[tid] = a;
}

__global__ void zero_kernel(float* __restrict__ p, int count) {
  int i = blockIdx.x * 256 + threadIdx.x;
  if (i < count) p[i] = 0.f;
}

// ---------------- build layer inputs (node-major fp32) ----------------
__global__ void build_inp0_kernel(const float* __restrict__ src, const float* __restrict__ h1,
                                  float* __restrict__ inp, int t) {
  int idx = blockIdx.x * 256 + threadIdx.x;
  if (idx >= 1024 * 32 * 68) return;
  int f = idx % 68; int nb = idx / 68; int b = nb & 31; int n = nb >> 5;
  float v;
  if (f < 2)       v = src[((size_t)(b * 12 + t) * 1024 + n) * 2 + f];
  else if (f < 66) v = h1[(size_t)nb * 64 + f - 2];
  else             v = 0.f;
  inp[idx] = v;
}

__global__ void build_inp1_kernel(const float* __restrict__ h1, const float* __restrict__ h2,
                                  float* __restrict__ inp) {
  int idx = blockIdx.x * 256 + threadIdx.x;
  if (idx >= 1024 * 32 * 128) return;
  int f = idx & 127; int nb = idx >> 7;
  inp[idx] = (f < 64) ? h1[(size_t)nb * 64 + f] : h2[(size_t)nb * 64 + f - 64];
}

// ---------------- tiled transpose: X[1024][C] fp32 -> Xt[C][1024] fp16 ----------------
__global__ __launch_bounds__(256) void transpose_kernel(const float* __restrict__ X,
                                                        __half* __restrict__ Xt, int C) {
  __shared__ float T[32][33];
  int c0 = blockIdx.x * 32;
  int r0 = blockIdx.y * 32;
  int tid = threadIdx.x;
  int tc = tid & 31, tr = tid >> 5;
#pragma unroll
  for (int rr = 0; rr < 32; rr += 8)
    T[tr + rr][tc] = X[(size_t)(r0 + tr + rr) * C + c0 + tc];
  __syncthreads();
  int cl = tid >> 3, q = (tid & 7) * 4;
  __half2 h0 = __floats2half2_rn(T[q + 0][cl], T[q + 1][cl]);
  __half2 h1 = __floats2half2_rn(T[q + 2][cl], T[q + 3][cl]);
  __half2* o = (__half2*)(Xt + (size_t)(c0 + cl) * 1024 + r0 + q);
  o[0] = h0; o[1] = h1;
}

// ---------------- Y[1024 x Nc] = Ah[1024x1024] @ X, MFMA fp16 ----------------
__global__ __launch_bounds__(256) void gemm_mfma_kernel(const __half* __restrict__ Ahg,
                                                        const __half* __restrict__ Xtg,
                                                        float* __restrict__ Y, int Nc) {
  __shared__ __align__(16) _Float16 As[64][40];
  __shared__ __align__(16) _Float16 Bs[128][40];
  const _Float16* __restrict__ Ah = (const _Float16*)Ahg;
  const _Float16* __restrict__ Xt = (const _Float16*)Xtg;
  int tid = threadIdx.x;
  int row0 = blockIdx.y * 64;
  int col0 = blockIdx.x * 128;
  int wave = tid >> 6, lane = tid & 63;
  int wm = wave & 1, wn = wave >> 1;
  int fm = lane & 15, fg = lane >> 4;

  f32x4 acc[2][4] = {};
  int ar = tid >> 2, aq = (tid & 3) * 8;
  for (int k0 = 0; k0 < 1024; k0 += 32) {
    *(float4*)&As[ar][aq] = *(const float4*)(Ah + (size_t)(row0 + ar) * 1024 + k0 + aq);
#pragma unroll
    for (int u = 0; u < 2; ++u) {
      int idx = tid + u * 256;
      int br = idx >> 2, bq = (idx & 3) * 8;
      *(float4*)&Bs[br][bq] = *(const float4*)(Xt + (size_t)(col0 + br) * 1024 + k0 + bq);
    }
    __syncthreads();
    f16x8 af[2], bf[4];
#pragma unroll
    for (int i = 0; i < 2; ++i)
      af[i] = *(const f16x8*)&As[wm * 32 + i * 16 + fm][fg * 8];
#pragma unroll
    for (int j = 0; j < 4; ++j)
      bf[j] = *(const f16x8*)&Bs[wn * 64 + j * 16 + fm][fg * 8];
#pragma unroll
    for (int i = 0; i < 2; ++i)
#pragma unroll
      for (int j = 0; j < 4; ++j)
        acc[i][j] = __builtin_amdgcn_mfma_f32_16x16x32_f16(af[i], bf[j], acc[i][j], 0, 0, 0);
    __syncthreads();
  }
#pragma unroll
  for (int i = 0; i < 2; ++i) {
#pragma unroll
    for (int j = 0; j < 4; ++j) {
      int col = col0 + wn * 64 + j * 16 + fm;
      int rbase = row0 + wm * 32 + i * 16 + fg * 4;
#pragma unroll
      for (int r = 0; r < 4; ++r)
        Y[(size_t)(rbase + r) * Nc + col] = acc[i][j][r];
    }
  }
}

// ---------------- gate (MFMA): zr = sigmoid(Xn @ Wt[n]^T + Bg[n]); zh=z*h; rbuf=r ----------------
// One block per node; 4 waves split o (O=128, 32 each). Xn[32 x KIp] staged fp16 in LDS.
template <int KIP, bool L0>
__global__ __launch_bounds__(256) void gate_mfma_kernel(
    const float* __restrict__ inp, const float* __restrict__ Ainp,
    const __half* __restrict__ Wtg, const float* __restrict__ Bg,
    const float* __restrict__ h, float* __restrict__ zh, float* __restrict__ rbuf) {
  constexpr int STRIDE = KIP + 8;
  __shared__ __align__(16) _Float16 Xs[32 * STRIDE];
  int n = blockIdx.x;
  if (L0) {
    const float* inp_n = inp + (size_t)n * 32 * 68;
    const float* Ainp_n = Ainp + (size_t)n * 32 * 68;
    for (int i = threadIdx.x; i < 32 * KIP; i += 256) {
      int b = i / KIP, ki = i - b * KIP;
      float v = 0.f;
      if (ki < 80) { if (ki < 66) v = inp_n[b * 68 + ki]; }
      else { int f = ki - 80; if (f < 66) v = Ainp_n[b * 68 + f]; }
      Xs[b * STRIDE + ki] = (_Float16)v;
    }
  } else {
    const float* inp_n = inp + (size_t)n * 32 * 128;
    const float* Ainp_n = Ainp + (size_t)n * 32 * 128;
#pragma unroll
    for (int u = 0; u < 8; ++u) {
      int idx = (threadIdx.x + u * 256) * 4;
      int b = idx >> 8, k0 = idx & 255;
      float4 v = (k0 < 128) ? *(const float4*)(inp_n + b * 128 + k0)
                            : *(const float4*)(Ainp_n + b * 128 + (k0 - 128));
      __half2* dst = (__half2*)&Xs[b * STRIDE + k0];
      dst[0] = __floats2half2_rn(v.x, v.y);
      dst[1] = __floats2half2_rn(v.z, v.w);
    }
  }
  __syncthreads();
  int wave = threadIdx.x >> 6, lane = threadIdx.x & 63;
  int fm = lane & 15, fg = lane >> 4;
  f32x4 acc[2][2] = {};
  const _Float16* Wn = (const _Float16*)Wtg + ((size_t)n * 128 + wave * 32) * KIP;
#pragma unroll
  for (int kc = 0; kc < KIP / 32; ++kc) {
    f16x8 af[2], bf[2];
#pragma unroll
    for (int i = 0; i < 2; ++i)
      af[i] = *(const f16x8*)&Xs[(i * 16 + fm) * STRIDE + kc * 32 + fg * 8];
#pragma unroll
    for (int j = 0; j < 2; ++j)
      bf[j] = *(const f16x8*)(Wn + (size_t)(j * 16 + fm) * KIP + kc * 32 + fg * 8);
#pragma unroll
    for (int i = 0; i < 2; ++i)
#pragma unroll
      for (int j = 0; j < 2; ++j)
        acc[i][j] = __builtin_amdgcn_mfma_f32_16x16x32_f16(af[i], bf[j], acc[i][j], 0, 0, 0);
  }
  const float* Bn = Bg + n * 128;
#pragma unroll
  for (int j = 0; j < 2; ++j) {
    int o = wave * 32 + j * 16 + fm;
    float bias = Bn[o];
#pragma unroll
    for (int i = 0; i < 2; ++i)
#pragma unroll
      for (int r = 0; r < 4; ++r) {
        int b = i * 16 + fg * 4 + r;
        float s = 1.f / (1.f + __expf(-(acc[i][j][r] + bias)));
        size_t base = ((size_t)n * 32 + b) * 64;
        if (o < 64) zh[base + o] = s * h[base + o];
        else        rbuf[base + o - 64] = s;
      }
  }
}

// ---------------- upd (MFMA): hc = tanh(Xc @ Wt[n]^T + Bu[n]); h = r*h + (1-r)*hc ----------------
template <int KIP, bool L0>
__global__ __launch_bounds__(256) void upd_mfma_kernel(
    const float* __restrict__ inp, const float* __restrict__ Ainp,
    const float* __restrict__ zh, const float* __restrict__ Azh,
    const __half* __restrict__ Wtu, const float* __restrict__ Bu,
    const float* __restrict__ rbuf, float* __restrict__ h) {
  constexpr int STRIDE = KIP + 8;
  __shared__ __align__(16) _Float16 Xs[32 * STRIDE];
  int n = blockIdx.x;
  const float* zh_n = zh + (size_t)n * 2048;
  const float* Azh_n = Azh + (size_t)n * 2048;
  if (L0) {
    const float* inp_n = inp + (size_t)n * 32 * 68;
    const float* Ainp_n = Ainp + (size_t)n * 32 * 68;
    for (int i = threadIdx.x; i < 32 * KIP; i += 256) {
      int b = i / KIP, ki = i - b * KIP;
      float v = 0.f;
      if (ki < 80) {
        if (ki < 2)       v = inp_n[b * 68 + ki];
        else if (ki < 66) v = zh_n[b * 64 + ki - 2];
      } else {
        int f = ki - 80;
        if (f < 2)       v = Ainp_n[b * 68 + f];
        else if (f < 66) v = Azh_n[b * 64 + f - 2];
      }
      Xs[b * STRIDE + ki] = (_Float16)v;
    }
  } else {
    const float* inp_n = inp + (size_t)n * 32 * 128;
    const float* Ainp_n = Ainp + (size_t)n * 32 * 128;
#pragma unroll
    for (int u = 0; u < 8; ++u) {
      int idx = (threadIdx.x + u * 256) * 4;
      int b = idx >> 8, k0 = idx & 255;
      int reg = k0 >> 6, f = k0 & 63;
      const float* srcp;
      if (reg == 0)      srcp = inp_n + b * 128 + f;
      else if (reg == 1) srcp = zh_n + b * 64 + f;
      else if (reg == 2) srcp = Ainp_n + b * 128 + f;
      else               srcp = Azh_n + b * 64 + f;
      float4 v = *(const float4*)srcp;
      __half2* dst = (__half2*)&Xs[b * STRIDE + k0];
      dst[0] = __floats2half2_rn(v.x, v.y);
      dst[1] = __floats2half2_rn(v.z, v.w);
    }
  }
  __syncthreads();
  int wave = threadIdx.x >> 6, lane = threadIdx.x & 63;
  int fm = lane & 15, fg = lane >> 4;
  f32x4 acc[2] = {};
  const _Float16* Wn = (const _Float16*)Wtu + ((size_t)n * 64 + wave * 16) * KIP;
#pragma unroll
  for (int kc = 0; kc < KIP / 32; ++kc) {
    f16x8 bf = *(const f16x8*)(Wn + (size_t)fm * KIP + kc * 32 + fg * 8);
#pragma unroll
    for (int i = 0; i < 2; ++i) {
      f16x8 af = *(const f16x8*)&Xs[(i * 16 + fm) * STRIDE + kc * 32 + fg * 8];
      acc[i] = __builtin_amdgcn_mfma_f32_16x16x32_f16(af, bf, acc[i], 0, 0, 0);
    }
  }
  int o = wave * 16 + fm;
  float bias = Bu[n * 64 + o];
#pragma unroll
  for (int i = 0; i < 2; ++i)
#pragma unroll
    for (int r = 0; r < 4; ++r) {
      int b = i * 16 + fg * 4 + r;
      float x = acc[i][r] + bias;
      x = fminf(fmaxf(x, -15.f), 15.f);
      float e = __expf(2.f * x);
      float hc = (e - 1.f) / (e + 1.f);
      size_t base = ((size_t)n * 32 + b) * 64;
      float rr = rbuf[base + o];
      float hold = h[base + o];
      h[base + o] = rr * hold + (1.f - rr) * hc;
    }
}

// ---------------- out[b,o,n] = h2[n,b,:] . conv_w[o,:] + conv_b[o] ----------------
__global__ void final_conv_kernel(const float* __restrict__ h2, const float* __restrict__ cw,
                                  const float* __restrict__ cb, float* __restrict__ out) {
  int tid = blockIdx.x * 256 + threadIdx.x;
  if (tid >= 32 * 1024) return;
  int n = tid & 1023, b = tid >> 10;
  const float* hp = h2 + ((size_t)n * 32 + b) * 64;
  float hv[64];
#pragma unroll
  for (int i = 0; i < 64; ++i) hv[i] = hp[i];
#pragma unroll
  for (int o = 0; o < 12; ++o) {
    float acc = cb[o];
#pragma unroll
    for (int i = 0; i < 64; ++i) acc += hv[i] * cw[o * 64 + i];
    out[((size_t)b * 12 + o) * 1024 + n] = acc;
  }
}

extern "C" void kernel_launch(void* const* d_in, const int* in_sizes, int n_in,
                              void* d_out, int out_size, void* d_ws, size_t ws_size,
                              hipStream_t stream) {
  const float* src = (const float*)d_in[0];
  const float* E   = (const float*)d_in[1];
  const float* gw0 = (const float*)d_in[2];
  const float* gb0 = (const float*)d_in[3];
  const float* uw0 = (const float*)d_in[4];
  const float* ub0 = (const float*)d_in[5];
  const float* gw1 = (const float*)d_in[6];
  const float* gb1 = (const float*)d_in[7];
  const float* uw1 = (const float*)d_in[8];
  const float* ub1 = (const float*)d_in[9];
  const float* cw  = (const float*)d_in[10];
  const float* cb  = (const float*)d_in[11];
  float* out = (float*)d_out;
  (void)in_sizes; (void)n_in; (void)out_size; (void)ws_size;

  char* base = (char*)d_ws;
  size_t off = 0;
  auto alloc = [&](size_t bytes) -> void* {
    void* p = base + off; off += (bytes + 511) & ~(size_t)511; return p;
  };
  __half* Ah   = (__half*)alloc((size_t)1024 * 1024 * 2);           //   2.1 MB
  __half* WtG0 = (__half*)alloc((size_t)1024 * 128 * 160 * 2);      //  41.9 MB
  __half* WtU0 = (__half*)alloc((size_t)1024 * 64 * 160 * 2);       //  21.0 MB
  __half* WtG1 = (__half*)alloc((size_t)1024 * 128 * 256 * 2);      //  67.1 MB
  __half* WtU1 = (__half*)alloc((size_t)1024 * 64 * 256 * 2);       //  33.6 MB
  float*  Bg0  = (float*) alloc((size_t)1024 * 128 * 4);
  float*  Bu0  = (float*) alloc((size_t)1024 * 64 * 4);
  float*  Bg1  = (float*) alloc((size_t)1024 * 128 * 4);
  float*  Bu1  = (float*) alloc((size_t)1024 * 64 * 4);
  float*  inp  = (float*) alloc((size_t)1024 * 32 * 128 * 4);       //  16.8 MB
  float*  Ainp = (float*) alloc((size_t)1024 * 32 * 128 * 4);       //  16.8 MB
  float*  zh   = (float*) alloc((size_t)1024 * 32 * 64 * 4);        //   8.4 MB
  float*  Azh  = (float*) alloc((size_t)1024 * 32 * 64 * 4);
  float*  h1   = (float*) alloc((size_t)1024 * 32 * 64 * 4);
  float*  h2   = (float*) alloc((size_t)1024 * 32 * 64 * 4);
  // scratch region shared (stream-serialized lifetimes): poolT (prelude, 2.1MB) /
  // inpT (fp16 transposed gemm input, 8.4MB) / rbuf (gate->upd r values, 8.4MB)
  char*   scr  = (char*) alloc((size_t)4096 * 1024 * 2);            //   8.4 MB
  __half* zhT  = (__half*)alloc((size_t)2048 * 1024 * 2);           //   4.2 MB
  float*  poolT = (float*)scr;
  __half* inpT  = (__half*)scr;
  float*  rbuf  = (float*)scr;
  // total ~247 MB

  // ---- prelude ----
  compute_A_kernel<<<1024, 256, 0, stream>>>(E, Ah);
  auto mwt = [&](const float* pool, __half* Wt, int F, int Fp, int O) {
    int KIp = 2 * Fp;
    int total = 16 * O * KIp;
    pool_transpose_kernel<<<(total + 255) / 256, 256, 0, stream>>>(pool, poolT, F, Fp, O);
    make_wt_kernel<<<dim3(O, 16), 256, 0, stream>>>(E, poolT, Wt, O, KIp);
  };
  mwt(gw0, WtG0, 66, 80, 128);
  mwt(uw0, WtU0, 66, 80, 64);
  mwt(gw1, WtG1, 128, 128, 128);
  mwt(uw1, WtU1, 128, 128, 64);
  auto mb = [&](const float* pool, float* Bo, int O) {
    make_b_kernel<<<(1024 * O + 255) / 256, 256, 0, stream>>>(E, pool, Bo, O);
  };
  mb(gb0, Bg0, 128); mb(ub0, Bu0, 64); mb(gb1, Bg1, 128); mb(ub1, Bu1, 64);
  zero_kernel<<<(2 * 1024 * 32 * 64 + 255) / 256, 256, 0, stream>>>(h1, 2 * 1024 * 32 * 64);

  auto gemm = [&](const float* X, __half* XT, float* Yo, int Nc) {
    transpose_kernel<<<dim3(Nc / 32, 32), 256, 0, stream>>>(X, XT, Nc);
    gemm_mfma_kernel<<<dim3(Nc / 128, 16), 256, 0, stream>>>(Ah, XT, Yo, Nc);
  };

  // ---- 12 GRU steps ----
  for (int t = 0; t < 12; ++t) {
    // layer 0 (F=66, LD=68, KIp=160)
    build_inp0_kernel<<<(1024 * 32 * 68 + 255) / 256, 256, 0, stream>>>(src, h1, inp, t);
    gemm(inp, inpT, Ainp, 2176);
    gate_mfma_kernel<160, true><<<1024, 256, 0, stream>>>(inp, Ainp, WtG0, Bg0, h1, zh, rbuf);
    gemm(zh, zhT, Azh, 2048);
    upd_mfma_kernel<160, true><<<1024, 256, 0, stream>>>(inp, Ainp, zh, Azh, WtU0, Bu0, rbuf, h1);
    // layer 1 (F=128, LD=128, KIp=256)
    build_inp1_kernel<<<(1024 * 32 * 128 + 255) / 256, 256, 0, stream>>>(h1, h2, inp);
    gemm(inp, inpT, Ainp, 4096);
    gate_mfma_kernel<256, false><<<1024, 256, 0, stream>>>(inp, Ainp, WtG1, Bg1, h2, zh, rbuf);
    gemm(zh, zhT, Azh, 2048);
    upd_mfma_kernel<256, false><<<1024, 256, 0, stream>>>(inp, Ainp, zh, Azh, WtU1, Bu1, rbuf, h2);
  }

  final_conv_kernel<<<(32 * 1024 + 255) / 256, 256, 0, stream>>>(h2, cw, cb, out);
}

// Round 4
// 2056.801 us; speedup vs baseline: 3.2774x; 1.2752x over previous
//
#include <hip/hip_runtime.h>
#include <hip/hip_fp16.h>

// AGCRN: B=32 T=12 N=1024 C=2 D=16 H=64 K=2 OUT=12
// All GEMM-side activations fp16. h has fp32 master + fp16 mirror.
// A@[x|h] split: A@x_t precomputed for all t (prelude, Nc=768).
// Layer0 weight ki layout (per k-part, Fp=80): [state(64) | x(2) | pad(14)] (zero W in pad).
// Layer1 (Fp=128): identity [h1|h2] / [h1|zh].

typedef _Float16 f16x8 __attribute__((ext_vector_type(8)));
typedef float f32x4 __attribute__((ext_vector_type(4)));

// ---------------- A = softmax(relu(E E^T)) -> fp16 ----------------
__global__ __launch_bounds__(256) void compute_A_kernel(const float* __restrict__ E,
                                                        __half* __restrict__ Ah) {
  int n = blockIdx.x;
  int tid = threadIdx.x;
  __shared__ float red[256];
  float en[16];
#pragma unroll
  for (int d = 0; d < 16; ++d) en[d] = E[n * 16 + d];
  float v[4];
#pragma unroll
  for (int q = 0; q < 4; ++q) {
    int m = tid + q * 256;
    const float* Em = E + m * 16;
    float dot = 0.f;
#pragma unroll
    for (int d = 0; d < 16; ++d) dot += en[d] * Em[d];
    v[q] = fmaxf(dot, 0.f);
  }
  float mx = fmaxf(fmaxf(v[0], v[1]), fmaxf(v[2], v[3]));
  red[tid] = mx; __syncthreads();
  for (int s = 128; s > 0; s >>= 1) { if (tid < s) red[tid] = fmaxf(red[tid], red[tid + s]); __syncthreads(); }
  mx = red[0];
  __syncthreads();
  float e[4], sum = 0.f;
#pragma unroll
  for (int q = 0; q < 4; ++q) { e[q] = expf(v[q] - mx); sum += e[q]; }
  red[tid] = sum; __syncthreads();
  for (int s = 128; s > 0; s >>= 1) { if (tid < s) red[tid] += red[tid + s]; __syncthreads(); }
  float inv = 1.f / red[0];
#pragma unroll
  for (int q = 0; q < 4; ++q) Ah[(size_t)n * 1024 + tid + q * 256] = __float2half(e[q] * inv);
}

// ---------------- poolT[d][o][kip]: permuted/padded K-contiguous pool ----------------
// kip = kk*Fp + j.  F==Fp (L1): i=j.  F<Fp (L0, Fp=80): j<64 -> i=j+2 (state), j=64,65 -> i=j-64 (x), else 0.
__global__ void pool_transpose_kernel(const float* __restrict__ pool, float* __restrict__ poolT,
                                      int F, int Fp, int O) {
  int KIp = 2 * Fp;
  int total = 16 * O * KIp;
  int t = blockIdx.x * 256 + threadIdx.x;
  if (t >= total) return;
  int kip = t % KIp;
  int rest = t / KIp;
  int o = rest % O;
  int d = rest / O;
  int kk = (kip >= Fp) ? 1 : 0;
  int j = kip - kk * Fp;
  int i;
  if (F == Fp) i = j;
  else i = (j < 64) ? j + 2 : (j < 66 ? j - 64 : -1);
  poolT[t] = (i >= 0) ? pool[(((size_t)d * 2 + kk) * F + i) * O + o] : 0.f;
}

// ---------------- Wt[n][o][ki] = sum_d E[n,d] poolT[d][o][ki], fp16 ----------------
__global__ __launch_bounds__(256) void make_wt_kernel(const float* __restrict__ E,
                                                      const float* __restrict__ poolT,
                                                      __half* __restrict__ Wt,
                                                      int O, int KIp) {
  __shared__ float pl[16 * 256];
  __shared__ float Es[64 * 17];
  int o = blockIdx.x;
  int n0 = blockIdx.y * 64;
  int q = KIp >> 2;
  for (int idx = threadIdx.x; idx < 4 * KIp; idx += 256) {
    int d = idx / q;
    int k4 = (idx - d * q) * 4;
    float4 v = *(const float4*)(poolT + ((size_t)d * O + o) * KIp + k4);
    *(float4*)&pl[d * KIp + k4] = v;
  }
  {
    int nl = threadIdx.x >> 2, d0 = (threadIdx.x & 3) * 4;
    float4 v = *(const float4*)(E + (size_t)(n0 + nl) * 16 + d0);
    Es[nl * 17 + d0 + 0] = v.x; Es[nl * 17 + d0 + 1] = v.y;
    Es[nl * 17 + d0 + 2] = v.z; Es[nl * 17 + d0 + 3] = v.w;
  }
  __syncthreads();
  int nl = threadIdx.x & 63, kq = threadIdx.x >> 6;
  int k0 = kq * q;
  float e[16];
#pragma unroll
  for (int d = 0; d < 16; ++d) e[d] = Es[nl * 17 + d];
  __half* orow = Wt + ((size_t)(n0 + nl) * O + o) * KIp + k0;
  for (int kk = 0; kk < q; kk += 8) {
    float a[8];
#pragma unroll
    for (int j = 0; j < 8; ++j) {
      float s = 0.f;
#pragma unroll
      for (int d = 0; d < 16; ++d) s += e[d] * pl[d * KIp + k0 + kk + j];
      a[j] = s;
    }
    float4 pk;
    __half2* ph = (__half2*)&pk;
    ph[0] = __floats2half2_rn(a[0], a[1]);
    ph[1] = __floats2half2_rn(a[2], a[3]);
    ph[2] = __floats2half2_rn(a[4], a[5]);
    ph[3] = __floats2half2_rn(a[6], a[7]);
    *(float4*)(orow + kk) = pk;
  }
}

// ---------------- per-node bias ----------------
__global__ void make_b_kernel(const float* __restrict__ E, const float* __restrict__ pool,
                              float* __restrict__ Bout, int O) {
  int tid = blockIdx.x * 256 + threadIdx.x;
  if (tid >= 1024 * O) return;
  int n = tid / O, o = tid % O;
  const float* En = E + n * 16;
  float a = 0.f;
#pragma unroll
  for (int d = 0; d < 16; ++d) a += En[d] * pool[d * O + o];
  Bout[tid] = a;
}

__global__ void zero_kernel(float* __restrict__ p, int count) {
  int i = blockIdx.x * 256 + threadIdx.x;
  if (i < count) p[i] = 0.f;
}

// ---------------- xT[(t*32+b)*2+cc][n] = src[b][t][n][cc], fp16 ----------------
__global__ void build_xt_kernel(const float* __restrict__ src, __half* __restrict__ xT) {
  int bid = blockIdx.x; int t = bid >> 5, b = bid & 31;
  const float* s = src + (size_t)(b * 12 + t) * 2048;
  __half* o0 = xT + (size_t)(t * 64 + b * 2) * 1024;
  for (int n = threadIdx.x; n < 1024; n += 256) {
    float2 v = *(const float2*)(s + n * 2);
    o0[n] = __float2half(v.x);
    o0[1024 + n] = __float2half(v.y);
  }
}

// ---------------- transpose fp16: X[1024][2048] -> XT[2048][1024] ----------------
__global__ __launch_bounds__(256) void t16_kernel(const __half* __restrict__ Xg,
                                                  __half* __restrict__ XTg) {
  __shared__ __align__(16) _Float16 T[64][72];
  const _Float16* X = (const _Float16*)Xg;
  _Float16* XT = (_Float16*)XTg;
  int c0 = blockIdx.x * 64;   // col tile in X (2048 dim)
  int m0 = blockIdx.y * 64;   // row tile in X (1024 dim)
  int t = threadIdx.x;
#pragma unroll
  for (int u = 0; u < 2; ++u) {
    int idx = t + u * 256;
    int r = idx >> 3, ch = idx & 7;
    f16x8 v = *(const f16x8*)(X + (size_t)(m0 + r) * 2048 + c0 + ch * 8);
#pragma unroll
    for (int j = 0; j < 8; ++j) T[ch * 8 + j][r] = v[j];
  }
  __syncthreads();
#pragma unroll
  for (int u = 0; u < 2; ++u) {
    int idx = t + u * 256;
    int r = idx >> 3, ch = idx & 7;
    *(f16x8*)(XT + (size_t)(c0 + r) * 1024 + m0 + ch * 8) = *(const f16x8*)&T[r][ch * 8];
  }
}

// ---------------- Y[1024 x Nc] = Ah[1024x1024] @ B, fp16 out ----------------
__global__ __launch_bounds__(256) void gemm_mfma_kernel(const __half* __restrict__ Ahg,
                                                        const __half* __restrict__ Xtg,
                                                        __half* __restrict__ Yg, int Nc) {
  __shared__ __align__(16) _Float16 As[64][40];
  __shared__ __align__(16) _Float16 Bs[128][40];
  const _Float16* __restrict__ Ah = (const _Float16*)Ahg;
  const _Float16* __restrict__ Xt = (const _Float16*)Xtg;
  _Float16* __restrict__ Y = (_Float16*)Yg;
  int tid = threadIdx.x;
  int row0 = blockIdx.y * 64;
  int col0 = blockIdx.x * 128;
  int wave = tid >> 6, lane = tid & 63;
  int wm = wave & 1, wn = wave >> 1;
  int fm = lane & 15, fg = lane >> 4;

  f32x4 acc[2][4] = {};
  int ar = tid >> 2, aq = (tid & 3) * 8;
  for (int k0 = 0; k0 < 1024; k0 += 32) {
    *(float4*)&As[ar][aq] = *(const float4*)(Ah + (size_t)(row0 + ar) * 1024 + k0 + aq);
#pragma unroll
    for (int u = 0; u < 2; ++u) {
      int idx = tid + u * 256;
      int br = idx >> 2, bq = (idx & 3) * 8;
      *(float4*)&Bs[br][bq] = *(const float4*)(Xt + (size_t)(col0 + br) * 1024 + k0 + bq);
    }
    __syncthreads();
    f16x8 af[2], bf[4];
#pragma unroll
    for (int i = 0; i < 2; ++i)
      af[i] = *(const f16x8*)&As[wm * 32 + i * 16 + fm][fg * 8];
#pragma unroll
    for (int j = 0; j < 4; ++j)
      bf[j] = *(const f16x8*)&Bs[wn * 64 + j * 16 + fm][fg * 8];
#pragma unroll
    for (int i = 0; i < 2; ++i)
#pragma unroll
      for (int j = 0; j < 4; ++j)
        acc[i][j] = __builtin_amdgcn_mfma_f32_16x16x32_f16(af[i], bf[j], acc[i][j], 0, 0, 0);
    __syncthreads();
  }
#pragma unroll
  for (int i = 0; i < 2; ++i) {
#pragma unroll
    for (int j = 0; j < 4; ++j) {
      int col = col0 + wn * 64 + j * 16 + fm;
      int rbase = row0 + wm * 32 + i * 16 + fg * 4;
#pragma unroll
      for (int r = 0; r < 4; ++r)
        Y[(size_t)(rbase + r) * Nc + col] = (_Float16)acc[i][j][r];
    }
  }
}

// ---------------- gate L0: zr = sigmoid([h1|x | Ah1|Ax] @ Wt + B); zh=z*h32; rbuf=r ----------------
__global__ __launch_bounds__(256) void gate0_kernel(
    const __half* __restrict__ h16, const __half* __restrict__ YA,   // A@h1 [1024][2048]
    const float* __restrict__ src, const __half* __restrict__ Axt, int tstep,
    const __half* __restrict__ Wtg, const float* __restrict__ Bg,
    const float* __restrict__ h32, __half* __restrict__ zh, float* __restrict__ rbuf) {
  constexpr int KIP = 160, STRIDE = 168;
  __shared__ __align__(16) _Float16 Xs[32 * STRIDE];
  int n = blockIdx.x;
  int t = threadIdx.x;
#pragma unroll
  for (int u = 0; u < 2; ++u) {           // 32 b x 2 parts x 8 chunks
    int idx = t + u * 256;
    int b = idx >> 4, part = (idx >> 3) & 1, ch = idx & 7;
    const _Float16* s = part ? (const _Float16*)YA + (size_t)n * 2048 + b * 64 + ch * 8
                             : (const _Float16*)h16 + (size_t)n * 2048 + b * 64 + ch * 8;
    *(f16x8*)&Xs[b * STRIDE + part * 80 + ch * 8] = *(const f16x8*)s;
  }
  if (t < 32) {                            // x_t and A@x_t (2 vals each)
    int b = t;
    float2 xv = *(const float2*)(src + ((size_t)(b * 12 + tstep) * 1024 + n) * 2);
    Xs[b * STRIDE + 64] = (_Float16)xv.x;
    Xs[b * STRIDE + 65] = (_Float16)xv.y;
    const _Float16* ax = (const _Float16*)Axt + (size_t)n * 768 + tstep * 64 + b * 2;
    Xs[b * STRIDE + 144] = ax[0];
    Xs[b * STRIDE + 145] = ax[1];
  }
  for (int idx = t; idx < 896; idx += 256) {  // zero pads j=66..79 both parts
    int b = idx / 28, jj = idx % 28;
    int col = (jj < 14) ? 66 + jj : 132 + jj;
    Xs[b * STRIDE + col] = (_Float16)0.f;
  }
  __syncthreads();
  int wave = t >> 6, lane = t & 63;
  int fm = lane & 15, fg = lane >> 4;
  f32x4 acc[2][2] = {};
  const _Float16* Wn = (const _Float16*)Wtg + ((size_t)n * 128 + wave * 32) * KIP;
#pragma unroll
  for (int kc = 0; kc < KIP / 32; ++kc) {
    f16x8 af[2], bf[2];
#pragma unroll
    for (int i = 0; i < 2; ++i)
      af[i] = *(const f16x8*)&Xs[(i * 16 + fm) * STRIDE + kc * 32 + fg * 8];
#pragma unroll
    for (int j = 0; j < 2; ++j)
      bf[j] = *(const f16x8*)(Wn + (size_t)(j * 16 + fm) * KIP + kc * 32 + fg * 8);
#pragma unroll
    for (int i = 0; i < 2; ++i)
#pragma unroll
      for (int j = 0; j < 2; ++j)
        acc[i][j] = __builtin_amdgcn_mfma_f32_16x16x32_f16(af[i], bf[j], acc[i][j], 0, 0, 0);
  }
  const float* Bn = Bg + n * 128;
#pragma unroll
  for (int j = 0; j < 2; ++j) {
    int o = wave * 32 + j * 16 + fm;
    float bias = Bn[o];
#pragma unroll
    for (int i = 0; i < 2; ++i)
#pragma unroll
      for (int r = 0; r < 4; ++r) {
        int b = i * 16 + fg * 4 + r;
        float s = 1.f / (1.f + __expf(-(acc[i][j][r] + bias)));
        size_t base = (size_t)n * 2048 + b * 64;
        if (o < 64) zh[base + o] = __float2half(s * h32[base + o]);
        else        rbuf[base + o - 64] = s;
      }
  }
}

// ---------------- upd L0: hc = tanh([zh|x | Azh|Ax] @ Wt + B); h = r*h + (1-r)*hc ----------------
__global__ __launch_bounds__(256) void upd0_kernel(
    const __half* __restrict__ zh, const __half* __restrict__ YZ,   // A@zh [1024][2048]
    const float* __restrict__ src, const __half* __restrict__ Axt, int tstep,
    const __half* __restrict__ Wtg, const float* __restrict__ Bu,
    const float* __restrict__ rbuf, float* __restrict__ h32, __half* __restrict__ h16) {
  constexpr int KIP = 160, STRIDE = 168;
  __shared__ __align__(16) _Float16 Xs[32 * STRIDE];
  int n = blockIdx.x;
  int t = threadIdx.x;
#pragma unroll
  for (int u = 0; u < 2; ++u) {
    int idx = t + u * 256;
    int b = idx >> 4, part = (idx >> 3) & 1, ch = idx & 7;
    const _Float16* s = part ? (const _Float16*)YZ + (size_t)n * 2048 + b * 64 + ch * 8
                             : (const _Float16*)zh + (size_t)n * 2048 + b * 64 + ch * 8;
    *(f16x8*)&Xs[b * STRIDE + part * 80 + ch * 8] = *(const f16x8*)s;
  }
  if (t < 32) {
    int b = t;
    float2 xv = *(const float2*)(src + ((size_t)(b * 12 + tstep) * 1024 + n) * 2);
    Xs[b * STRIDE + 64] = (_Float16)xv.x;
    Xs[b * STRIDE + 65] = (_Float16)xv.y;
    const _Float16* ax = (const _Float16*)Axt + (size_t)n * 768 + tstep * 64 + b * 2;
    Xs[b * STRIDE + 144] = ax[0];
    Xs[b * STRIDE + 145] = ax[1];
  }
  for (int idx = t; idx < 896; idx += 256) {
    int b = idx / 28, jj = idx % 28;
    int col = (jj < 14) ? 66 + jj : 132 + jj;
    Xs[b * STRIDE + col] = (_Float16)0.f;
  }
  __syncthreads();
  int wave = t >> 6, lane = t & 63;
  int fm = lane & 15, fg = lane >> 4;
  f32x4 acc[2] = {};
  const _Float16* Wn = (const _Float16*)Wtg + ((size_t)n * 64 + wave * 16) * KIP;
#pragma unroll
  for (int kc = 0; kc < KIP / 32; ++kc) {
    f16x8 bf = *(const f16x8*)(Wn + (size_t)fm * KIP + kc * 32 + fg * 8);
#pragma unroll
    for (int i = 0; i < 2; ++i) {
      f16x8 af = *(const f16x8*)&Xs[(i * 16 + fm) * STRIDE + kc * 32 + fg * 8];
      acc[i] = __builtin_amdgcn_mfma_f32_16x16x32_f16(af, bf, acc[i], 0, 0, 0);
    }
  }
  int o = wave * 16 + fm;
  float bias = Bu[n * 64 + o];
#pragma unroll
  for (int i = 0; i < 2; ++i)
#pragma unroll
    for (int r = 0; r < 4; ++r) {
      int b = i * 16 + fg * 4 + r;
      float x = acc[i][r] + bias;
      x = fminf(fmaxf(x, -15.f), 15.f);
      float e = __expf(2.f * x);
      float hc = (e - 1.f) / (e + 1.f);
      size_t base = (size_t)n * 2048 + b * 64;
      float rr = rbuf[base + o];
      float hnew = rr * h32[base + o] + (1.f - rr) * hc;
      h32[base + o] = hnew;
      h16[base + o] = __float2half(hnew);
    }
}

// ---------------- gate L1: zr = sigmoid([h1|h2 | Ah1|Ah2] @ Wt + B) ----------------
__global__ __launch_bounds__(256) void gate1_kernel(
    const __half* __restrict__ h1_16, const __half* __restrict__ h2_16,
    const __half* __restrict__ YA,   // A@[h1|h2]: [1024][4096]
    const __half* __restrict__ Wtg, const float* __restrict__ Bg,
    const float* __restrict__ h32, __half* __restrict__ zh, float* __restrict__ rbuf) {
  constexpr int KIP = 256, STRIDE = 264;
  __shared__ __align__(16) _Float16 Xs[32 * STRIDE];
  int n = blockIdx.x;
  int t = threadIdx.x;
#pragma unroll
  for (int u = 0; u < 4; ++u) {
    int idx = t + u * 256;
    int b = idx >> 5, q = idx & 31;
    const _Float16* s;
    if (q < 8)       s = (const _Float16*)h1_16 + (size_t)n * 2048 + b * 64 + q * 8;
    else if (q < 16) s = (const _Float16*)h2_16 + (size_t)n * 2048 + b * 64 + (q - 8) * 8;
    else if (q < 24) s = (const _Float16*)YA + (size_t)n * 4096 + b * 64 + (q - 16) * 8;
    else             s = (const _Float16*)YA + (size_t)n * 4096 + 2048 + b * 64 + (q - 24) * 8;
    *(f16x8*)&Xs[b * STRIDE + q * 8] = *(const f16x8*)s;
  }
  __syncthreads();
  int wave = t >> 6, lane = t & 63;
  int fm = lane & 15, fg = lane >> 4;
  f32x4 acc[2][2] = {};
  const _Float16* Wn = (const _Float16*)Wtg + ((size_t)n * 128 + wave * 32) * KIP;
#pragma unroll
  for (int kc = 0; kc < KIP / 32; ++kc) {
    f16x8 af[2], bf[2];
#pragma unroll
    for (int i = 0; i < 2; ++i)
      af[i] = *(const f16x8*)&Xs[(i * 16 + fm) * STRIDE + kc * 32 + fg * 8];
#pragma unroll
    for (int j = 0; j < 2; ++j)
      bf[j] = *(const f16x8*)(Wn + (size_t)(j * 16 + fm) * KIP + kc * 32 + fg * 8);
#pragma unroll
    for (int i = 0; i < 2; ++i)
#pragma unroll
      for (int j = 0; j < 2; ++j)
        acc[i][j] = __builtin_amdgcn_mfma_f32_16x16x32_f16(af[i], bf[j], acc[i][j], 0, 0, 0);
  }
  const float* Bn = Bg + n * 128;
#pragma unroll
  for (int j = 0; j < 2; ++j) {
    int o = wave * 32 + j * 16 + fm;
    float bias = Bn[o];
#pragma unroll
    for (int i = 0; i < 2; ++i)
#pragma unroll
      for (int r = 0; r < 4; ++r) {
        int b = i * 16 + fg * 4 + r;
        float s = 1.f / (1.f + __expf(-(acc[i][j][r] + bias)));
        size_t base = (size_t)n * 2048 + b * 64;
        if (o < 64) zh[base + o] = __float2half(s * h32[base + o]);
        else        rbuf[base + o - 64] = s;
      }
  }
}

// ---------------- upd L1: hc = tanh([h1|zh | Ah1|Azh] @ Wt + B); h2 = r*h2 + (1-r)*hc ----------------
__global__ __launch_bounds__(256) void upd1_kernel(
    const __half* __restrict__ h1_16, const __half* __restrict__ zh,
    const __half* __restrict__ YA,   // A@[h1|h2] (first half = A@h1, reused)
    const __half* __restrict__ YZ,   // A@zh [1024][2048]
    const __half* __restrict__ Wtg, const float* __restrict__ Bu,
    const float* __restrict__ rbuf, float* __restrict__ h32, __half* __restrict__ h16) {
  constexpr int KIP = 256, STRIDE = 264;
  __shared__ __align__(16) _Float16 Xs[32 * STRIDE];
  int n = blockIdx.x;
  int t = threadIdx.x;
#pragma unroll
  for (int u = 0; u < 4; ++u) {
    int idx = t + u * 256;
    int b = idx >> 5, q = idx & 31;
    const _Float16* s;
    if (q < 8)       s = (const _Float16*)h1_16 + (size_t)n * 2048 + b * 64 + q * 8;
    else if (q < 16) s = (const _Float16*)zh + (size_t)n * 2048 + b * 64 + (q - 8) * 8;
    else if (q < 24) s = (const _Float16*)YA + (size_t)n * 4096 + b * 64 + (q - 16) * 8;
    else             s = (const _Float16*)YZ + (size_t)n * 2048 + b * 64 + (q - 24) * 8;
    *(f16x8*)&Xs[b * STRIDE + q * 8] = *(const f16x8*)s;
  }
  __syncthreads();
  int wave = t >> 6, lane = t & 63;
  int fm = lane & 15, fg = lane >> 4;
  f32x4 acc[2] = {};
  const _Float16* Wn = (const _Float16*)Wtg + ((size_t)n * 64 + wave * 16) * KIP;
#pragma unroll
  for (int kc = 0; kc < KIP / 32; ++kc) {
    f16x8 bf = *(const f16x8*)(Wn + (size_t)fm * KIP + kc * 32 + fg * 8);
#pragma unroll
    for (int i = 0; i < 2; ++i) {
      f16x8 af = *(const f16x8*)&Xs[(i * 16 + fm) * STRIDE + kc * 32 + fg * 8];
      acc[i] = __builtin_amdgcn_mfma_f32_16x16x32_f16(af, bf, acc[i], 0, 0, 0);
    }
  }
  int o = wave * 16 + fm;
  float bias = Bu[n * 64 + o];
#pragma unroll
  for (int i = 0; i < 2; ++i)
#pragma unroll
    for (int r = 0; r < 4; ++r) {
      int b = i * 16 + fg * 4 + r;
      float x = acc[i][r] + bias;
      x = fminf(fmaxf(x, -15.f), 15.f);
      float e = __expf(2.f * x);
      float hc = (e - 1.f) / (e + 1.f);
      size_t base = (size_t)n * 2048 + b * 64;
      float rr = rbuf[base + o];
      float hnew = rr * h32[base + o] + (1.f - rr) * hc;
      h32[base + o] = hnew;
      h16[base + o] = __float2half(hnew);
    }
}

// ---------------- out[b,o,n] = h2[n,b,:] . conv_w[o,:] + conv_b[o] ----------------
__global__ void final_conv_kernel(const float* __restrict__ h2, const float* __restrict__ cw,
                                  const float* __restrict__ cb, float* __restrict__ out) {
  int tid = blockIdx.x * 256 + threadIdx.x;
  if (tid >= 32 * 1024) return;
  int n = tid & 1023, b = tid >> 10;
  const float* hp = h2 + ((size_t)n * 32 + b) * 64;
  float hv[64];
#pragma unroll
  for (int i = 0; i < 64; ++i) hv[i] = hp[i];
#pragma unroll
  for (int o = 0; o < 12; ++o) {
    float acc = cb[o];
#pragma unroll
    for (int i = 0; i < 64; ++i) acc += hv[i] * cw[o * 64 + i];
    out[((size_t)b * 12 + o) * 1024 + n] = acc;
  }
}

extern "C" void kernel_launch(void* const* d_in, const int* in_sizes, int n_in,
                              void* d_out, int out_size, void* d_ws, size_t ws_size,
                              hipStream_t stream) {
  const float* src = (const float*)d_in[0];
  const float* E   = (const float*)d_in[1];
  const float* gw0 = (const float*)d_in[2];
  const float* gb0 = (const float*)d_in[3];
  const float* uw0 = (const float*)d_in[4];
  const float* ub0 = (const float*)d_in[5];
  const float* gw1 = (const float*)d_in[6];
  const float* gb1 = (const float*)d_in[7];
  const float* uw1 = (const float*)d_in[8];
  const float* ub1 = (const float*)d_in[9];
  const float* cw  = (const float*)d_in[10];
  const float* cb  = (const float*)d_in[11];
  float* out = (float*)d_out;
  (void)in_sizes; (void)n_in; (void)out_size; (void)ws_size;

  char* base = (char*)d_ws;
  size_t off = 0;
  auto alloc = [&](size_t bytes) -> void* {
    void* p = base + off; off += (bytes + 511) & ~(size_t)511; return p;
  };
  __half* Ah   = (__half*)alloc((size_t)1024 * 1024 * 2);           //   2.1 MB
  __half* WtG0 = (__half*)alloc((size_t)1024 * 128 * 160 * 2);      //  41.9 MB
  __half* WtU0 = (__half*)alloc((size_t)1024 * 64 * 160 * 2);       //  21.0 MB
  __half* WtG1 = (__half*)alloc((size_t)1024 * 128 * 256 * 2);      //  67.1 MB
  __half* WtU1 = (__half*)alloc((size_t)1024 * 64 * 256 * 2);       //  33.6 MB
  float*  Bg0  = (float*) alloc((size_t)1024 * 128 * 4);
  float*  Bu0  = (float*) alloc((size_t)1024 * 64 * 4);
  float*  Bg1  = (float*) alloc((size_t)1024 * 128 * 4);
  float*  Bu1  = (float*) alloc((size_t)1024 * 64 * 4);
  float*  h1_32 = (float*)alloc((size_t)1024 * 2048 * 4);           //   8.4 MB
  float*  h2_32 = (float*)alloc((size_t)1024 * 2048 * 4);           //   8.4 MB
  __half* h1_16 = (__half*)alloc((size_t)1024 * 2048 * 2);          //   4.2 MB
  __half* h2_16 = (__half*)alloc((size_t)1024 * 2048 * 2);          //   4.2 MB
  __half* zh   = (__half*)alloc((size_t)1024 * 2048 * 2);           //   4.2 MB
  __half* YA0  = (__half*)alloc((size_t)1024 * 2048 * 2);           //   4.2 MB (A@h1, L0)
  __half* YA1  = (__half*)alloc((size_t)1024 * 4096 * 2);           //   8.4 MB (A@[h1|h2], L1)
  __half* YZ   = (__half*)alloc((size_t)1024 * 2048 * 2);           //   4.2 MB (A@zh)
  __half* XT   = (__half*)alloc((size_t)4096 * 1024 * 2);           //   8.4 MB (transposed B)
  __half* Axt  = (__half*)alloc((size_t)1024 * 768 * 2);            //   1.5 MB (A@x all t)
  float*  rbuf = (float*) alloc((size_t)1024 * 2048 * 4);           //   8.4 MB (also prelude scratch)
  float*  poolT = rbuf;                                             //  2.1 MB, prelude-only
  __half* xT   = (__half*)(rbuf + (size_t)1024 * 1024);             //  1.5 MB, prelude-only
  // total ~232 MB

  // ---- prelude ----
  compute_A_kernel<<<1024, 256, 0, stream>>>(E, Ah);
  auto mwt = [&](const float* pool, __half* Wt, int F, int Fp, int O) {
    int KIp = 2 * Fp;
    int total = 16 * O * KIp;
    pool_transpose_kernel<<<(total + 255) / 256, 256, 0, stream>>>(pool, poolT, F, Fp, O);
    make_wt_kernel<<<dim3(O, 16), 256, 0, stream>>>(E, poolT, Wt, O, KIp);
  };
  mwt(gw0, WtG0, 66, 80, 128);
  mwt(uw0, WtU0, 66, 80, 64);
  mwt(gw1, WtG1, 128, 128, 128);
  mwt(uw1, WtU1, 128, 128, 64);
  auto mb = [&](const float* pool, float* Bo, int O) {
    make_b_kernel<<<(1024 * O + 255) / 256, 256, 0, stream>>>(E, pool, Bo, O);
  };
  mb(gb0, Bg0, 128); mb(ub0, Bu0, 64); mb(gb1, Bg1, 128); mb(ub1, Bu1, 64);
  build_xt_kernel<<<384, 256, 0, stream>>>(src, xT);
  gemm_mfma_kernel<<<dim3(768 / 128, 16), 256, 0, stream>>>(Ah, xT, Axt, 768);
  zero_kernel<<<(6291456 + 255) / 256, 256, 0, stream>>>(h1_32, 6291456);  // h32 x2 + h16 x2

  // ---- 12 GRU steps ----
  for (int t = 0; t < 12; ++t) {
    // layer 0
    t16_kernel<<<dim3(32, 16), 256, 0, stream>>>(h1_16, XT);
    gemm_mfma_kernel<<<dim3(16, 16), 256, 0, stream>>>(Ah, XT, YA0, 2048);
    gate0_kernel<<<1024, 256, 0, stream>>>(h1_16, YA0, src, Axt, t, WtG0, Bg0, h1_32, zh, rbuf);
    t16_kernel<<<dim3(32, 16), 256, 0, stream>>>(zh, XT);
    gemm_mfma_kernel<<<dim3(16, 16), 256, 0, stream>>>(Ah, XT, YZ, 2048);
    upd0_kernel<<<1024, 256, 0, stream>>>(zh, YZ, src, Axt, t, WtU0, Bu0, rbuf, h1_32, h1_16);
    // layer 1
    t16_kernel<<<dim3(32, 16), 256, 0, stream>>>(h1_16, XT);
    t16_kernel<<<dim3(32, 16), 256, 0, stream>>>(h2_16, XT + (size_t)2048 * 1024);
    gemm_mfma_kernel<<<dim3(32, 16), 256, 0, stream>>>(Ah, XT, YA1, 4096);
    gate1_kernel<<<1024, 256, 0, stream>>>(h1_16, h2_16, YA1, WtG1, Bg1, h2_32, zh, rbuf);
    t16_kernel<<<dim3(32, 16), 256, 0, stream>>>(zh, XT);
    gemm_mfma_kernel<<<dim3(16, 16), 256, 0, stream>>>(Ah, XT, YZ, 2048);
    upd1_kernel<<<1024, 256, 0, stream>>>(h1_16, zh, YA1, YZ, WtU1, Bu1, rbuf, h2_32, h2_16);
  }

  final_conv_kernel<<<(32 * 1024 + 255) / 256, 256, 0, stream>>>(h2_32, cw, cb, out);
}

// Round 5
// 1724.568 us; speedup vs baseline: 3.9087x; 1.1926x over previous
//
#include <hip/hip_runtime.h>
#include <hip/hip_fp16.h>

// AGCRN: B=32 T=12 N=1024 C=2 D=16 H=64 K=2 OUT=12
// Node-major activations [n][(b,f)], fp16 on all GEMM paths; h fp32 master + fp16 mirror.
// Per step (3 A-GEMMs, A@h1 computed once and reused across gate1/upd1/next-step gate0):
//   gate0 -> t16_dual(zh0,h2) -> gemm128(A@[zh0|h2], 4096) -> upd0 ->
//   t16(h1) -> gemm64(A@h1, 2048 -> YB) -> gate1 -> t16(zh1) -> gemm64(A@zh1 -> YC) -> upd1

typedef _Float16 f16x8 __attribute__((ext_vector_type(8)));
typedef float f32x4 __attribute__((ext_vector_type(4)));

// ---------------- A = softmax(relu(E E^T)) -> fp16 ----------------
__global__ __launch_bounds__(256) void compute_A_kernel(const float* __restrict__ E,
                                                        __half* __restrict__ Ah) {
  int n = blockIdx.x;
  int tid = threadIdx.x;
  __shared__ float red[256];
  float en[16];
#pragma unroll
  for (int d = 0; d < 16; ++d) en[d] = E[n * 16 + d];
  float v[4];
#pragma unroll
  for (int q = 0; q < 4; ++q) {
    int m = tid + q * 256;
    const float* Em = E + m * 16;
    float dot = 0.f;
#pragma unroll
    for (int d = 0; d < 16; ++d) dot += en[d] * Em[d];
    v[q] = fmaxf(dot, 0.f);
  }
  float mx = fmaxf(fmaxf(v[0], v[1]), fmaxf(v[2], v[3]));
  red[tid] = mx; __syncthreads();
  for (int s = 128; s > 0; s >>= 1) { if (tid < s) red[tid] = fmaxf(red[tid], red[tid + s]); __syncthreads(); }
  mx = red[0];
  __syncthreads();
  float e[4], sum = 0.f;
#pragma unroll
  for (int q = 0; q < 4; ++q) { e[q] = expf(v[q] - mx); sum += e[q]; }
  red[tid] = sum; __syncthreads();
  for (int s = 128; s > 0; s >>= 1) { if (tid < s) red[tid] += red[tid + s]; __syncthreads(); }
  float inv = 1.f / red[0];
#pragma unroll
  for (int q = 0; q < 4; ++q) Ah[(size_t)n * 1024 + tid + q * 256] = __float2half(e[q] * inv);
}

// ---------------- poolT[d][o][kip]: permuted/padded K-contiguous pool ----------------
__global__ void pool_transpose_kernel(const float* __restrict__ pool, float* __restrict__ poolT,
                                      int F, int Fp, int O) {
  int KIp = 2 * Fp;
  int total = 16 * O * KIp;
  int t = blockIdx.x * 256 + threadIdx.x;
  if (t >= total) return;
  int kip = t % KIp;
  int rest = t / KIp;
  int o = rest % O;
  int d = rest / O;
  int kk = (kip >= Fp) ? 1 : 0;
  int j = kip - kk * Fp;
  int i;
  if (F == Fp) i = j;
  else i = (j < 64) ? j + 2 : (j < 66 ? j - 64 : -1);
  poolT[t] = (i >= 0) ? pool[(((size_t)d * 2 + kk) * F + i) * O + o] : 0.f;
}

// ---------------- Wt[n][o][ki] = sum_d E[n,d] poolT[d][o][ki], fp16 ----------------
__global__ __launch_bounds__(256) void make_wt_kernel(const float* __restrict__ E,
                                                      const float* __restrict__ poolT,
                                                      __half* __restrict__ Wt,
                                                      int O, int KIp) {
  __shared__ float pl[16 * 256];
  __shared__ float Es[64 * 17];
  int o = blockIdx.x;
  int n0 = blockIdx.y * 64;
  int q = KIp >> 2;
  for (int idx = threadIdx.x; idx < 4 * KIp; idx += 256) {
    int d = idx / q;
    int k4 = (idx - d * q) * 4;
    float4 v = *(const float4*)(poolT + ((size_t)d * O + o) * KIp + k4);
    *(float4*)&pl[d * KIp + k4] = v;
  }
  {
    int nl = threadIdx.x >> 2, d0 = (threadIdx.x & 3) * 4;
    float4 v = *(const float4*)(E + (size_t)(n0 + nl) * 16 + d0);
    Es[nl * 17 + d0 + 0] = v.x; Es[nl * 17 + d0 + 1] = v.y;
    Es[nl * 17 + d0 + 2] = v.z; Es[nl * 17 + d0 + 3] = v.w;
  }
  __syncthreads();
  int nl = threadIdx.x & 63, kq = threadIdx.x >> 6;
  int k0 = kq * q;
  float e[16];
#pragma unroll
  for (int d = 0; d < 16; ++d) e[d] = Es[nl * 17 + d];
  __half* orow = Wt + ((size_t)(n0 + nl) * O + o) * KIp + k0;
  for (int kk = 0; kk < q; kk += 8) {
    float a[8];
#pragma unroll
    for (int j = 0; j < 8; ++j) {
      float s = 0.f;
#pragma unroll
      for (int d = 0; d < 16; ++d) s += e[d] * pl[d * KIp + k0 + kk + j];
      a[j] = s;
    }
    float4 pk;
    __half2* ph = (__half2*)&pk;
    ph[0] = __floats2half2_rn(a[0], a[1]);
    ph[1] = __floats2half2_rn(a[2], a[3]);
    ph[2] = __floats2half2_rn(a[4], a[5]);
    ph[3] = __floats2half2_rn(a[6], a[7]);
    *(float4*)(orow + kk) = pk;
  }
}

// ---------------- per-node bias ----------------
__global__ void make_b_kernel(const float* __restrict__ E, const float* __restrict__ pool,
                              float* __restrict__ Bout, int O) {
  int tid = blockIdx.x * 256 + threadIdx.x;
  if (tid >= 1024 * O) return;
  int n = tid / O, o = tid % O;
  const float* En = E + n * 16;
  float a = 0.f;
#pragma unroll
  for (int d = 0; d < 16; ++d) a += En[d] * pool[d * O + o];
  Bout[tid] = a;
}

__global__ void zero_kernel(float* __restrict__ p, int count) {
  int i = blockIdx.x * 256 + threadIdx.x;
  if (i < count) p[i] = 0.f;
}

// ---------------- xT[(t*32+b)*2+cc][n] = src[b][t][n][cc], fp16 ----------------
__global__ void build_xt_kernel(const float* __restrict__ src, __half* __restrict__ xT) {
  int bid = blockIdx.x; int t = bid >> 5, b = bid & 31;
  const float* s = src + (size_t)(b * 12 + t) * 2048;
  __half* o0 = xT + (size_t)(t * 64 + b * 2) * 1024;
  for (int n = threadIdx.x; n < 1024; n += 256) {
    float2 v = *(const float2*)(s + n * 2);
    o0[n] = __float2half(v.x);
    o0[1024 + n] = __float2half(v.y);
  }
}

// ---------------- transpose fp16: X[1024][2048] -> XT[2048][1024] ----------------
__global__ __launch_bounds__(256) void t16_kernel(const __half* __restrict__ Xg,
                                                  __half* __restrict__ XTg) {
  __shared__ __align__(16) _Float16 T[64][72];
  const _Float16* X = (const _Float16*)Xg;
  _Float16* XT = (_Float16*)XTg;
  int c0 = blockIdx.x * 64;
  int m0 = blockIdx.y * 64;
  int t = threadIdx.x;
#pragma unroll
  for (int u = 0; u < 2; ++u) {
    int idx = t + u * 256;
    int r = idx >> 3, ch = idx & 7;
    f16x8 v = *(const f16x8*)(X + (size_t)(m0 + r) * 2048 + c0 + ch * 8);
#pragma unroll
    for (int j = 0; j < 8; ++j) T[ch * 8 + j][r] = v[j];
  }
  __syncthreads();
#pragma unroll
  for (int u = 0; u < 2; ++u) {
    int idx = t + u * 256;
    int r = idx >> 3, ch = idx & 7;
    *(f16x8*)(XT + (size_t)(c0 + r) * 1024 + m0 + ch * 8) = *(const f16x8*)&T[r][ch * 8];
  }
}

// ---------------- dual transpose: [Xa | Xb] (each [1024][2048]) -> XT[4096][1024] ----------------
__global__ __launch_bounds__(256) void t16_dual_kernel(const __half* __restrict__ Xag,
                                                       const __half* __restrict__ Xbg,
                                                       __half* __restrict__ XTg) {
  __shared__ __align__(16) _Float16 T[64][72];
  int bx = blockIdx.x;
  const _Float16* X;
  int c0, drow;
  if (bx < 32) { X = (const _Float16*)Xag; c0 = bx * 64; drow = c0; }
  else         { X = (const _Float16*)Xbg; c0 = (bx - 32) * 64; drow = 2048 + c0; }
  _Float16* XT = (_Float16*)XTg;
  int m0 = blockIdx.y * 64;
  int t = threadIdx.x;
#pragma unroll
  for (int u = 0; u < 2; ++u) {
    int idx = t + u * 256;
    int r = idx >> 3, ch = idx & 7;
    f16x8 v = *(const f16x8*)(X + (size_t)(m0 + r) * 2048 + c0 + ch * 8);
#pragma unroll
    for (int j = 0; j < 8; ++j) T[ch * 8 + j][r] = v[j];
  }
  __syncthreads();
#pragma unroll
  for (int u = 0; u < 2; ++u) {
    int idx = t + u * 256;
    int r = idx >> 3, ch = idx & 7;
    *(f16x8*)(XT + (size_t)(drow + r) * 1024 + m0 + ch * 8) = *(const f16x8*)&T[r][ch * 8];
  }
}

// ---------------- gemm128: Y[1024 x Nc] = Ah @ B, tile 64x128 (for Nc>=4096 and prelude) ----------------
__global__ __launch_bounds__(256) void gemm_mfma_kernel(const __half* __restrict__ Ahg,
                                                        const __half* __restrict__ Xtg,
                                                        __half* __restrict__ Yg, int Nc) {
  __shared__ __align__(16) _Float16 As[64][40];
  __shared__ __align__(16) _Float16 Bs[128][40];
  const _Float16* __restrict__ Ah = (const _Float16*)Ahg;
  const _Float16* __restrict__ Xt = (const _Float16*)Xtg;
  _Float16* __restrict__ Y = (_Float16*)Yg;
  int tid = threadIdx.x;
  int row0 = blockIdx.y * 64;
  int col0 = blockIdx.x * 128;
  int wave = tid >> 6, lane = tid & 63;
  int wm = wave & 1, wn = wave >> 1;
  int fm = lane & 15, fg = lane >> 4;

  f32x4 acc[2][4] = {};
  int ar = tid >> 2, aq = (tid & 3) * 8;
  for (int k0 = 0; k0 < 1024; k0 += 32) {
    *(float4*)&As[ar][aq] = *(const float4*)(Ah + (size_t)(row0 + ar) * 1024 + k0 + aq);
#pragma unroll
    for (int u = 0; u < 2; ++u) {
      int idx = tid + u * 256;
      int br = idx >> 2, bq = (idx & 3) * 8;
      *(float4*)&Bs[br][bq] = *(const float4*)(Xt + (size_t)(col0 + br) * 1024 + k0 + bq);
    }
    __syncthreads();
    f16x8 af[2], bf[4];
#pragma unroll
    for (int i = 0; i < 2; ++i)
      af[i] = *(const f16x8*)&As[wm * 32 + i * 16 + fm][fg * 8];
#pragma unroll
    for (int j = 0; j < 4; ++j)
      bf[j] = *(const f16x8*)&Bs[wn * 64 + j * 16 + fm][fg * 8];
#pragma unroll
    for (int i = 0; i < 2; ++i)
#pragma unroll
      for (int j = 0; j < 4; ++j)
        acc[i][j] = __builtin_amdgcn_mfma_f32_16x16x32_f16(af[i], bf[j], acc[i][j], 0, 0, 0);
    __syncthreads();
  }
#pragma unroll
  for (int i = 0; i < 2; ++i) {
#pragma unroll
    for (int j = 0; j < 4; ++j) {
      int col = col0 + wn * 64 + j * 16 + fm;
      int rbase = row0 + wm * 32 + i * 16 + fg * 4;
#pragma unroll
      for (int r = 0; r < 4; ++r)
        Y[(size_t)(rbase + r) * Nc + col] = (_Float16)acc[i][j][r];
    }
  }
}

// ---------------- gemm64: Y[1024 x 2048] = Ah @ B, tile 64x64 (512 blocks, 2/CU) ----------------
__global__ __launch_bounds__(256) void gemm64_kernel(const __half* __restrict__ Ahg,
                                                     const __half* __restrict__ Xtg,
                                                     __half* __restrict__ Yg) {
  constexpr int Nc = 2048;
  __shared__ __align__(16) _Float16 As[64][40];
  __shared__ __align__(16) _Float16 Bs[64][40];
  const _Float16* __restrict__ Ah = (const _Float16*)Ahg;
  const _Float16* __restrict__ Xt = (const _Float16*)Xtg;
  _Float16* __restrict__ Y = (_Float16*)Yg;
  int tid = threadIdx.x;
  int row0 = blockIdx.y * 64;
  int col0 = blockIdx.x * 64;
  int wave = tid >> 6, lane = tid & 63;
  int wm = wave & 1, wn = wave >> 1;
  int fm = lane & 15, fg = lane >> 4;

  f32x4 acc[2][2] = {};
  int ar = tid >> 2, aq = (tid & 3) * 8;
  for (int k0 = 0; k0 < 1024; k0 += 32) {
    *(float4*)&As[ar][aq] = *(const float4*)(Ah + (size_t)(row0 + ar) * 1024 + k0 + aq);
    *(float4*)&Bs[ar][aq] = *(const float4*)(Xt + (size_t)(col0 + ar) * 1024 + k0 + aq);
    __syncthreads();
    f16x8 af[2], bf[2];
#pragma unroll
    for (int i = 0; i < 2; ++i)
      af[i] = *(const f16x8*)&As[wm * 32 + i * 16 + fm][fg * 8];
#pragma unroll
    for (int j = 0; j < 2; ++j)
      bf[j] = *(const f16x8*)&Bs[wn * 32 + j * 16 + fm][fg * 8];
#pragma unroll
    for (int i = 0; i < 2; ++i)
#pragma unroll
      for (int j = 0; j < 2; ++j)
        acc[i][j] = __builtin_amdgcn_mfma_f32_16x16x32_f16(af[i], bf[j], acc[i][j], 0, 0, 0);
    __syncthreads();
  }
#pragma unroll
  for (int i = 0; i < 2; ++i) {
#pragma unroll
    for (int j = 0; j < 2; ++j) {
      int col = col0 + wn * 32 + j * 16 + fm;
      int rbase = row0 + wm * 32 + i * 16 + fg * 4;
#pragma unroll
      for (int r = 0; r < 4; ++r)
        Y[(size_t)(rbase + r) * Nc + col] = (_Float16)acc[i][j][r];
    }
  }
}

// ---------------- gate L0: zr = sigmoid([h1|x | Ah1|Ax] @ Wt + B); zh=z*h32; rbuf=r ----------------
__global__ __launch_bounds__(256) void gate0_kernel(
    const __half* __restrict__ h16, const __half* __restrict__ YB,   // A@h1 [1024][2048]
    const float* __restrict__ src, const __half* __restrict__ Axt, int tstep,
    const __half* __restrict__ Wtg, const float* __restrict__ Bg,
    const float* __restrict__ h32, __half* __restrict__ zh, float* __restrict__ rbuf) {
  constexpr int KIP = 160, STRIDE = 168;
  __shared__ __align__(16) _Float16 Xs[32 * STRIDE];
  int n = blockIdx.x;
  int t = threadIdx.x;
#pragma unroll
  for (int u = 0; u < 2; ++u) {
    int idx = t + u * 256;
    int b = idx >> 4, part = (idx >> 3) & 1, ch = idx & 7;
    const _Float16* s = part ? (const _Float16*)YB + (size_t)n * 2048 + b * 64 + ch * 8
                             : (const _Float16*)h16 + (size_t)n * 2048 + b * 64 + ch * 8;
    *(f16x8*)&Xs[b * STRIDE + part * 80 + ch * 8] = *(const f16x8*)s;
  }
  if (t < 32) {
    int b = t;
    float2 xv = *(const float2*)(src + ((size_t)(b * 12 + tstep) * 1024 + n) * 2);
    Xs[b * STRIDE + 64] = (_Float16)xv.x;
    Xs[b * STRIDE + 65] = (_Float16)xv.y;
    const _Float16* ax = (const _Float16*)Axt + (size_t)n * 768 + tstep * 64 + b * 2;
    Xs[b * STRIDE + 144] = ax[0];
    Xs[b * STRIDE + 145] = ax[1];
  }
  for (int idx = t; idx < 896; idx += 256) {
    int b = idx / 28, jj = idx % 28;
    int col = (jj < 14) ? 66 + jj : 132 + jj;
    Xs[b * STRIDE + col] = (_Float16)0.f;
  }
  __syncthreads();
  int wave = t >> 6, lane = t & 63;
  int fm = lane & 15, fg = lane >> 4;
  f32x4 acc[2][2] = {};
  const _Float16* Wn = (const _Float16*)Wtg + ((size_t)n * 128 + wave * 32) * KIP;
#pragma unroll
  for (int kc = 0; kc < KIP / 32; ++kc) {
    f16x8 af[2], bf[2];
#pragma unroll
    for (int i = 0; i < 2; ++i)
      af[i] = *(const f16x8*)&Xs[(i * 16 + fm) * STRIDE + kc * 32 + fg * 8];
#pragma unroll
    for (int j = 0; j < 2; ++j)
      bf[j] = *(const f16x8*)(Wn + (size_t)(j * 16 + fm) * KIP + kc * 32 + fg * 8);
#pragma unroll
    for (int i = 0; i < 2; ++i)
#pragma unroll
      for (int j = 0; j < 2; ++j)
        acc[i][j] = __builtin_amdgcn_mfma_f32_16x16x32_f16(af[i], bf[j], acc[i][j], 0, 0, 0);
  }
  const float* Bn = Bg + n * 128;
#pragma unroll
  for (int j = 0; j < 2; ++j) {
    int o = wave * 32 + j * 16 + fm;
    float bias = Bn[o];
#pragma unroll
    for (int i = 0; i < 2; ++i)
#pragma unroll
      for (int r = 0; r < 4; ++r) {
        int b = i * 16 + fg * 4 + r;
        float s = 1.f / (1.f + __expf(-(acc[i][j][r] + bias)));
        size_t base = (size_t)n * 2048 + b * 64;
        if (o < 64) zh[base + o] = __float2half(s * h32[base + o]);
        else        rbuf[base + o - 64] = s;
      }
  }
}

// ---------------- upd L0: hc = tanh([zh|x | Azh|Ax] @ Wt + B); h = r*h + (1-r)*hc ----------------
// A@zh comes from YA2 first half (row stride 4096).
__global__ __launch_bounds__(256) void upd0_kernel(
    const __half* __restrict__ zh, const __half* __restrict__ YA2,
    const float* __restrict__ src, const __half* __restrict__ Axt, int tstep,
    const __half* __restrict__ Wtg, const float* __restrict__ Bu,
    const float* __restrict__ rbuf, float* __restrict__ h32, __half* __restrict__ h16) {
  constexpr int KIP = 160, STRIDE = 168;
  __shared__ __align__(16) _Float16 Xs[32 * STRIDE];
  int n = blockIdx.x;
  int t = threadIdx.x;
#pragma unroll
  for (int u = 0; u < 2; ++u) {
    int idx = t + u * 256;
    int b = idx >> 4, part = (idx >> 3) & 1, ch = idx & 7;
    const _Float16* s = part ? (const _Float16*)YA2 + (size_t)n * 4096 + b * 64 + ch * 8
                             : (const _Float16*)zh + (size_t)n * 2048 + b * 64 + ch * 8;
    *(f16x8*)&Xs[b * STRIDE + part * 80 + ch * 8] = *(const f16x8*)s;
  }
  if (t < 32) {
    int b = t;
    float2 xv = *(const float2*)(src + ((size_t)(b * 12 + tstep) * 1024 + n) * 2);
    Xs[b * STRIDE + 64] = (_Float16)xv.x;
    Xs[b * STRIDE + 65] = (_Float16)xv.y;
    const _Float16* ax = (const _Float16*)Axt + (size_t)n * 768 + tstep * 64 + b * 2;
    Xs[b * STRIDE + 144] = ax[0];
    Xs[b * STRIDE + 145] = ax[1];
  }
  for (int idx = t; idx < 896; idx += 256) {
    int b = idx / 28, jj = idx % 28;
    int col = (jj < 14) ? 66 + jj : 132 + jj;
    Xs[b * STRIDE + col] = (_Float16)0.f;
  }
  __syncthreads();
  int wave = t >> 6, lane = t & 63;
  int fm = lane & 15, fg = lane >> 4;
  f32x4 acc[2] = {};
  const _Float16* Wn = (const _Float16*)Wtg + ((size_t)n * 64 + wave * 16) * KIP;
#pragma unroll
  for (int kc = 0; kc < KIP / 32; ++kc) {
    f16x8 bf = *(const f16x8*)(Wn + (size_t)fm * KIP + kc * 32 + fg * 8);
#pragma unroll
    for (int i = 0; i < 2; ++i) {
      f16x8 af = *(const f16x8*)&Xs[(i * 16 + fm) * STRIDE + kc * 32 + fg * 8];
      acc[i] = __builtin_amdgcn_mfma_f32_16x16x32_f16(af, bf, acc[i], 0, 0, 0);
    }
  }
  int o = wave * 16 + fm;
  float bias = Bu[n * 64 + o];
#pragma unroll
  for (int i = 0; i < 2; ++i)
#pragma unroll
    for (int r = 0; r < 4; ++r) {
      int b = i * 16 + fg * 4 + r;
      float x = acc[i][r] + bias;
      x = fminf(fmaxf(x, -15.f), 15.f);
      float e = __expf(2.f * x);
      float hc = (e - 1.f) / (e + 1.f);
      size_t base = (size_t)n * 2048 + b * 64;
      float rr = rbuf[base + o];
      float hnew = rr * h32[base + o] + (1.f - rr) * hc;
      h32[base + o] = hnew;
      h16[base + o] = __float2half(hnew);
    }
}

// ---------------- gate L1: zr = sigmoid([h1|h2 | Ah1|Ah2] @ Wt + B) ----------------
// A@h1 = YB [1024][2048]; A@h2 = YA2 second half (stride 4096, offset 2048).
__global__ __launch_bounds__(256) void gate1_kernel(
    const __half* __restrict__ h1_16, const __half* __restrict__ h2_16,
    const __half* __restrict__ YB, const __half* __restrict__ YA2,
    const __half* __restrict__ Wtg, const float* __restrict__ Bg,
    const float* __restrict__ h32, __half* __restrict__ zh, float* __restrict__ rbuf) {
  constexpr int KIP = 256, STRIDE = 264;
  __shared__ __align__(16) _Float16 Xs[32 * STRIDE];
  int n = blockIdx.x;
  int t = threadIdx.x;
#pragma unroll
  for (int u = 0; u < 4; ++u) {
    int idx = t + u * 256;
    int b = idx >> 5, q = idx & 31;
    const _Float16* s;
    if (q < 8)       s = (const _Float16*)h1_16 + (size_t)n * 2048 + b * 64 + q * 8;
    else if (q < 16) s = (const _Float16*)h2_16 + (size_t)n * 2048 + b * 64 + (q - 8) * 8;
    else if (q < 24) s = (const _Float16*)YB + (size_t)n * 2048 + b * 64 + (q - 16) * 8;
    else             s = (const _Float16*)YA2 + (size_t)n * 4096 + 2048 + b * 64 + (q - 24) * 8;
    *(f16x8*)&Xs[b * STRIDE + q * 8] = *(const f16x8*)s;
  }
  __syncthreads();
  int wave = t >> 6, lane = t & 63;
  int fm = lane & 15, fg = lane >> 4;
  f32x4 acc[2][2] = {};
  const _Float16* Wn = (const _Float16*)Wtg + ((size_t)n * 128 + wave * 32) * KIP;
#pragma unroll
  for (int kc = 0; kc < KIP / 32; ++kc) {
    f16x8 af[2], bf[2];
#pragma unroll
    for (int i = 0; i < 2; ++i)
      af[i] = *(const f16x8*)&Xs[(i * 16 + fm) * STRIDE + kc * 32 + fg * 8];
#pragma unroll
    for (int j = 0; j < 2; ++j)
      bf[j] = *(const f16x8*)(Wn + (size_t)(j * 16 + fm) * KIP + kc * 32 + fg * 8);
#pragma unroll
    for (int i = 0; i < 2; ++i)
#pragma unroll
      for (int j = 0; j < 2; ++j)
        acc[i][j] = __builtin_amdgcn_mfma_f32_16x16x32_f16(af[i], bf[j], acc[i][j], 0, 0, 0);
  }
  const float* Bn = Bg + n * 128;
#pragma unroll
  for (int j = 0; j < 2; ++j) {
    int o = wave * 32 + j * 16 + fm;
    float bias = Bn[o];
#pragma unroll
    for (int i = 0; i < 2; ++i)
#pragma unroll
      for (int r = 0; r < 4; ++r) {
        int b = i * 16 + fg * 4 + r;
        float s = 1.f / (1.f + __expf(-(acc[i][j][r] + bias)));
        size_t base = (size_t)n * 2048 + b * 64;
        if (o < 64) zh[base + o] = __float2half(s * h32[base + o]);
        else        rbuf[base + o - 64] = s;
      }
  }
}

// ---------------- upd L1: hc = tanh([h1|zh | Ah1|Azh] @ Wt + B); h2 = r*h2 + (1-r)*hc ----------------
__global__ __launch_bounds__(256) void upd1_kernel(
    const __half* __restrict__ h1_16, const __half* __restrict__ zh,
    const __half* __restrict__ YB, const __half* __restrict__ YC,
    const __half* __restrict__ Wtg, const float* __restrict__ Bu,
    const float* __restrict__ rbuf, float* __restrict__ h32, __half* __restrict__ h16) {
  constexpr int KIP = 256, STRIDE = 264;
  __shared__ __align__(16) _Float16 Xs[32 * STRIDE];
  int n = blockIdx.x;
  int t = threadIdx.x;
#pragma unroll
  for (int u = 0; u < 4; ++u) {
    int idx = t + u * 256;
    int b = idx >> 5, q = idx & 31;
    const _Float16* s;
    if (q < 8)       s = (const _Float16*)h1_16 + (size_t)n * 2048 + b * 64 + q * 8;
    else if (q < 16) s = (const _Float16*)zh + (size_t)n * 2048 + b * 64 + (q - 8) * 8;
    else if (q < 24) s = (const _Float16*)YB + (size_t)n * 2048 + b * 64 + (q - 16) * 8;
    else             s = (const _Float16*)YC + (size_t)n * 2048 + b * 64 + (q - 24) * 8;
    *(f16x8*)&Xs[b * STRIDE + q * 8] = *(const f16x8*)s;
  }
  __syncthreads();
  int wave = t >> 6, lane = t & 63;
  int fm = lane & 15, fg = lane >> 4;
  f32x4 acc[2] = {};
  const _Float16* Wn = (const _Float16*)Wtg + ((size_t)n * 64 + wave * 16) * KIP;
#pragma unroll
  for (int kc = 0; kc < KIP / 32; ++kc) {
    f16x8 bf = *(const f16x8*)(Wn + (size_t)fm * KIP + kc * 32 + fg * 8);
#pragma unroll
    for (int i = 0; i < 2; ++i) {
      f16x8 af = *(const f16x8*)&Xs[(i * 16 + fm) * STRIDE + kc * 32 + fg * 8];
      acc[i] = __builtin_amdgcn_mfma_f32_16x16x32_f16(af, bf, acc[i], 0, 0, 0);
    }
  }
  int o = wave * 16 + fm;
  float bias = Bu[n * 64 + o];
#pragma unroll
  for (int i = 0; i < 2; ++i)
#pragma unroll
    for (int r = 0; r < 4; ++r) {
      int b = i * 16 + fg * 4 + r;
      float x = acc[i][r] + bias;
      x = fminf(fmaxf(x, -15.f), 15.f);
      float e = __expf(2.f * x);
      float hc = (e - 1.f) / (e + 1.f);
      size_t base = (size_t)n * 2048 + b * 64;
      float rr = rbuf[base + o];
      float hnew = rr * h32[base + o] + (1.f - rr) * hc;
      h32[base + o] = hnew;
      h16[base + o] = __float2half(hnew);
    }
}

// ---------------- out[b,o,n] = h2[n,b,:] . conv_w[o,:] + conv_b[o] ----------------
__global__ void final_conv_kernel(const float* __restrict__ h2, const float* __restrict__ cw,
                                  const float* __restrict__ cb, float* __restrict__ out) {
  int tid = blockIdx.x * 256 + threadIdx.x;
  if (tid >= 32 * 1024) return;
  int n = tid & 1023, b = tid >> 10;
  const float* hp = h2 + ((size_t)n * 32 + b) * 64;
  float hv[64];
#pragma unroll
  for (int i = 0; i < 64; ++i) hv[i] = hp[i];
#pragma unroll
  for (int o = 0; o < 12; ++o) {
    float acc = cb[o];
#pragma unroll
    for (int i = 0; i < 64; ++i) acc += hv[i] * cw[o * 64 + i];
    out[((size_t)b * 12 + o) * 1024 + n] = acc;
  }
}

extern "C" void kernel_launch(void* const* d_in, const int* in_sizes, int n_in,
                              void* d_out, int out_size, void* d_ws, size_t ws_size,
                              hipStream_t stream) {
  const float* src = (const float*)d_in[0];
  const float* E   = (const float*)d_in[1];
  const float* gw0 = (const float*)d_in[2];
  const float* gb0 = (const float*)d_in[3];
  const float* uw0 = (const float*)d_in[4];
  const float* ub0 = (const float*)d_in[5];
  const float* gw1 = (const float*)d_in[6];
  const float* gb1 = (const float*)d_in[7];
  const float* uw1 = (const float*)d_in[8];
  const float* ub1 = (const float*)d_in[9];
  const float* cw  = (const float*)d_in[10];
  const float* cb  = (const float*)d_in[11];
  float* out = (float*)d_out;
  (void)in_sizes; (void)n_in; (void)out_size; (void)ws_size;

  char* base = (char*)d_ws;
  size_t off = 0;
  auto alloc = [&](size_t bytes) -> void* {
    void* p = base + off; off += (bytes + 511) & ~(size_t)511; return p;
  };
  __half* Ah   = (__half*)alloc((size_t)1024 * 1024 * 2);           //   2.1 MB
  __half* WtG0 = (__half*)alloc((size_t)1024 * 128 * 160 * 2);      //  41.9 MB
  __half* WtU0 = (__half*)alloc((size_t)1024 * 64 * 160 * 2);       //  21.0 MB
  __half* WtG1 = (__half*)alloc((size_t)1024 * 128 * 256 * 2);      //  67.1 MB
  __half* WtU1 = (__half*)alloc((size_t)1024 * 64 * 256 * 2);       //  33.6 MB
  float*  Bg0  = (float*) alloc((size_t)1024 * 128 * 4);
  float*  Bu0  = (float*) alloc((size_t)1024 * 64 * 4);
  float*  Bg1  = (float*) alloc((size_t)1024 * 128 * 4);
  float*  Bu1  = (float*) alloc((size_t)1024 * 64 * 4);
  // zero-initialized region (contiguous): h1_32, h2_32, h1_16, h2_16, YB
  float*  h1_32 = (float*)alloc((size_t)1024 * 2048 * 4);           //   8.4 MB
  float*  h2_32 = (float*)alloc((size_t)1024 * 2048 * 4);           //   8.4 MB
  __half* h1_16 = (__half*)alloc((size_t)1024 * 2048 * 2);          //   4.2 MB
  __half* h2_16 = (__half*)alloc((size_t)1024 * 2048 * 2);          //   4.2 MB
  __half* YB   = (__half*)alloc((size_t)1024 * 2048 * 2);           //   4.2 MB (A@h1)
  __half* zh   = (__half*)alloc((size_t)1024 * 2048 * 2);           //   4.2 MB
  __half* YA2  = (__half*)alloc((size_t)1024 * 4096 * 2);           //   8.4 MB ([A@zh0 | A@h2])
  __half* YC   = (__half*)alloc((size_t)1024 * 2048 * 2);           //   4.2 MB (A@zh1)
  __half* XT   = (__half*)alloc((size_t)4096 * 1024 * 2);           //   8.4 MB (transposed B)
  __half* Axt  = (__half*)alloc((size_t)1024 * 768 * 2);            //   1.5 MB (A@x all t)
  float*  rbuf = (float*) alloc((size_t)1024 * 2048 * 4);           //   8.4 MB (+ prelude scratch)
  float*  poolT = rbuf;
  __half* xT   = (__half*)(rbuf + (size_t)1024 * 1024);
  // total ~229 MB

  // ---- prelude ----
  compute_A_kernel<<<1024, 256, 0, stream>>>(E, Ah);
  auto mwt = [&](const float* pool, __half* Wt, int F, int Fp, int O) {
    int KIp = 2 * Fp;
    int total = 16 * O * KIp;
    pool_transpose_kernel<<<(total + 255) / 256, 256, 0, stream>>>(pool, poolT, F, Fp, O);
    make_wt_kernel<<<dim3(O, 16), 256, 0, stream>>>(E, poolT, Wt, O, KIp);
  };
  mwt(gw0, WtG0, 66, 80, 128);
  mwt(uw0, WtU0, 66, 80, 64);
  mwt(gw1, WtG1, 128, 128, 128);
  mwt(uw1, WtU1, 128, 128, 64);
  auto mb = [&](const float* pool, float* Bo, int O) {
    make_b_kernel<<<(1024 * O + 255) / 256, 256, 0, stream>>>(E, pool, Bo, O);
  };
  mb(gb0, Bg0, 128); mb(ub0, Bu0, 64); mb(gb1, Bg1, 128); mb(ub1, Bu1, 64);
  build_xt_kernel<<<384, 256, 0, stream>>>(src, xT);
  gemm_mfma_kernel<<<dim3(768 / 128, 16), 256, 0, stream>>>(Ah, xT, Axt, 768);
  // zero h1_32,h2_32,h1_16,h2_16,YB (contiguous, 29.4 MB = 7340032 float-units)
  zero_kernel<<<(7340032 + 255) / 256, 256, 0, stream>>>(h1_32, 7340032);

  // ---- 12 GRU steps (3 A-GEMMs/step; A@h1 computed once, reused) ----
  for (int t = 0; t < 12; ++t) {
    gate0_kernel<<<1024, 256, 0, stream>>>(h1_16, YB, src, Axt, t, WtG0, Bg0, h1_32, zh, rbuf);
    t16_dual_kernel<<<dim3(64, 16), 256, 0, stream>>>(zh, h2_16, XT);
    gemm_mfma_kernel<<<dim3(32, 16), 256, 0, stream>>>(Ah, XT, YA2, 4096);
    upd0_kernel<<<1024, 256, 0, stream>>>(zh, YA2, src, Axt, t, WtU0, Bu0, rbuf, h1_32, h1_16);
    t16_kernel<<<dim3(32, 16), 256, 0, stream>>>(h1_16, XT);
    gemm64_kernel<<<dim3(32, 16), 256, 0, stream>>>(Ah, XT, YB);
    gate1_kernel<<<1024, 256, 0, stream>>>(h1_16, h2_16, YB, YA2, WtG1, Bg1, h2_32, zh, rbuf);
    t16_kernel<<<dim3(32, 16), 256, 0, stream>>>(zh, XT);
    gemm64_kernel<<<dim3(32, 16), 256, 0, stream>>>(Ah, XT, YC);
    upd1_kernel<<<1024, 256, 0, stream>>>(h1_16, zh, YB, YC, WtU1, Bu1, rbuf, h2_32, h2_16);
  }

  final_conv_kernel<<<(32 * 1024 + 255) / 256, 256, 0, stream>>>(h2_32, cw, cb, out);
}

// Round 6
// 1571.831 us; speedup vs baseline: 4.2886x; 1.0972x over previous
//
#include <hip/hip_runtime.h>
#include <hip/hip_fp16.h>

// AGCRN: B=32 T=12 N=1024 C=2 D=16 H=64 K=2 OUT=12
// Node-major activations [n][(b,f)], fp16 on all GEMM paths; h fp32 master + fp16 mirror.
// Per step (3 A-GEMMs; A@h1 computed once, reused by gate1/upd1/next gate0):
//   gate0 -> t16_dual(zh0,h2) -> gemm(A@[zh0|h2],4096) -> upd0 ->
//   t16(h1) -> gemm(A@h1 -> YB) -> gate1 -> t16(zh1) -> gemm(A@zh1 -> YC) -> upd1
// gemm_db: reg-double-buffered K-loop (K=64/stage, prefetch overlaps compute).

typedef _Float16 f16x8 __attribute__((ext_vector_type(8)));
typedef float f32x4 __attribute__((ext_vector_type(4)));

// ---------------- A = softmax(relu(E E^T)) -> fp16 ----------------
__global__ __launch_bounds__(256) void compute_A_kernel(const float* __restrict__ E,
                                                        __half* __restrict__ Ah) {
  int n = blockIdx.x;
  int tid = threadIdx.x;
  __shared__ float red[256];
  float en[16];
#pragma unroll
  for (int d = 0; d < 16; ++d) en[d] = E[n * 16 + d];
  float v[4];
#pragma unroll
  for (int q = 0; q < 4; ++q) {
    int m = tid + q * 256;
    const float* Em = E + m * 16;
    float dot = 0.f;
#pragma unroll
    for (int d = 0; d < 16; ++d) dot += en[d] * Em[d];
    v[q] = fmaxf(dot, 0.f);
  }
  float mx = fmaxf(fmaxf(v[0], v[1]), fmaxf(v[2], v[3]));
  red[tid] = mx; __syncthreads();
  for (int s = 128; s > 0; s >>= 1) { if (tid < s) red[tid] = fmaxf(red[tid], red[tid + s]); __syncthreads(); }
  mx = red[0];
  __syncthreads();
  float e[4], sum = 0.f;
#pragma unroll
  for (int q = 0; q < 4; ++q) { e[q] = expf(v[q] - mx); sum += e[q]; }
  red[tid] = sum; __syncthreads();
  for (int s = 128; s > 0; s >>= 1) { if (tid < s) red[tid] += red[tid + s]; __syncthreads(); }
  float inv = 1.f / red[0];
#pragma unroll
  for (int q = 0; q < 4; ++q) Ah[(size_t)n * 1024 + tid + q * 256] = __float2half(e[q] * inv);
}

// ---------------- merged poolT: 4 segments, permuted/padded K-contiguous ----------------
// seg sizes (floats): G0 16*128*160=327680, U0 16*64*160=163840, G1 16*128*256=524288, U1 16*64*256=262144
__global__ void pool_transpose_all_kernel(const float* __restrict__ gw0, const float* __restrict__ uw0,
                                          const float* __restrict__ gw1, const float* __restrict__ uw1,
                                          float* __restrict__ poolT) {
  int t = blockIdx.x * 256 + threadIdx.x;
  if (t >= 1277952) return;
  const float* pool; int F, Fp, O, loc;
  if (t < 327680)       { pool = gw0; F = 66;  Fp = 80;  O = 128; loc = t; }
  else if (t < 491520)  { pool = uw0; F = 66;  Fp = 80;  O = 64;  loc = t - 327680; }
  else if (t < 1015808) { pool = gw1; F = 128; Fp = 128; O = 128; loc = t - 491520; }
  else                  { pool = uw1; F = 128; Fp = 128; O = 64;  loc = t - 1015808; }
  int KIp = 2 * Fp;
  int kip = loc % KIp;
  int rest = loc / KIp;
  int o = rest % O;
  int d = rest / O;
  int kk = (kip >= Fp) ? 1 : 0;
  int j = kip - kk * Fp;
  int i;
  if (F == Fp) i = j;
  else i = (j < 64) ? j + 2 : (j < 66 ? j - 64 : -1);
  poolT[t] = (i >= 0) ? pool[(((size_t)d * 2 + kk) * F + i) * O + o] : 0.f;
}

// ---------------- merged Wt builder: LDS-bounce for coalesced writes ----------------
// grid (384, 16): bx segment -> (o, O, KIp, poolT seg, Wt dst); by = 64-node group.
__global__ __launch_bounds__(256) void make_wt_all_kernel(
    const float* __restrict__ E, const float* __restrict__ poolT,
    __half* __restrict__ WtG0, __half* __restrict__ WtU0,
    __half* __restrict__ WtG1, __half* __restrict__ WtU1) {
  __shared__ float pl[16 * 256];
  __shared__ float Es[64 * 17];
  __shared__ __align__(16) _Float16 wbuf[64][264];
  int bx = blockIdx.x;
  int o, O, KIp; const float* pt; __half* Wt;
  if (bx < 128)      { o = bx;       O = 128; KIp = 160; pt = poolT;           Wt = WtG0; }
  else if (bx < 192) { o = bx - 128; O = 64;  KIp = 160; pt = poolT + 327680;  Wt = WtU0; }
  else if (bx < 320) { o = bx - 192; O = 128; KIp = 256; pt = poolT + 491520;  Wt = WtG1; }
  else               { o = bx - 320; O = 64;  KIp = 256; pt = poolT + 1015808; Wt = WtU1; }
  int n0 = blockIdx.y * 64;
  int q = KIp >> 2;
  for (int idx = threadIdx.x; idx < 4 * KIp; idx += 256) {
    int d = idx / q;
    int k4 = (idx - d * q) * 4;
    float4 v = *(const float4*)(pt + ((size_t)d * O + o) * KIp + k4);
    *(float4*)&pl[d * KIp + k4] = v;
  }
  {
    int nl = threadIdx.x >> 2, d0 = (threadIdx.x & 3) * 4;
    float4 v = *(const float4*)(E + (size_t)(n0 + nl) * 16 + d0);
    Es[nl * 17 + d0 + 0] = v.x; Es[nl * 17 + d0 + 1] = v.y;
    Es[nl * 17 + d0 + 2] = v.z; Es[nl * 17 + d0 + 3] = v.w;
  }
  __syncthreads();
  int nl = threadIdx.x & 63, kq = threadIdx.x >> 6;
  int k0 = kq * q;
  float e[16];
#pragma unroll
  for (int d = 0; d < 16; ++d) e[d] = Es[nl * 17 + d];
  for (int kk = 0; kk < q; kk += 8) {
    float a[8];
#pragma unroll
    for (int j = 0; j < 8; ++j) {
      float s = 0.f;
#pragma unroll
      for (int d = 0; d < 16; ++d) s += e[d] * pl[d * KIp + k0 + kk + j];
      a[j] = s;
    }
    f16x8 pk;
#pragma unroll
    for (int j = 0; j < 8; ++j) pk[j] = (_Float16)a[j];
    *(f16x8*)&wbuf[nl][k0 + kk] = pk;
  }
  __syncthreads();
  // coalesced write phase: node rows are KIp-contiguous in Wt
  int chunks = KIp >> 3;                  // f16x8 chunks per node row
  int tot = 64 * chunks;
  for (int idx = threadIdx.x; idx < tot; idx += 256) {
    int nsub = idx / chunks;
    int pos = (idx - nsub * chunks) * 8;
    *(float4*)(Wt + ((size_t)(n0 + nsub) * O + o) * KIp + pos) = *(float4*)&wbuf[nsub][pos];
  }
}

// ---------------- merged per-node biases ----------------
__global__ void make_b_all_kernel(const float* __restrict__ E,
                                  const float* __restrict__ gb0, const float* __restrict__ ub0,
                                  const float* __restrict__ gb1, const float* __restrict__ ub1,
                                  float* __restrict__ Bg0, float* __restrict__ Bu0,
                                  float* __restrict__ Bg1, float* __restrict__ Bu1) {
  int tid = blockIdx.x * 256 + threadIdx.x;
  if (tid >= 1024 * 384) return;
  int n = tid / 384, c = tid - n * 384;
  const float* pool; float* outp; int O, o;
  if (c < 128)      { pool = gb0; outp = Bg0; O = 128; o = c; }
  else if (c < 192) { pool = ub0; outp = Bu0; O = 64;  o = c - 128; }
  else if (c < 320) { pool = gb1; outp = Bg1; O = 128; o = c - 192; }
  else              { pool = ub1; outp = Bu1; O = 64;  o = c - 320; }
  const float* En = E + n * 16;
  float a = 0.f;
#pragma unroll
  for (int d = 0; d < 16; ++d) a += En[d] * pool[d * O + o];
  outp[n * O + o] = a;
}

__global__ void zero_kernel(float* __restrict__ p, int count) {
  int i = blockIdx.x * 256 + threadIdx.x;
  if (i < count) p[i] = 0.f;
}

// ---------------- xT[(t*32+b)*2+cc][n] = src[b][t][n][cc], fp16 ----------------
__global__ void build_xt_kernel(const float* __restrict__ src, __half* __restrict__ xT) {
  int bid = blockIdx.x; int t = bid >> 5, b = bid & 31;
  const float* s = src + (size_t)(b * 12 + t) * 2048;
  __half* o0 = xT + (size_t)(t * 64 + b * 2) * 1024;
  for (int n = threadIdx.x; n < 1024; n += 256) {
    float2 v = *(const float2*)(s + n * 2);
    o0[n] = __float2half(v.x);
    o0[1024 + n] = __float2half(v.y);
  }
}

// ---------------- transpose fp16: X[1024][2048] -> XT[2048][1024] ----------------
__global__ __launch_bounds__(256) void t16_kernel(const __half* __restrict__ Xg,
                                                  __half* __restrict__ XTg) {
  __shared__ __align__(16) _Float16 T[64][72];
  const _Float16* X = (const _Float16*)Xg;
  _Float16* XT = (_Float16*)XTg;
  int c0 = blockIdx.x * 64;
  int m0 = blockIdx.y * 64;
  int t = threadIdx.x;
#pragma unroll
  for (int u = 0; u < 2; ++u) {
    int idx = t + u * 256;
    int r = idx >> 3, ch = idx & 7;
    f16x8 v = *(const f16x8*)(X + (size_t)(m0 + r) * 2048 + c0 + ch * 8);
#pragma unroll
    for (int j = 0; j < 8; ++j) T[ch * 8 + j][r] = v[j];
  }
  __syncthreads();
#pragma unroll
  for (int u = 0; u < 2; ++u) {
    int idx = t + u * 256;
    int r = idx >> 3, ch = idx & 7;
    *(f16x8*)(XT + (size_t)(c0 + r) * 1024 + m0 + ch * 8) = *(const f16x8*)&T[r][ch * 8];
  }
}

// ---------------- dual transpose: [Xa | Xb] (each [1024][2048]) -> XT[4096][1024] ----------------
__global__ __launch_bounds__(256) void t16_dual_kernel(const __half* __restrict__ Xag,
                                                       const __half* __restrict__ Xbg,
                                                       __half* __restrict__ XTg) {
  __shared__ __align__(16) _Float16 T[64][72];
  int bx = blockIdx.x;
  const _Float16* X;
  int c0, drow;
  if (bx < 32) { X = (const _Float16*)Xag; c0 = bx * 64; drow = c0; }
  else         { X = (const _Float16*)Xbg; c0 = (bx - 32) * 64; drow = 2048 + c0; }
  _Float16* XT = (_Float16*)XTg;
  int m0 = blockIdx.y * 64;
  int t = threadIdx.x;
#pragma unroll
  for (int u = 0; u < 2; ++u) {
    int idx = t + u * 256;
    int r = idx >> 3, ch = idx & 7;
    f16x8 v = *(const f16x8*)(X + (size_t)(m0 + r) * 2048 + c0 + ch * 8);
#pragma unroll
    for (int j = 0; j < 8; ++j) T[ch * 8 + j][r] = v[j];
  }
  __syncthreads();
#pragma unroll
  for (int u = 0; u < 2; ++u) {
    int idx = t + u * 256;
    int r = idx >> 3, ch = idx & 7;
    *(f16x8*)(XT + (size_t)(drow + r) * 1024 + m0 + ch * 8) = *(const f16x8*)&T[r][ch * 8];
  }
}

// ---------------- gemm_db: Y[1024 x Nc] = Ah @ B, 64x64 tile, reg-double-buffered K=64 stages ----
__global__ __launch_bounds__(256) void gemm_db_kernel(const __half* __restrict__ Ahg,
                                                      const __half* __restrict__ Xtg,
                                                      __half* __restrict__ Yg, int Nc) {
  __shared__ __align__(16) _Float16 As[64][72];
  __shared__ __align__(16) _Float16 Bs[64][72];
  const _Float16* __restrict__ Ah = (const _Float16*)Ahg;
  const _Float16* __restrict__ Xt = (const _Float16*)Xtg;
  _Float16* __restrict__ Y = (_Float16*)Yg;
  int tid = threadIdx.x;
  int row0 = blockIdx.y * 64;
  int col0 = blockIdx.x * 64;
  int wave = tid >> 6, lane = tid & 63;
  int wm = wave & 1, wn = wave >> 1;
  int fm = lane & 15, fg = lane >> 4;

  int sr = tid >> 2;            // staging row 0..63
  int sc = (tid & 3) * 16;      // staging col (halves)
  const _Float16* pa = Ah + (size_t)(row0 + sr) * 1024 + sc;
  const _Float16* pb = Xt + (size_t)(col0 + sr) * 1024 + sc;

  // stage-0 prefetch
  f16x8 ra0 = *(const f16x8*)(pa);
  f16x8 ra1 = *(const f16x8*)(pa + 8);
  f16x8 rb0 = *(const f16x8*)(pb);
  f16x8 rb1 = *(const f16x8*)(pb + 8);

  f32x4 acc[2][2] = {};
  for (int k0 = 0; k0 < 1024; k0 += 64) {
    *(f16x8*)&As[sr][sc] = ra0;
    *(f16x8*)&As[sr][sc + 8] = ra1;
    *(f16x8*)&Bs[sr][sc] = rb0;
    *(f16x8*)&Bs[sr][sc + 8] = rb1;
    __syncthreads();
    if (k0 + 64 < 1024) {       // prefetch next stage; latency overlaps compute below
      ra0 = *(const f16x8*)(pa + k0 + 64);
      ra1 = *(const f16x8*)(pa + k0 + 72);
      rb0 = *(const f16x8*)(pb + k0 + 64);
      rb1 = *(const f16x8*)(pb + k0 + 72);
    }
#pragma unroll
    for (int kc = 0; kc < 2; ++kc) {
      f16x8 af[2], bf[2];
#pragma unroll
      for (int i = 0; i < 2; ++i)
        af[i] = *(const f16x8*)&As[wm * 32 + i * 16 + fm][kc * 32 + fg * 8];
#pragma unroll
      for (int j = 0; j < 2; ++j)
        bf[j] = *(const f16x8*)&Bs[wn * 32 + j * 16 + fm][kc * 32 + fg * 8];
#pragma unroll
      for (int i = 0; i < 2; ++i)
#pragma unroll
        for (int j = 0; j < 2; ++j)
          acc[i][j] = __builtin_amdgcn_mfma_f32_16x16x32_f16(af[i], bf[j], acc[i][j], 0, 0, 0);
    }
    __syncthreads();
  }
#pragma unroll
  for (int i = 0; i < 2; ++i) {
#pragma unroll
    for (int j = 0; j < 2; ++j) {
      int col = col0 + wn * 32 + j * 16 + fm;
      int rbase = row0 + wm * 32 + i * 16 + fg * 4;
#pragma unroll
      for (int r = 0; r < 4; ++r)
        Y[(size_t)(rbase + r) * Nc + col] = (_Float16)acc[i][j][r];
    }
  }
}

// ---------------- gate L0: zr = sigmoid([h1|x | Ah1|Ax] @ Wt + B); zh=z*h32; rbuf=r ----------------
__global__ __launch_bounds__(256) void gate0_kernel(
    const __half* __restrict__ h16, const __half* __restrict__ YB,
    const float* __restrict__ src, const __half* __restrict__ Axt, int tstep,
    const __half* __restrict__ Wtg, const float* __restrict__ Bg,
    const float* __restrict__ h32, __half* __restrict__ zh, float* __restrict__ rbuf) {
  constexpr int KIP = 160, STRIDE = 168;
  __shared__ __align__(16) _Float16 Xs[32 * STRIDE];
  int n = blockIdx.x;
  int t = threadIdx.x;
#pragma unroll
  for (int u = 0; u < 2; ++u) {
    int idx = t + u * 256;
    int b = idx >> 4, part = (idx >> 3) & 1, ch = idx & 7;
    const _Float16* s = part ? (const _Float16*)YB + (size_t)n * 2048 + b * 64 + ch * 8
                             : (const _Float16*)h16 + (size_t)n * 2048 + b * 64 + ch * 8;
    *(f16x8*)&Xs[b * STRIDE + part * 80 + ch * 8] = *(const f16x8*)s;
  }
  if (t < 32) {
    int b = t;
    float2 xv = *(const float2*)(src + ((size_t)(b * 12 + tstep) * 1024 + n) * 2);
    Xs[b * STRIDE + 64] = (_Float16)xv.x;
    Xs[b * STRIDE + 65] = (_Float16)xv.y;
    const _Float16* ax = (const _Float16*)Axt + (size_t)n * 768 + tstep * 64 + b * 2;
    Xs[b * STRIDE + 144] = ax[0];
    Xs[b * STRIDE + 145] = ax[1];
  }
  for (int idx = t; idx < 896; idx += 256) {
    int b = idx / 28, jj = idx % 28;
    int col = (jj < 14) ? 66 + jj : 132 + jj;
    Xs[b * STRIDE + col] = (_Float16)0.f;
  }
  __syncthreads();
  int wave = t >> 6, lane = t & 63;
  int fm = lane & 15, fg = lane >> 4;
  f32x4 acc[2][2] = {};
  const _Float16* Wn = (const _Float16*)Wtg + ((size_t)n * 128 + wave * 32) * KIP;
#pragma unroll
  for (int kc = 0; kc < KIP / 32; ++kc) {
    f16x8 af[2], bf[2];
#pragma unroll
    for (int i = 0; i < 2; ++i)
      af[i] = *(const f16x8*)&Xs[(i * 16 + fm) * STRIDE + kc * 32 + fg * 8];
#pragma unroll
    for (int j = 0; j < 2; ++j)
      bf[j] = *(const f16x8*)(Wn + (size_t)(j * 16 + fm) * KIP + kc * 32 + fg * 8);
#pragma unroll
    for (int i = 0; i < 2; ++i)
#pragma unroll
      for (int j = 0; j < 2; ++j)
        acc[i][j] = __builtin_amdgcn_mfma_f32_16x16x32_f16(af[i], bf[j], acc[i][j], 0, 0, 0);
  }
  const float* Bn = Bg + n * 128;
#pragma unroll
  for (int j = 0; j < 2; ++j) {
    int o = wave * 32 + j * 16 + fm;
    float bias = Bn[o];
#pragma unroll
    for (int i = 0; i < 2; ++i)
#pragma unroll
      for (int r = 0; r < 4; ++r) {
        int b = i * 16 + fg * 4 + r;
        float s = 1.f / (1.f + __expf(-(acc[i][j][r] + bias)));
        size_t base = (size_t)n * 2048 + b * 64;
        if (o < 64) zh[base + o] = __float2half(s * h32[base + o]);
        else        rbuf[base + o - 64] = s;
      }
  }
}

// ---------------- upd L0: hc = tanh([zh|x | Azh|Ax] @ Wt + B); h = r*h + (1-r)*hc ----------------
__global__ __launch_bounds__(256) void upd0_kernel(
    const __half* __restrict__ zh, const __half* __restrict__ YA2,
    const float* __restrict__ src, const __half* __restrict__ Axt, int tstep,
    const __half* __restrict__ Wtg, const float* __restrict__ Bu,
    const float* __restrict__ rbuf, float* __restrict__ h32, __half* __restrict__ h16) {
  constexpr int KIP = 160, STRIDE = 168;
  __shared__ __align__(16) _Float16 Xs[32 * STRIDE];
  int n = blockIdx.x;
  int t = threadIdx.x;
#pragma unroll
  for (int u = 0; u < 2; ++u) {
    int idx = t + u * 256;
    int b = idx >> 4, part = (idx >> 3) & 1, ch = idx & 7;
    const _Float16* s = part ? (const _Float16*)YA2 + (size_t)n * 4096 + b * 64 + ch * 8
                             : (const _Float16*)zh + (size_t)n * 2048 + b * 64 + ch * 8;
    *(f16x8*)&Xs[b * STRIDE + part * 80 + ch * 8] = *(const f16x8*)s;
  }
  if (t < 32) {
    int b = t;
    float2 xv = *(const float2*)(src + ((size_t)(b * 12 + tstep) * 1024 + n) * 2);
    Xs[b * STRIDE + 64] = (_Float16)xv.x;
    Xs[b * STRIDE + 65] = (_Float16)xv.y;
    const _Float16* ax = (const _Float16*)Axt + (size_t)n * 768 + tstep * 64 + b * 2;
    Xs[b * STRIDE + 144] = ax[0];
    Xs[b * STRIDE + 145] = ax[1];
  }
  for (int idx = t; idx < 896; idx += 256) {
    int b = idx / 28, jj = idx % 28;
    int col = (jj < 14) ? 66 + jj : 132 + jj;
    Xs[b * STRIDE + col] = (_Float16)0.f;
  }
  __syncthreads();
  int wave = t >> 6, lane = t & 63;
  int fm = lane & 15, fg = lane >> 4;
  f32x4 acc[2] = {};
  const _Float16* Wn = (const _Float16*)Wtg + ((size_t)n * 64 + wave * 16) * KIP;
#pragma unroll
  for (int kc = 0; kc < KIP / 32; ++kc) {
    f16x8 bf = *(const f16x8*)(Wn + (size_t)fm * KIP + kc * 32 + fg * 8);
#pragma unroll
    for (int i = 0; i < 2; ++i) {
      f16x8 af = *(const f16x8*)&Xs[(i * 16 + fm) * STRIDE + kc * 32 + fg * 8];
      acc[i] = __builtin_amdgcn_mfma_f32_16x16x32_f16(af, bf, acc[i], 0, 0, 0);
    }
  }
  int o = wave * 16 + fm;
  float bias = Bu[n * 64 + o];
#pragma unroll
  for (int i = 0; i < 2; ++i)
#pragma unroll
    for (int r = 0; r < 4; ++r) {
      int b = i * 16 + fg * 4 + r;
      float x = acc[i][r] + bias;
      x = fminf(fmaxf(x, -15.f), 15.f);
      float e = __expf(2.f * x);
      float hc = (e - 1.f) / (e + 1.f);
      size_t base = (size_t)n * 2048 + b * 64;
      float rr = rbuf[base + o];
      float hnew = rr * h32[base + o] + (1.f - rr) * hc;
      h32[base + o] = hnew;
      h16[base + o] = __float2half(hnew);
    }
}

// ---------------- gate L1: zr = sigmoid([h1|h2 | Ah1|Ah2] @ Wt + B) ----------------
__global__ __launch_bounds__(256) void gate1_kernel(
    const __half* __restrict__ h1_16, const __half* __restrict__ h2_16,
    const __half* __restrict__ YB, const __half* __restrict__ YA2,
    const __half* __restrict__ Wtg, const float* __restrict__ Bg,
    const float* __restrict__ h32, __half* __restrict__ zh, float* __restrict__ rbuf) {
  constexpr int KIP = 256, STRIDE = 264;
  __shared__ __align__(16) _Float16 Xs[32 * STRIDE];
  int n = blockIdx.x;
  int t = threadIdx.x;
#pragma unroll
  for (int u = 0; u < 4; ++u) {
    int idx = t + u * 256;
    int b = idx >> 5, q = idx & 31;
    const _Float16* s;
    if (q < 8)       s = (const _Float16*)h1_16 + (size_t)n * 2048 + b * 64 + q * 8;
    else if (q < 16) s = (const _Float16*)h2_16 + (size_t)n * 2048 + b * 64 + (q - 8) * 8;
    else if (q < 24) s = (const _Float16*)YB + (size_t)n * 2048 + b * 64 + (q - 16) * 8;
    else             s = (const _Float16*)YA2 + (size_t)n * 4096 + 2048 + b * 64 + (q - 24) * 8;
    *(f16x8*)&Xs[b * STRIDE + q * 8] = *(const f16x8*)s;
  }
  __syncthreads();
  int wave = t >> 6, lane = t & 63;
  int fm = lane & 15, fg = lane >> 4;
  f32x4 acc[2][2] = {};
  const _Float16* Wn = (const _Float16*)Wtg + ((size_t)n * 128 + wave * 32) * KIP;
#pragma unroll
  for (int kc = 0; kc < KIP / 32; ++kc) {
    f16x8 af[2], bf[2];
#pragma unroll
    for (int i = 0; i < 2; ++i)
      af[i] = *(const f16x8*)&Xs[(i * 16 + fm) * STRIDE + kc * 32 + fg * 8];
#pragma unroll
    for (int j = 0; j < 2; ++j)
      bf[j] = *(const f16x8*)(Wn + (size_t)(j * 16 + fm) * KIP + kc * 32 + fg * 8);
#pragma unroll
    for (int i = 0; i < 2; ++i)
#pragma unroll
      for (int j = 0; j < 2; ++j)
        acc[i][j] = __builtin_amdgcn_mfma_f32_16x16x32_f16(af[i], bf[j], acc[i][j], 0, 0, 0);
  }
  const float* Bn = Bg + n * 128;
#pragma unroll
  for (int j = 0; j < 2; ++j) {
    int o = wave * 32 + j * 16 + fm;
    float bias = Bn[o];
#pragma unroll
    for (int i = 0; i < 2; ++i)
#pragma unroll
      for (int r = 0; r < 4; ++r) {
        int b = i * 16 + fg * 4 + r;
        float s = 1.f / (1.f + __expf(-(acc[i][j][r] + bias)));
        size_t base = (size_t)n * 2048 + b * 64;
        if (o < 64) zh[base + o] = __float2half(s * h32[base + o]);
        else        rbuf[base + o - 64] = s;
      }
  }
}

// ---------------- upd L1: hc = tanh([h1|zh | Ah1|Azh] @ Wt + B); h2 = r*h2 + (1-r)*hc ----------------
__global__ __launch_bounds__(256) void upd1_kernel(
    const __half* __restrict__ h1_16, const __half* __restrict__ zh,
    const __half* __restrict__ YB, const __half* __restrict__ YC,
    const __half* __restrict__ Wtg, const float* __restrict__ Bu,
    const float* __restrict__ rbuf, float* __restrict__ h32, __half* __restrict__ h16) {
  constexpr int KIP = 256, STRIDE = 264;
  __shared__ __align__(16) _Float16 Xs[32 * STRIDE];
  int n = blockIdx.x;
  int t = threadIdx.x;
#pragma unroll
  for (int u = 0; u < 4; ++u) {
    int idx = t + u * 256;
    int b = idx >> 5, q = idx & 31;
    const _Float16* s;
    if (q < 8)       s = (const _Float16*)h1_16 + (size_t)n * 2048 + b * 64 + q * 8;
    else if (q < 16) s = (const _Float16*)zh + (size_t)n * 2048 + b * 64 + (q - 8) * 8;
    else if (q < 24) s = (const _Float16*)YB + (size_t)n * 2048 + b * 64 + (q - 16) * 8;
    else             s = (const _Float16*)YC + (size_t)n * 2048 + b * 64 + (q - 24) * 8;
    *(f16x8*)&Xs[b * STRIDE + q * 8] = *(const f16x8*)s;
  }
  __syncthreads();
  int wave = t >> 6, lane = t & 63;
  int fm = lane & 15, fg = lane >> 4;
  f32x4 acc[2] = {};
  const _Float16* Wn = (const _Float16*)Wtg + ((size_t)n * 64 + wave * 16) * KIP;
#pragma unroll
  for (int kc = 0; kc < KIP / 32; ++kc) {
    f16x8 bf = *(const f16x8*)(Wn + (size_t)fm * KIP + kc * 32 + fg * 8);
#pragma unroll
    for (int i = 0; i < 2; ++i) {
      f16x8 af = *(const f16x8*)&Xs[(i * 16 + fm) * STRIDE + kc * 32 + fg * 8];
      acc[i] = __builtin_amdgcn_mfma_f32_16x16x32_f16(af, bf, acc[i], 0, 0, 0);
    }
  }
  int o = wave * 16 + fm;
  float bias = Bu[n * 64 + o];
#pragma unroll
  for (int i = 0; i < 2; ++i)
#pragma unroll
    for (int r = 0; r < 4; ++r) {
      int b = i * 16 + fg * 4 + r;
      float x = acc[i][r] + bias;
      x = fminf(fmaxf(x, -15.f), 15.f);
      float e = __expf(2.f * x);
      float hc = (e - 1.f) / (e + 1.f);
      size_t base = (size_t)n * 2048 + b * 64;
      float rr = rbuf[base + o];
      float hnew = rr * h32[base + o] + (1.f - rr) * hc;
      h32[base + o] = hnew;
      h16[base + o] = __float2half(hnew);
    }
}

// ---------------- out[b,o,n] = h2[n,b,:] . conv_w[o,:] + conv_b[o] ----------------
__global__ void final_conv_kernel(const float* __restrict__ h2, const float* __restrict__ cw,
                                  const float* __restrict__ cb, float* __restrict__ out) {
  int tid = blockIdx.x * 256 + threadIdx.x;
  if (tid >= 32 * 1024) return;
  int n = tid & 1023, b = tid >> 10;
  const float* hp = h2 + ((size_t)n * 32 + b) * 64;
  float hv[64];
#pragma unroll
  for (int i = 0; i < 64; ++i) hv[i] = hp[i];
#pragma unroll
  for (int o = 0; o < 12; ++o) {
    float acc = cb[o];
#pragma unroll
    for (int i = 0; i < 64; ++i) acc += hv[i] * cw[o * 64 + i];
    out[((size_t)b * 12 + o) * 1024 + n] = acc;
  }
}

extern "C" void kernel_launch(void* const* d_in, const int* in_sizes, int n_in,
                              void* d_out, int out_size, void* d_ws, size_t ws_size,
                              hipStream_t stream) {
  const float* src = (const float*)d_in[0];
  const float* E   = (const float*)d_in[1];
  const float* gw0 = (const float*)d_in[2];
  const float* gb0 = (const float*)d_in[3];
  const float* uw0 = (const float*)d_in[4];
  const float* ub0 = (const float*)d_in[5];
  const float* gw1 = (const float*)d_in[6];
  const float* gb1 = (const float*)d_in[7];
  const float* uw1 = (const float*)d_in[8];
  const float* ub1 = (const float*)d_in[9];
  const float* cw  = (const float*)d_in[10];
  const float* cb  = (const float*)d_in[11];
  float* out = (float*)d_out;
  (void)in_sizes; (void)n_in; (void)out_size; (void)ws_size;

  char* base = (char*)d_ws;
  size_t off = 0;
  auto alloc = [&](size_t bytes) -> void* {
    void* p = base + off; off += (bytes + 511) & ~(size_t)511; return p;
  };
  __half* Ah   = (__half*)alloc((size_t)1024 * 1024 * 2);           //   2.1 MB
  __half* WtG0 = (__half*)alloc((size_t)1024 * 128 * 160 * 2);      //  41.9 MB
  __half* WtU0 = (__half*)alloc((size_t)1024 * 64 * 160 * 2);       //  21.0 MB
  __half* WtG1 = (__half*)alloc((size_t)1024 * 128 * 256 * 2);      //  67.1 MB
  __half* WtU1 = (__half*)alloc((size_t)1024 * 64 * 256 * 2);       //  33.6 MB
  float*  Bg0  = (float*) alloc((size_t)1024 * 128 * 4);
  float*  Bu0  = (float*) alloc((size_t)1024 * 64 * 4);
  float*  Bg1  = (float*) alloc((size_t)1024 * 128 * 4);
  float*  Bu1  = (float*) alloc((size_t)1024 * 64 * 4);
  // zero-initialized region (contiguous): h1_32, h2_32, h1_16, h2_16, YB
  float*  h1_32 = (float*)alloc((size_t)1024 * 2048 * 4);           //   8.4 MB
  float*  h2_32 = (float*)alloc((size_t)1024 * 2048 * 4);           //   8.4 MB
  __half* h1_16 = (__half*)alloc((size_t)1024 * 2048 * 2);          //   4.2 MB
  __half* h2_16 = (__half*)alloc((size_t)1024 * 2048 * 2);          //   4.2 MB
  __half* YB   = (__half*)alloc((size_t)1024 * 2048 * 2);           //   4.2 MB (A@h1)
  __half* zh   = (__half*)alloc((size_t)1024 * 2048 * 2);           //   4.2 MB
  __half* YA2  = (__half*)alloc((size_t)1024 * 4096 * 2);           //   8.4 MB ([A@zh0 | A@h2])
  __half* YC   = (__half*)alloc((size_t)1024 * 2048 * 2);           //   4.2 MB (A@zh1)
  __half* XT   = (__half*)alloc((size_t)4096 * 1024 * 2);           //   8.4 MB (transposed B)
  __half* Axt  = (__half*)alloc((size_t)1024 * 768 * 2);            //   1.5 MB (A@x all t)
  float*  rbuf = (float*) alloc((size_t)1024 * 2048 * 4);           //   8.4 MB (+ prelude scratch)
  float*  poolT = rbuf;                                             // 5.11 MB prelude-only
  __half* xT   = (__half*)(rbuf + (size_t)1310720);                 // 1.5 MB prelude-only
  // total ~229 MB

  // ---- prelude (7 dispatches) ----
  compute_A_kernel<<<1024, 256, 0, stream>>>(E, Ah);
  pool_transpose_all_kernel<<<(1277952 + 255) / 256, 256, 0, stream>>>(gw0, uw0, gw1, uw1, poolT);
  make_wt_all_kernel<<<dim3(384, 16), 256, 0, stream>>>(E, poolT, WtG0, WtU0, WtG1, WtU1);
  make_b_all_kernel<<<(1024 * 384 + 255) / 256, 256, 0, stream>>>(E, gb0, ub0, gb1, ub1,
                                                                  Bg0, Bu0, Bg1, Bu1);
  build_xt_kernel<<<384, 256, 0, stream>>>(src, xT);
  gemm_db_kernel<<<dim3(12, 16), 256, 0, stream>>>(Ah, xT, Axt, 768);
  // zero h1_32,h2_32,h1_16,h2_16,YB (contiguous, 7340032 float-units)
  zero_kernel<<<(7340032 + 255) / 256, 256, 0, stream>>>(h1_32, 7340032);

  // ---- 12 GRU steps ----
  for (int t = 0; t < 12; ++t) {
    gate0_kernel<<<1024, 256, 0, stream>>>(h1_16, YB, src, Axt, t, WtG0, Bg0, h1_32, zh, rbuf);
    t16_dual_kernel<<<dim3(64, 16), 256, 0, stream>>>(zh, h2_16, XT);
    gemm_db_kernel<<<dim3(64, 16), 256, 0, stream>>>(Ah, XT, YA2, 4096);
    upd0_kernel<<<1024, 256, 0, stream>>>(zh, YA2, src, Axt, t, WtU0, Bu0, rbuf, h1_32, h1_16);
    t16_kernel<<<dim3(32, 16), 256, 0, stream>>>(h1_16, XT);
    gemm_db_kernel<<<dim3(32, 16), 256, 0, stream>>>(Ah, XT, YB, 2048);
    gate1_kernel<<<1024, 256, 0, stream>>>(h1_16, h2_16, YB, YA2, WtG1, Bg1, h2_32, zh, rbuf);
    t16_kernel<<<dim3(32, 16), 256, 0, stream>>>(zh, XT);
    gemm_db_kernel<<<dim3(32, 16), 256, 0, stream>>>(Ah, XT, YC, 2048);
    upd1_kernel<<<1024, 256, 0, stream>>>(h1_16, zh, YB, YC, WtU1, Bu1, rbuf, h2_32, h2_16);
  }

  final_conv_kernel<<<(32 * 1024 + 255) / 256, 256, 0, stream>>>(h2_32, cw, cb, out);
}

// Round 7
// 1523.096 us; speedup vs baseline: 4.4258x; 1.0320x over previous
//
#include <hip/hip_runtime.h>
#include <hip/hip_fp16.h>

// AGCRN: B=32 T=12 N=1024 C=2 D=16 H=64 K=2 OUT=12
// Node-major activations [n][(b,f)], fp16 on GEMM paths; h fp32 master + fp16 mirror.
// gemm_nt: B-operand read node-major directly; in-LDS transpose with XOR chunk swizzle
//   (Bs stride 80 halves; chunk ck stored at ck^(col&7): staging b32 writes and b128
//    frag reads both spread over all 32 banks).
// Per step (7 dispatches):
//   gate0 -> gemm(A@[zh0|h2],4096) -> upd0 -> gemm(A@h1->YB) -> gate1 -> gemm(A@zh1->YC) -> upd1

typedef _Float16 f16x8 __attribute__((ext_vector_type(8)));
typedef _Float16 f16x2 __attribute__((ext_vector_type(2)));
typedef float f32x4 __attribute__((ext_vector_type(4)));

// ---------------- A = softmax(relu(E E^T)) -> fp16 ----------------
__global__ __launch_bounds__(256) void compute_A_kernel(const float* __restrict__ E,
                                                        __half* __restrict__ Ah) {
  int n = blockIdx.x;
  int tid = threadIdx.x;
  __shared__ float red[256];
  float en[16];
#pragma unroll
  for (int d = 0; d < 16; ++d) en[d] = E[n * 16 + d];
  float v[4];
#pragma unroll
  for (int q = 0; q < 4; ++q) {
    int m = tid + q * 256;
    const float* Em = E + m * 16;
    float dot = 0.f;
#pragma unroll
    for (int d = 0; d < 16; ++d) dot += en[d] * Em[d];
    v[q] = fmaxf(dot, 0.f);
  }
  float mx = fmaxf(fmaxf(v[0], v[1]), fmaxf(v[2], v[3]));
  red[tid] = mx; __syncthreads();
  for (int s = 128; s > 0; s >>= 1) { if (tid < s) red[tid] = fmaxf(red[tid], red[tid + s]); __syncthreads(); }
  mx = red[0];
  __syncthreads();
  float e[4], sum = 0.f;
#pragma unroll
  for (int q = 0; q < 4; ++q) { e[q] = expf(v[q] - mx); sum += e[q]; }
  red[tid] = sum; __syncthreads();
  for (int s = 128; s > 0; s >>= 1) { if (tid < s) red[tid] += red[tid + s]; __syncthreads(); }
  float inv = 1.f / red[0];
#pragma unroll
  for (int q = 0; q < 4; ++q) Ah[(size_t)n * 1024 + tid + q * 256] = __float2half(e[q] * inv);
}

// ---------------- merged poolT: 4 segments, permuted/padded K-contiguous ----------------
__global__ void pool_transpose_all_kernel(const float* __restrict__ gw0, const float* __restrict__ uw0,
                                          const float* __restrict__ gw1, const float* __restrict__ uw1,
                                          float* __restrict__ poolT) {
  int t = blockIdx.x * 256 + threadIdx.x;
  if (t >= 1277952) return;
  const float* pool; int F, Fp, O, loc;
  if (t < 327680)       { pool = gw0; F = 66;  Fp = 80;  O = 128; loc = t; }
  else if (t < 491520)  { pool = uw0; F = 66;  Fp = 80;  O = 64;  loc = t - 327680; }
  else if (t < 1015808) { pool = gw1; F = 128; Fp = 128; O = 128; loc = t - 491520; }
  else                  { pool = uw1; F = 128; Fp = 128; O = 64;  loc = t - 1015808; }
  int KIp = 2 * Fp;
  int kip = loc % KIp;
  int rest = loc / KIp;
  int o = rest % O;
  int d = rest / O;
  int kk = (kip >= Fp) ? 1 : 0;
  int j = kip - kk * Fp;
  int i;
  if (F == Fp) i = j;
  else i = (j < 64) ? j + 2 : (j < 66 ? j - 64 : -1);
  poolT[t] = (i >= 0) ? pool[(((size_t)d * 2 + kk) * F + i) * O + o] : 0.f;
}

// ---------------- merged Wt builder: scalar-pipe pool reads + LDS-bounce writes ----------------
// grid (384, 16). Pool data is wave-uniform -> read via scalar loads (readfirstlane'd offset),
// no pl LDS staging. Compute is pure VALU (v_fmac vgpr,sgpr).
__global__ __launch_bounds__(256) void make_wt_all_kernel(
    const float* __restrict__ E, const float* __restrict__ poolT,
    __half* __restrict__ WtG0, __half* __restrict__ WtU0,
    __half* __restrict__ WtG1, __half* __restrict__ WtU1) {
  __shared__ float Es[64 * 17];
  __shared__ __align__(16) _Float16 wbuf[64][264];
  int bx = blockIdx.x;
  int o, O, KIp; const float* pt; __half* Wt;
  if (bx < 128)      { o = bx;       O = 128; KIp = 160; pt = poolT;           Wt = WtG0; }
  else if (bx < 192) { o = bx - 128; O = 64;  KIp = 160; pt = poolT + 327680;  Wt = WtU0; }
  else if (bx < 320) { o = bx - 192; O = 128; KIp = 256; pt = poolT + 491520;  Wt = WtG1; }
  else               { o = bx - 320; O = 64;  KIp = 256; pt = poolT + 1015808; Wt = WtU1; }
  int n0 = blockIdx.y * 64;
  {
    int nl = threadIdx.x >> 2, d0 = (threadIdx.x & 3) * 4;
    float4 v = *(const float4*)(E + (size_t)(n0 + nl) * 16 + d0);
    Es[nl * 17 + d0 + 0] = v.x; Es[nl * 17 + d0 + 1] = v.y;
    Es[nl * 17 + d0 + 2] = v.z; Es[nl * 17 + d0 + 3] = v.w;
  }
  __syncthreads();
  int nl = threadIdx.x & 63;
  int q = KIp >> 2;
  int ku = __builtin_amdgcn_readfirstlane((threadIdx.x >> 6) * q);  // uniform per wave
  float e[16];
#pragma unroll
  for (int d = 0; d < 16; ++d) e[d] = Es[nl * 17 + d];
  const float* pbase = pt + (size_t)o * KIp + ku;
  int strideOK = O * KIp;
  for (int kk = 0; kk < q; kk += 8) {
    float a[8] = {0.f, 0.f, 0.f, 0.f, 0.f, 0.f, 0.f, 0.f};
#pragma unroll
    for (int d = 0; d < 16; ++d) {
      const float* pd = pbase + (size_t)d * strideOK + kk;
#pragma unroll
      for (int j = 0; j < 8; ++j) a[j] = fmaf(e[d], pd[j], a[j]);
    }
    f16x8 pk;
#pragma unroll
    for (int j = 0; j < 8; ++j) pk[j] = (_Float16)a[j];
    *(f16x8*)&wbuf[nl][ku + kk] = pk;
  }
  __syncthreads();
  // coalesced write phase: node rows are KIp-contiguous in Wt
  int chunks = KIp >> 3;
  int tot = 64 * chunks;
  for (int idx = threadIdx.x; idx < tot; idx += 256) {
    int nsub = idx / chunks;
    int pos = (idx - nsub * chunks) * 8;
    *(float4*)(Wt + ((size_t)(n0 + nsub) * O + o) * KIp + pos) = *(float4*)&wbuf[nsub][pos];
  }
}

// ---------------- merged per-node biases ----------------
__global__ void make_b_all_kernel(const float* __restrict__ E,
                                  const float* __restrict__ gb0, const float* __restrict__ ub0,
                                  const float* __restrict__ gb1, const float* __restrict__ ub1,
                                  float* __restrict__ Bg0, float* __restrict__ Bu0,
                                  float* __restrict__ Bg1, float* __restrict__ Bu1) {
  int tid = blockIdx.x * 256 + threadIdx.x;
  if (tid >= 1024 * 384) return;
  int n = tid / 384, c = tid - n * 384;
  const float* pool; float* outp; int O, o;
  if (c < 128)      { pool = gb0; outp = Bg0; O = 128; o = c; }
  else if (c < 192) { pool = ub0; outp = Bu0; O = 64;  o = c - 128; }
  else if (c < 320) { pool = gb1; outp = Bg1; O = 128; o = c - 192; }
  else              { pool = ub1; outp = Bu1; O = 64;  o = c - 320; }
  const float* En = E + n * 16;
  float a = 0.f;
#pragma unroll
  for (int d = 0; d < 16; ++d) a += En[d] * pool[d * O + o];
  outp[n * O + o] = a;
}

__global__ void zero_kernel(float* __restrict__ p, int count) {
  int i = blockIdx.x * 256 + threadIdx.x;
  if (i < count) p[i] = 0.f;
}

// ---------------- x16[n][t*64+b*2+cc] = src[b][t][n][cc], fp16 node-major ----------------
__global__ void build_x16_kernel(const float* __restrict__ src, __half* __restrict__ x16) {
  int bid = blockIdx.x; int t = bid >> 5, b = bid & 31;   // 384 blocks
  const float* s = src + (size_t)(b * 12 + t) * 2048;
  __half* dst = x16 + t * 64 + b * 2;
  for (int n = threadIdx.x; n < 1024; n += 256) {
    float2 v = *(const float2*)(s + n * 2);
    *(__half2*)(dst + (size_t)n * 768) = __floats2half2_rn(v.x, v.y);
  }
}

// ---------------- gemm_nt: Y[1024 x Nc] = Ah @ X, X given node-major [k][c] ----------------
// 64x64 tile, K=64/stage, reg double-buffer. B transposed during staging:
// thread (kp=tid&31, cg=tid>>5) loads rows 2kp,2kp+1 x 8 cols; packs k-pairs -> b32 writes
// into swizzled Bs[col][ (ck^(col&7))*8 + k%8 ]. Frag reads b128 at swizzled chunk.
__global__ __launch_bounds__(256) void gemm_nt_kernel(
    const __half* __restrict__ Ahg, const __half* __restrict__ X0g,
    const __half* __restrict__ X1g, __half* __restrict__ Yg,
    int Nc, int cstride, int split) {
  __shared__ __align__(16) _Float16 As[64][72];
  __shared__ __align__(16) _Float16 Bs[64][80];
  const _Float16* __restrict__ Ah = (const _Float16*)Ahg;
  _Float16* __restrict__ Y = (_Float16*)Yg;
  int tid = threadIdx.x;
  int row0 = blockIdx.y * 64;
  int col0 = blockIdx.x * 64;
  const _Float16* __restrict__ Xsrc =
      (col0 < split) ? (const _Float16*)X0g : (const _Float16*)X1g;
  int colg = (col0 < split) ? col0 : col0 - split;
  int wave = tid >> 6, lane = tid & 63;
  int wm = wave & 1, wn = wave >> 1;
  int fm = lane & 15, fg = lane >> 4;

  // A staging ids
  int sr = tid >> 2, sc = (tid & 3) * 16;
  const _Float16* pa = Ah + (size_t)(row0 + sr) * 1024 + sc;
  // B staging ids
  int kp = tid & 31, cg = tid >> 5;          // rows 2kp,2kp+1 ; cols cg*8..cg*8+7
  const _Float16* pb0 = Xsrc + (size_t)(2 * kp) * cstride + colg + cg * 8;
  const _Float16* pb1 = pb0 + cstride;

  // stage-0 prefetch
  f16x8 ra0 = *(const f16x8*)(pa);
  f16x8 ra1 = *(const f16x8*)(pa + 8);
  f16x8 rb0 = *(const f16x8*)(pb0);
  f16x8 rb1 = *(const f16x8*)(pb1);

  int kk = 2 * kp;
  int kchunk = kp >> 2;              // k/8
  int kin = kk & 7;                  // k%8 (even)
  f32x4 acc[2][2] = {};
  for (int k0 = 0; k0 < 1024; k0 += 64) {
    *(f16x8*)&As[sr][sc] = ra0;
    *(f16x8*)&As[sr][sc + 8] = ra1;
#pragma unroll
    for (int i = 0; i < 8; ++i) {
      int c = cg * 8 + i;
      f16x2 p; p[0] = rb0[i]; p[1] = rb1[i];
      int pos = ((kchunk ^ (c & 7)) << 3) + kin;
      *(f16x2*)&Bs[c][pos] = p;
    }
    __syncthreads();
    if (k0 + 64 < 1024) {            // prefetch next stage; latency overlaps compute
      ra0 = *(const f16x8*)(pa + k0 + 64);
      ra1 = *(const f16x8*)(pa + k0 + 72);
      rb0 = *(const f16x8*)(pb0 + (size_t)(k0 + 64) * cstride);
      rb1 = *(const f16x8*)(pb1 + (size_t)(k0 + 64) * cstride);
    }
#pragma unroll
    for (int kc = 0; kc < 2; ++kc) {
      int ck = kc * 4 + fg;
      f16x8 af[2], bf[2];
#pragma unroll
      for (int i = 0; i < 2; ++i)
        af[i] = *(const f16x8*)&As[wm * 32 + i * 16 + fm][kc * 32 + fg * 8];
#pragma unroll
      for (int j = 0; j < 2; ++j) {
        int cl = wn * 32 + j * 16 + fm;
        bf[j] = *(const f16x8*)&Bs[cl][(ck ^ (cl & 7)) << 3];
      }
#pragma unroll
      for (int i = 0; i < 2; ++i)
#pragma unroll
        for (int j = 0; j < 2; ++j)
          acc[i][j] = __builtin_amdgcn_mfma_f32_16x16x32_f16(af[i], bf[j], acc[i][j], 0, 0, 0);
    }
    __syncthreads();
  }
#pragma unroll
  for (int i = 0; i < 2; ++i) {
#pragma unroll
    for (int j = 0; j < 2; ++j) {
      int col = col0 + wn * 32 + j * 16 + fm;
      int rbase = row0 + wm * 32 + i * 16 + fg * 4;
#pragma unroll
      for (int r = 0; r < 4; ++r)
        Y[(size_t)(rbase + r) * Nc + col] = (_Float16)acc[i][j][r];
    }
  }
}

// ---------------- gate L0: zr = sigmoid([h1|x | Ah1|Ax] @ Wt + B); zh=z*h32; rbuf=r ----------------
__global__ __launch_bounds__(256) void gate0_kernel(
    const __half* __restrict__ h16, const __half* __restrict__ YB,
    const float* __restrict__ src, const __half* __restrict__ Axt, int tstep,
    const __half* __restrict__ Wtg, const float* __restrict__ Bg,
    const float* __restrict__ h32, __half* __restrict__ zh, float* __restrict__ rbuf) {
  constexpr int KIP = 160, STRIDE = 168;
  __shared__ __align__(16) _Float16 Xs[32 * STRIDE];
  int n = blockIdx.x;
  int t = threadIdx.x;
#pragma unroll
  for (int u = 0; u < 2; ++u) {
    int idx = t + u * 256;
    int b = idx >> 4, part = (idx >> 3) & 1, ch = idx & 7;
    const _Float16* s = part ? (const _Float16*)YB + (size_t)n * 2048 + b * 64 + ch * 8
                             : (const _Float16*)h16 + (size_t)n * 2048 + b * 64 + ch * 8;
    *(f16x8*)&Xs[b * STRIDE + part * 80 + ch * 8] = *(const f16x8*)s;
  }
  if (t < 32) {
    int b = t;
    float2 xv = *(const float2*)(src + ((size_t)(b * 12 + tstep) * 1024 + n) * 2);
    Xs[b * STRIDE + 64] = (_Float16)xv.x;
    Xs[b * STRIDE + 65] = (_Float16)xv.y;
    const _Float16* ax = (const _Float16*)Axt + (size_t)n * 768 + tstep * 64 + b * 2;
    Xs[b * STRIDE + 144] = ax[0];
    Xs[b * STRIDE + 145] = ax[1];
  }
  for (int idx = t; idx < 896; idx += 256) {
    int b = idx / 28, jj = idx % 28;
    int col = (jj < 14) ? 66 + jj : 132 + jj;
    Xs[b * STRIDE + col] = (_Float16)0.f;
  }
  __syncthreads();
  int wave = t >> 6, lane = t & 63;
  int fm = lane & 15, fg = lane >> 4;
  f32x4 acc[2][2] = {};
  const _Float16* Wn = (const _Float16*)Wtg + ((size_t)n * 128 + wave * 32) * KIP;
#pragma unroll
  for (int kc = 0; kc < KIP / 32; ++kc) {
    f16x8 af[2], bf[2];
#pragma unroll
    for (int i = 0; i < 2; ++i)
      af[i] = *(const f16x8*)&Xs[(i * 16 + fm) * STRIDE + kc * 32 + fg * 8];
#pragma unroll
    for (int j = 0; j < 2; ++j)
      bf[j] = *(const f16x8*)(Wn + (size_t)(j * 16 + fm) * KIP + kc * 32 + fg * 8);
#pragma unroll
    for (int i = 0; i < 2; ++i)
#pragma unroll
      for (int j = 0; j < 2; ++j)
        acc[i][j] = __builtin_amdgcn_mfma_f32_16x16x32_f16(af[i], bf[j], acc[i][j], 0, 0, 0);
  }
  const float* Bn = Bg + n * 128;
#pragma unroll
  for (int j = 0; j < 2; ++j) {
    int o = wave * 32 + j * 16 + fm;
    float bias = Bn[o];
#pragma unroll
    for (int i = 0; i < 2; ++i)
#pragma unroll
      for (int r = 0; r < 4; ++r) {
        int b = i * 16 + fg * 4 + r;
        float s = 1.f / (1.f + __expf(-(acc[i][j][r] + bias)));
        size_t base = (size_t)n * 2048 + b * 64;
        if (o < 64) zh[base + o] = __float2half(s * h32[base + o]);
        else        rbuf[base + o - 64] = s;
      }
  }
}

// ---------------- upd L0: hc = tanh([zh|x | Azh|Ax] @ Wt + B); h = r*h + (1-r)*hc ----------------
__global__ __launch_bounds__(256) void upd0_kernel(
    const __half* __restrict__ zh, const __half* __restrict__ YA2,
    const float* __restrict__ src, const __half* __restrict__ Axt, int tstep,
    const __half* __restrict__ Wtg, const float* __restrict__ Bu,
    const float* __restrict__ rbuf, float* __restrict__ h32, __half* __restrict__ h16) {
  constexpr int KIP = 160, STRIDE = 168;
  __shared__ __align__(16) _Float16 Xs[32 * STRIDE];
  int n = blockIdx.x;
  int t = threadIdx.x;
#pragma unroll
  for (int u = 0; u < 2; ++u) {
    int idx = t + u * 256;
    int b = idx >> 4, part = (idx >> 3) & 1, ch = idx & 7;
    const _Float16* s = part ? (const _Float16*)YA2 + (size_t)n * 4096 + b * 64 + ch * 8
                             : (const _Float16*)zh + (size_t)n * 2048 + b * 64 + ch * 8;
    *(f16x8*)&Xs[b * STRIDE + part * 80 + ch * 8] = *(const f16x8*)s;
  }
  if (t < 32) {
    int b = t;
    float2 xv = *(const float2*)(src + ((size_t)(b * 12 + tstep) * 1024 + n) * 2);
    Xs[b * STRIDE + 64] = (_Float16)xv.x;
    Xs[b * STRIDE + 65] = (_Float16)xv.y;
    const _Float16* ax = (const _Float16*)Axt + (size_t)n * 768 + tstep * 64 + b * 2;
    Xs[b * STRIDE + 144] = ax[0];
    Xs[b * STRIDE + 145] = ax[1];
  }
  for (int idx = t; idx < 896; idx += 256) {
    int b = idx / 28, jj = idx % 28;
    int col = (jj < 14) ? 66 + jj : 132 + jj;
    Xs[b * STRIDE + col] = (_Float16)0.f;
  }
  __syncthreads();
  int wave = t >> 6, lane = t & 63;
  int fm = lane & 15, fg = lane >> 4;
  f32x4 acc[2] = {};
  const _Float16* Wn = (const _Float16*)Wtg + ((size_t)n * 64 + wave * 16) * KIP;
#pragma unroll
  for (int kc = 0; kc < KIP / 32; ++kc) {
    f16x8 bf = *(const f16x8*)(Wn + (size_t)fm * KIP + kc * 32 + fg * 8);
#pragma unroll
    for (int i = 0; i < 2; ++i) {
      f16x8 af = *(const f16x8*)&Xs[(i * 16 + fm) * STRIDE + kc * 32 + fg * 8];
      acc[i] = __builtin_amdgcn_mfma_f32_16x16x32_f16(af, bf, acc[i], 0, 0, 0);
    }
  }
  int o = wave * 16 + fm;
  float bias = Bu[n * 64 + o];
#pragma unroll
  for (int i = 0; i < 2; ++i)
#pragma unroll
    for (int r = 0; r < 4; ++r) {
      int b = i * 16 + fg * 4 + r;
      float x = acc[i][r] + bias;
      x = fminf(fmaxf(x, -15.f), 15.f);
      float e = __expf(2.f * x);
      float hc = (e - 1.f) / (e + 1.f);
      size_t base = (size_t)n * 2048 + b * 64;
      float rr = rbuf[base + o];
      float hnew = rr * h32[base + o] + (1.f - rr) * hc;
      h32[base + o] = hnew;
      h16[base + o] = __float2half(hnew);
    }
}

// ---------------- gate L1: zr = sigmoid([h1|h2 | Ah1|Ah2] @ Wt + B) ----------------
__global__ __launch_bounds__(256) void gate1_kernel(
    const __half* __restrict__ h1_16, const __half* __restrict__ h2_16,
    const __half* __restrict__ YB, const __half* __restrict__ YA2,
    const __half* __restrict__ Wtg, const float* __restrict__ Bg,
    const float* __restrict__ h32, __half* __restrict__ zh, float* __restrict__ rbuf) {
  constexpr int KIP = 256, STRIDE = 264;
  __shared__ __align__(16) _Float16 Xs[32 * STRIDE];
  int n = blockIdx.x;
  int t = threadIdx.x;
#pragma unroll
  for (int u = 0; u < 4; ++u) {
    int idx = t + u * 256;
    int b = idx >> 5, q = idx & 31;
    const _Float16* s;
    if (q < 8)       s = (const _Float16*)h1_16 + (size_t)n * 2048 + b * 64 + q * 8;
    else if (q < 16) s = (const _Float16*)h2_16 + (size_t)n * 2048 + b * 64 + (q - 8) * 8;
    else if (q < 24) s = (const _Float16*)YB + (size_t)n * 2048 + b * 64 + (q - 16) * 8;
    else             s = (const _Float16*)YA2 + (size_t)n * 4096 + 2048 + b * 64 + (q - 24) * 8;
    *(f16x8*)&Xs[b * STRIDE + q * 8] = *(const f16x8*)s;
  }
  __syncthreads();
  int wave = t >> 6, lane = t & 63;
  int fm = lane & 15, fg = lane >> 4;
  f32x4 acc[2][2] = {};
  const _Float16* Wn = (const _Float16*)Wtg + ((size_t)n * 128 + wave * 32) * KIP;
#pragma unroll
  for (int kc = 0; kc < KIP / 32; ++kc) {
    f16x8 af[2], bf[2];
#pragma unroll
    for (int i = 0; i < 2; ++i)
      af[i] = *(const f16x8*)&Xs[(i * 16 + fm) * STRIDE + kc * 32 + fg * 8];
#pragma unroll
    for (int j = 0; j < 2; ++j)
      bf[j] = *(const f16x8*)(Wn + (size_t)(j * 16 + fm) * KIP + kc * 32 + fg * 8);
#pragma unroll
    for (int i = 0; i < 2; ++i)
#pragma unroll
      for (int j = 0; j < 2; ++j)
        acc[i][j] = __builtin_amdgcn_mfma_f32_16x16x32_f16(af[i], bf[j], acc[i][j], 0, 0, 0);
  }
  const float* Bn = Bg + n * 128;
#pragma unroll
  for (int j = 0; j < 2; ++j) {
    int o = wave * 32 + j * 16 + fm;
    float bias = Bn[o];
#pragma unroll
    for (int i = 0; i < 2; ++i)
#pragma unroll
      for (int r = 0; r < 4; ++r) {
        int b = i * 16 + fg * 4 + r;
        float s = 1.f / (1.f + __expf(-(acc[i][j][r] + bias)));
        size_t base = (size_t)n * 2048 + b * 64;
        if (o < 64) zh[base + o] = __float2half(s * h32[base + o]);
        else        rbuf[base + o - 64] = s;
      }
  }
}

// ---------------- upd L1: hc = tanh([h1|zh | Ah1|Azh] @ Wt + B); h2 = r*h2 + (1-r)*hc ----------------
__global__ __launch_bounds__(256) void upd1_kernel(
    const __half* __restrict__ h1_16, const __half* __restrict__ zh,
    const __half* __restrict__ YB, const __half* __restrict__ YC,
    const __half* __restrict__ Wtg, const float* __restrict__ Bu,
    const float* __restrict__ rbuf, float* __restrict__ h32, __half* __restrict__ h16) {
  constexpr int KIP = 256, STRIDE = 264;
  __shared__ __align__(16) _Float16 Xs[32 * STRIDE];
  int n = blockIdx.x;
  int t = threadIdx.x;
#pragma unroll
  for (int u = 0; u < 4; ++u) {
    int idx = t + u * 256;
    int b = idx >> 5, q = idx & 31;
    const _Float16* s;
    if (q < 8)       s = (const _Float16*)h1_16 + (size_t)n * 2048 + b * 64 + q * 8;
    else if (q < 16) s = (const _Float16*)zh + (size_t)n * 2048 + b * 64 + (q - 8) * 8;
    else if (q < 24) s = (const _Float16*)YB + (size_t)n * 2048 + b * 64 + (q - 16) * 8;
    else             s = (const _Float16*)YC + (size_t)n * 2048 + b * 64 + (q - 24) * 8;
    *(f16x8*)&Xs[b * STRIDE + q * 8] = *(const f16x8*)s;
  }
  __syncthreads();
  int wave = t >> 6, lane = t & 63;
  int fm = lane & 15, fg = lane >> 4;
  f32x4 acc[2] = {};
  const _Float16* Wn = (const _Float16*)Wtg + ((size_t)n * 64 + wave * 16) * KIP;
#pragma unroll
  for (int kc = 0; kc < KIP / 32; ++kc) {
    f16x8 bf = *(const f16x8*)(Wn + (size_t)fm * KIP + kc * 32 + fg * 8);
#pragma unroll
    for (int i = 0; i < 2; ++i) {
      f16x8 af = *(const f16x8*)&Xs[(i * 16 + fm) * STRIDE + kc * 32 + fg * 8];
      acc[i] = __builtin_amdgcn_mfma_f32_16x16x32_f16(af, bf, acc[i], 0, 0, 0);
    }
  }
  int o = wave * 16 + fm;
  float bias = Bu[n * 64 + o];
#pragma unroll
  for (int i = 0; i < 2; ++i)
#pragma unroll
    for (int r = 0; r < 4; ++r) {
      int b = i * 16 + fg * 4 + r;
      float x = acc[i][r] + bias;
      x = fminf(fmaxf(x, -15.f), 15.f);
      float e = __expf(2.f * x);
      float hc = (e - 1.f) / (e + 1.f);
      size_t base = (size_t)n * 2048 + b * 64;
      float rr = rbuf[base + o];
      float hnew = rr * h32[base + o] + (1.f - rr) * hc;
      h32[base + o] = hnew;
      h16[base + o] = __float2half(hnew);
    }
}

// ---------------- out[b,o,n] = h2[n,b,:] . conv_w[o,:] + conv_b[o] ----------------
__global__ void final_conv_kernel(const float* __restrict__ h2, const float* __restrict__ cw,
                                  const float* __restrict__ cb, float* __restrict__ out) {
  int tid = blockIdx.x * 256 + threadIdx.x;
  if (tid >= 32 * 1024) return;
  int n = tid & 1023, b = tid >> 10;
  const float* hp = h2 + ((size_t)n * 32 + b) * 64;
  float hv[64];
#pragma unroll
  for (int i = 0; i < 64; ++i) hv[i] = hp[i];
#pragma unroll
  for (int o = 0; o < 12; ++o) {
    float acc = cb[o];
#pragma unroll
    for (int i = 0; i < 64; ++i) acc += hv[i] * cw[o * 64 + i];
    out[((size_t)b * 12 + o) * 1024 + n] = acc;
  }
}

extern "C" void kernel_launch(void* const* d_in, const int* in_sizes, int n_in,
                              void* d_out, int out_size, void* d_ws, size_t ws_size,
                              hipStream_t stream) {
  const float* src = (const float*)d_in[0];
  const float* E   = (const float*)d_in[1];
  const float* gw0 = (const float*)d_in[2];
  const float* gb0 = (const float*)d_in[3];
  const float* uw0 = (const float*)d_in[4];
  const float* ub0 = (const float*)d_in[5];
  const float* gw1 = (const float*)d_in[6];
  const float* gb1 = (const float*)d_in[7];
  const float* uw1 = (const float*)d_in[8];
  const float* ub1 = (const float*)d_in[9];
  const float* cw  = (const float*)d_in[10];
  const float* cb  = (const float*)d_in[11];
  float* out = (float*)d_out;
  (void)in_sizes; (void)n_in; (void)out_size; (void)ws_size;

  char* base = (char*)d_ws;
  size_t off = 0;
  auto alloc = [&](size_t bytes) -> void* {
    void* p = base + off; off += (bytes + 511) & ~(size_t)511; return p;
  };
  __half* Ah   = (__half*)alloc((size_t)1024 * 1024 * 2);           //   2.1 MB
  __half* WtG0 = (__half*)alloc((size_t)1024 * 128 * 160 * 2);      //  41.9 MB
  __half* WtU0 = (__half*)alloc((size_t)1024 * 64 * 160 * 2);       //  21.0 MB
  __half* WtG1 = (__half*)alloc((size_t)1024 * 128 * 256 * 2);      //  67.1 MB
  __half* WtU1 = (__half*)alloc((size_t)1024 * 64 * 256 * 2);       //  33.6 MB
  float*  Bg0  = (float*) alloc((size_t)1024 * 128 * 4);
  float*  Bu0  = (float*) alloc((size_t)1024 * 64 * 4);
  float*  Bg1  = (float*) alloc((size_t)1024 * 128 * 4);
  float*  Bu1  = (float*) alloc((size_t)1024 * 64 * 4);
  // zero-initialized region (contiguous): h1_32, h2_32, h1_16, h2_16, YB
  float*  h1_32 = (float*)alloc((size_t)1024 * 2048 * 4);           //   8.4 MB
  float*  h2_32 = (float*)alloc((size_t)1024 * 2048 * 4);           //   8.4 MB
  __half* h1_16 = (__half*)alloc((size_t)1024 * 2048 * 2);          //   4.2 MB
  __half* h2_16 = (__half*)alloc((size_t)1024 * 2048 * 2);          //   4.2 MB
  __half* YB   = (__half*)alloc((size_t)1024 * 2048 * 2);           //   4.2 MB (A@h1)
  __half* zh   = (__half*)alloc((size_t)1024 * 2048 * 2);           //   4.2 MB
  __half* YA2  = (__half*)alloc((size_t)1024 * 4096 * 2);           //   8.4 MB ([A@zh0 | A@h2])
  __half* YC   = (__half*)alloc((size_t)1024 * 2048 * 2);           //   4.2 MB (A@zh1)
  __half* Axt  = (__half*)alloc((size_t)1024 * 768 * 2);            //   1.5 MB (A@x all t)
  float*  rbuf = (float*) alloc((size_t)1024 * 2048 * 4);           //   8.4 MB (+ prelude scratch)
  float*  poolT = rbuf;                                             // 5.11 MB prelude-only
  __half* x16  = (__half*)(rbuf + (size_t)1310720);                 // 1.5 MB prelude-only
  // total ~221 MB

  // ---- prelude (7 dispatches) ----
  compute_A_kernel<<<1024, 256, 0, stream>>>(E, Ah);
  pool_transpose_all_kernel<<<(1277952 + 255) / 256, 256, 0, stream>>>(gw0, uw0, gw1, uw1, poolT);
  make_wt_all_kernel<<<dim3(384, 16), 256, 0, stream>>>(E, poolT, WtG0, WtU0, WtG1, WtU1);
  make_b_all_kernel<<<(1024 * 384 + 255) / 256, 256, 0, stream>>>(E, gb0, ub0, gb1, ub1,
                                                                  Bg0, Bu0, Bg1, Bu1);
  build_x16_kernel<<<384, 256, 0, stream>>>(src, x16);
  gemm_nt_kernel<<<dim3(12, 16), 256, 0, stream>>>(Ah, (__half*)x16, (__half*)x16, Axt,
                                                   768, 768, 768);
  zero_kernel<<<(7340032 + 255) / 256, 256, 0, stream>>>(h1_32, 7340032);

  // ---- 12 GRU steps (7 dispatches each) ----
  for (int t = 0; t < 12; ++t) {
    gate0_kernel<<<1024, 256, 0, stream>>>(h1_16, YB, src, Axt, t, WtG0, Bg0, h1_32, zh, rbuf);
    gemm_nt_kernel<<<dim3(64, 16), 256, 0, stream>>>(Ah, zh, h2_16, YA2, 4096, 2048, 2048);
    upd0_kernel<<<1024, 256, 0, stream>>>(zh, YA2, src, Axt, t, WtU0, Bu0, rbuf, h1_32, h1_16);
    gemm_nt_kernel<<<dim3(32, 16), 256, 0, stream>>>(Ah, h1_16, h1_16, YB, 2048, 2048, 2048);
    gate1_kernel<<<1024, 256, 0, stream>>>(h1_16, h2_16, YB, YA2, WtG1, Bg1, h2_32, zh, rbuf);
    gemm_nt_kernel<<<dim3(32, 16), 256, 0, stream>>>(Ah, zh, zh, YC, 2048, 2048, 2048);
    upd1_kernel<<<1024, 256, 0, stream>>>(h1_16, zh, YB, YC, WtU1, Bu1, rbuf, h2_32, h2_16);
  }

  final_conv_kernel<<<(32 * 1024 + 255) / 256, 256, 0, stream>>>(h2_32, cw, cb, out);
}

// Round 8
// 1516.455 us; speedup vs baseline: 4.4452x; 1.0044x over previous
//
#include <hip/hip_runtime.h>
#include <hip/hip_fp16.h>

// AGCRN: B=32 T=12 N=1024 C=2 D=16 H=64 K=2 OUT=12
// Node-major activations [n][(b,f)], fp16 on GEMM paths; h fp32 master + fp16 mirror.
// Wt built via MFMA (E16 @ poolT16, K=16 padded to 32), write-bound epilogue.
// gemm_nt: B read node-major, in-LDS transpose w/ XOR chunk swizzle, K=128/stage.
// Per step (7 dispatches):
//   gate0 -> gemm(A@[zh0|h2],4096) -> upd0 -> gemm(A@h1->YB) -> gate1 -> gemm(A@zh1->YC) -> upd1

typedef _Float16 f16x8 __attribute__((ext_vector_type(8)));
typedef _Float16 f16x4 __attribute__((ext_vector_type(4)));
typedef float f32x4 __attribute__((ext_vector_type(4)));

// ---------------- A = softmax(relu(E E^T)) -> fp16 ----------------
__global__ __launch_bounds__(256) void compute_A_kernel(const float* __restrict__ E,
                                                        __half* __restrict__ Ah) {
  int n = blockIdx.x;
  int tid = threadIdx.x;
  __shared__ float red[256];
  float en[16];
#pragma unroll
  for (int d = 0; d < 16; ++d) en[d] = E[n * 16 + d];
  float v[4];
#pragma unroll
  for (int q = 0; q < 4; ++q) {
    int m = tid + q * 256;
    const float* Em = E + m * 16;
    float dot = 0.f;
#pragma unroll
    for (int d = 0; d < 16; ++d) dot += en[d] * Em[d];
    v[q] = fmaxf(dot, 0.f);
  }
  float mx = fmaxf(fmaxf(v[0], v[1]), fmaxf(v[2], v[3]));
  red[tid] = mx; __syncthreads();
  for (int s = 128; s > 0; s >>= 1) { if (tid < s) red[tid] = fmaxf(red[tid], red[tid + s]); __syncthreads(); }
  mx = red[0];
  __syncthreads();
  float e[4], sum = 0.f;
#pragma unroll
  for (int q = 0; q < 4; ++q) { e[q] = expf(v[q] - mx); sum += e[q]; }
  red[tid] = sum; __syncthreads();
  for (int s = 128; s > 0; s >>= 1) { if (tid < s) red[tid] += red[tid + s]; __syncthreads(); }
  float inv = 1.f / red[0];
#pragma unroll
  for (int q = 0; q < 4; ++q) Ah[(size_t)n * 1024 + tid + q * 256] = __float2half(e[q] * inv);
}

// ---------------- E16[n][d] fp16, d padded 16->32 with zeros ----------------
__global__ void build_e16_kernel(const float* __restrict__ E, __half* __restrict__ E16) {
  int t = blockIdx.x * 256 + threadIdx.x;
  if (t >= 1024 * 32) return;
  int d = t & 31;
  E16[t] = (d < 16) ? __float2half(E[(t >> 5) * 16 + d]) : __half(0);
}

// ---------------- poolT16[j][d]: K-contiguous fp16 pool, j = (seg, o, kip) ----------------
// seg j-counts: G0 20480, U0 10240, G1 32768, U1 16384 (total 79872); d padded to 32.
__global__ void pool_t16_kernel(const float* __restrict__ gw0, const float* __restrict__ uw0,
                                const float* __restrict__ gw1, const float* __restrict__ uw1,
                                __half* __restrict__ poolT16) {
  int t = blockIdx.x * 256 + threadIdx.x;
  if (t >= 79872 * 32) return;
  int d = t & 31, j = t >> 5;
  if (d >= 16) { poolT16[t] = __half(0); return; }
  const float* pool; int F, Fp, O, loc;
  if (j < 20480)      { pool = gw0; F = 66;  Fp = 80;  O = 128; loc = j; }
  else if (j < 30720) { pool = uw0; F = 66;  Fp = 80;  O = 64;  loc = j - 20480; }
  else if (j < 63488) { pool = gw1; F = 128; Fp = 128; O = 128; loc = j - 30720; }
  else                { pool = uw1; F = 128; Fp = 128; O = 64;  loc = j - 63488; }
  int KIp = 2 * Fp;
  int o = loc / KIp, kip = loc - o * KIp;
  int kk = (kip >= Fp) ? 1 : 0;
  int jj = kip - kk * Fp;
  int i;
  if (F == Fp) i = jj;
  else i = (jj < 64) ? jj + 2 : (jj < 66 ? jj - 64 : -1);
  poolT16[t] = (i >= 0) ? __float2half(pool[(((size_t)d * 2 + kk) * F + i) * O + o]) : __half(0);
}

// ---------------- Wt via MFMA: Wt[n][j] = sum_d E16[n,d] * poolT16[j,d] ----------------
// grid (312, 16): 256-j tiles (seg boundaries are 256-aligned), 64-node groups.
__global__ __launch_bounds__(256) void make_wt_mfma_kernel(
    const __half* __restrict__ E16g, const __half* __restrict__ poolT16g,
    __half* __restrict__ WtG0, __half* __restrict__ WtU0,
    __half* __restrict__ WtG1, __half* __restrict__ WtU1) {
  __shared__ __align__(16) _Float16 Es[64][40];
  __shared__ __align__(16) _Float16 wbuf[64][264];
  const _Float16* E16 = (const _Float16*)E16g;
  const _Float16* pT = (const _Float16*)poolT16g;
  int bx = blockIdx.x;
  __half* Wt; int OK, jbase;
  if (bx < 80)       { Wt = WtG0; OK = 128 * 160; jbase = bx * 256; }
  else if (bx < 120) { Wt = WtU0; OK = 64 * 160;  jbase = (bx - 80) * 256; }
  else if (bx < 248) { Wt = WtG1; OK = 128 * 256; jbase = (bx - 120) * 256; }
  else               { Wt = WtU1; OK = 64 * 256;  jbase = (bx - 248) * 256; }
  int jglob0 = bx * 256;
  int n0 = blockIdx.y * 64;
  {
    int r = threadIdx.x >> 2, ch = (threadIdx.x & 3) * 8;
    *(f16x8*)&Es[r][ch] = *(const f16x8*)(E16 + (size_t)(n0 + r) * 32 + ch);
  }
  __syncthreads();
  int wave = threadIdx.x >> 6, lane = threadIdx.x & 63;
  int fm = lane & 15, fg = lane >> 4;
  f16x8 af[4];
#pragma unroll
  for (int i = 0; i < 4; ++i) af[i] = *(const f16x8*)&Es[i * 16 + fm][fg * 8];
  f32x4 acc[4][4] = {};
#pragma unroll
  for (int j = 0; j < 4; ++j) {
    int jc = jglob0 + wave * 64 + j * 16 + fm;
    f16x8 bf = *(const f16x8*)(pT + (size_t)jc * 32 + fg * 8);
#pragma unroll
    for (int i = 0; i < 4; ++i)
      acc[i][j] = __builtin_amdgcn_mfma_f32_16x16x32_f16(af[i], bf, acc[i][j], 0, 0, 0);
  }
#pragma unroll
  for (int i = 0; i < 4; ++i)
#pragma unroll
    for (int j = 0; j < 4; ++j)
#pragma unroll
      for (int r = 0; r < 4; ++r)
        wbuf[i * 16 + fg * 4 + r][wave * 64 + j * 16 + fm] = (_Float16)acc[i][j][r];
  __syncthreads();
  // coalesced write: per node, 256 j are address-contiguous within the segment
  for (int idx = threadIdx.x; idx < 64 * 32; idx += 256) {
    int nsub = idx >> 5, pos = (idx & 31) * 8;
    *(float4*)(Wt + (size_t)(n0 + nsub) * OK + jbase + pos) = *(float4*)&wbuf[nsub][pos];
  }
}

// ---------------- merged per-node biases ----------------
__global__ void make_b_all_kernel(const float* __restrict__ E,
                                  const float* __restrict__ gb0, const float* __restrict__ ub0,
                                  const float* __restrict__ gb1, const float* __restrict__ ub1,
                                  float* __restrict__ Bg0, float* __restrict__ Bu0,
                                  float* __restrict__ Bg1, float* __restrict__ Bu1) {
  int tid = blockIdx.x * 256 + threadIdx.x;
  if (tid >= 1024 * 384) return;
  int n = tid / 384, c = tid - n * 384;
  const float* pool; float* outp; int O, o;
  if (c < 128)      { pool = gb0; outp = Bg0; O = 128; o = c; }
  else if (c < 192) { pool = ub0; outp = Bu0; O = 64;  o = c - 128; }
  else if (c < 320) { pool = gb1; outp = Bg1; O = 128; o = c - 192; }
  else              { pool = ub1; outp = Bu1; O = 64;  o = c - 320; }
  const float* En = E + n * 16;
  float a = 0.f;
#pragma unroll
  for (int d = 0; d < 16; ++d) a += En[d] * pool[d * O + o];
  outp[n * O + o] = a;
}

__global__ void zero_kernel(float* __restrict__ p, int count) {
  int i = blockIdx.x * 256 + threadIdx.x;
  if (i < count) p[i] = 0.f;
}

// ---------------- x16[n][t*64+b*2+cc] = src[b][t][n][cc], fp16 node-major ----------------
__global__ void build_x16_kernel(const float* __restrict__ src, __half* __restrict__ x16) {
  int bid = blockIdx.x; int t = bid >> 5, b = bid & 31;   // 384 blocks
  const float* s = src + (size_t)(b * 12 + t) * 2048;
  __half* dst = x16 + t * 64 + b * 2;
  for (int n = threadIdx.x; n < 1024; n += 256) {
    float2 v = *(const float2*)(s + n * 2);
    *(__half2*)(dst + (size_t)n * 768) = __floats2half2_rn(v.x, v.y);
  }
}

// ---------------- gemm_nt: Y[1024 x Nc] = Ah @ X, X node-major [k][c]; K=128/stage ----------------
// 64x64 tile, reg double-buffer. B transposed during staging: thread (kq=tid&31,cg=tid>>5)
// loads rows 4kq..4kq+3 x 8 cols; per col one b64 write of 4 packed k's into
// Bs[c][ (chunk^(c&7))*8 + k0&7 ]. Frag reads b128 at swizzled chunk.
__global__ __launch_bounds__(256) void gemm_nt_kernel(
    const __half* __restrict__ Ahg, const __half* __restrict__ X0g,
    const __half* __restrict__ X1g, __half* __restrict__ Yg,
    int Nc, int cstride, int split) {
  __shared__ __align__(16) _Float16 As[64][136];
  __shared__ __align__(16) _Float16 Bs[64][144];
  const _Float16* __restrict__ Ah = (const _Float16*)Ahg;
  _Float16* __restrict__ Y = (_Float16*)Yg;
  int tid = threadIdx.x;
  int row0 = blockIdx.y * 64;
  int col0 = blockIdx.x * 64;
  const _Float16* __restrict__ Xsrc =
      (col0 < split) ? (const _Float16*)X0g : (const _Float16*)X1g;
  int colg = (col0 < split) ? col0 : col0 - split;
  int wave = tid >> 6, lane = tid & 63;
  int wm = wave & 1, wn = wave >> 1;
  int fm = lane & 15, fg = lane >> 4;

  // A staging: 64 rows x 128 K per stage; thread: row sr, 32 halves at sc
  int sr = tid >> 2, sc = (tid & 3) * 32;
  const _Float16* pa = Ah + (size_t)(row0 + sr) * 1024 + sc;
  // B staging: rows 4kq..4kq+3, cols cg*8..+7
  int kq = tid & 31, cg = tid >> 5;
  int kb = 4 * kq;
  const _Float16* pb = Xsrc + (size_t)kb * cstride + colg + cg * 8;
  int chunk = kq >> 1;          // (4kq)>>3
  int kin = (kq & 1) * 4;       // (4kq)&7

  // stage-0 prefetch
  f16x8 ra[4], rb[4];
#pragma unroll
  for (int c = 0; c < 4; ++c) ra[c] = *(const f16x8*)(pa + c * 8);
#pragma unroll
  for (int r = 0; r < 4; ++r) rb[r] = *(const f16x8*)(pb + (size_t)r * cstride);

  f32x4 acc[2][2] = {};
  for (int k0 = 0; k0 < 1024; k0 += 128) {
#pragma unroll
    for (int c = 0; c < 4; ++c) *(f16x8*)&As[sr][sc + c * 8] = ra[c];
#pragma unroll
    for (int i = 0; i < 8; ++i) {
      int c = cg * 8 + i;
      f16x4 p;
      p[0] = rb[0][i]; p[1] = rb[1][i]; p[2] = rb[2][i]; p[3] = rb[3][i];
      *(f16x4*)&Bs[c][((chunk ^ (c & 7)) << 3) + kin] = p;
    }
    __syncthreads();
    if (k0 + 128 < 1024) {       // prefetch next stage; latency overlaps compute
#pragma unroll
      for (int c = 0; c < 4; ++c) ra[c] = *(const f16x8*)(pa + k0 + 128 + c * 8);
#pragma unroll
      for (int r = 0; r < 4; ++r)
        rb[r] = *(const f16x8*)(pb + (size_t)(k0 + 128 + r) * cstride);
    }
#pragma unroll
    for (int kc = 0; kc < 4; ++kc) {
      int ck = kc * 4 + fg;
      f16x8 af[2], bf[2];
#pragma unroll
      for (int i = 0; i < 2; ++i)
        af[i] = *(const f16x8*)&As[wm * 32 + i * 16 + fm][kc * 32 + fg * 8];
#pragma unroll
      for (int j = 0; j < 2; ++j) {
        int cl = wn * 32 + j * 16 + fm;
        bf[j] = *(const f16x8*)&Bs[cl][(ck ^ (cl & 7)) << 3];
      }
#pragma unroll
      for (int i = 0; i < 2; ++i)
#pragma unroll
        for (int j = 0; j < 2; ++j)
          acc[i][j] = __builtin_amdgcn_mfma_f32_16x16x32_f16(af[i], bf[j], acc[i][j], 0, 0, 0);
    }
    __syncthreads();
  }
#pragma unroll
  for (int i = 0; i < 2; ++i) {
#pragma unroll
    for (int j = 0; j < 2; ++j) {
      int col = col0 + wn * 32 + j * 16 + fm;
      int rbase = row0 + wm * 32 + i * 16 + fg * 4;
#pragma unroll
      for (int r = 0; r < 4; ++r)
        Y[(size_t)(rbase + r) * Nc + col] = (_Float16)acc[i][j][r];
    }
  }
}

// ---------------- gate L0: zr = sigmoid([h1|x | Ah1|Ax] @ Wt + B); zh=z*h32; rbuf=r ----------------
__global__ __launch_bounds__(256) void gate0_kernel(
    const __half* __restrict__ h16, const __half* __restrict__ YB,
    const float* __restrict__ src, const __half* __restrict__ Axt, int tstep,
    const __half* __restrict__ Wtg, const float* __restrict__ Bg,
    const float* __restrict__ h32, __half* __restrict__ zh, float* __restrict__ rbuf) {
  constexpr int KIP = 160, STRIDE = 168;
  __shared__ __align__(16) _Float16 Xs[32 * STRIDE];
  int n = blockIdx.x;
  int t = threadIdx.x;
#pragma unroll
  for (int u = 0; u < 2; ++u) {
    int idx = t + u * 256;
    int b = idx >> 4, part = (idx >> 3) & 1, ch = idx & 7;
    const _Float16* s = part ? (const _Float16*)YB + (size_t)n * 2048 + b * 64 + ch * 8
                             : (const _Float16*)h16 + (size_t)n * 2048 + b * 64 + ch * 8;
    *(f16x8*)&Xs[b * STRIDE + part * 80 + ch * 8] = *(const f16x8*)s;
  }
  if (t < 32) {
    int b = t;
    float2 xv = *(const float2*)(src + ((size_t)(b * 12 + tstep) * 1024 + n) * 2);
    Xs[b * STRIDE + 64] = (_Float16)xv.x;
    Xs[b * STRIDE + 65] = (_Float16)xv.y;
    const _Float16* ax = (const _Float16*)Axt + (size_t)n * 768 + tstep * 64 + b * 2;
    Xs[b * STRIDE + 144] = ax[0];
    Xs[b * STRIDE + 145] = ax[1];
  }
  for (int idx = t; idx < 896; idx += 256) {
    int b = idx / 28, jj = idx % 28;
    int col = (jj < 14) ? 66 + jj : 132 + jj;
    Xs[b * STRIDE + col] = (_Float16)0.f;
  }
  __syncthreads();
  int wave = t >> 6, lane = t & 63;
  int fm = lane & 15, fg = lane >> 4;
  f32x4 acc[2][2] = {};
  const _Float16* Wn = (const _Float16*)Wtg + ((size_t)n * 128 + wave * 32) * KIP;
#pragma unroll
  for (int kc = 0; kc < KIP / 32; ++kc) {
    f16x8 af[2], bf[2];
#pragma unroll
    for (int i = 0; i < 2; ++i)
      af[i] = *(const f16x8*)&Xs[(i * 16 + fm) * STRIDE + kc * 32 + fg * 8];
#pragma unroll
    for (int j = 0; j < 2; ++j)
      bf[j] = *(const f16x8*)(Wn + (size_t)(j * 16 + fm) * KIP + kc * 32 + fg * 8);
#pragma unroll
    for (int i = 0; i < 2; ++i)
#pragma unroll
      for (int j = 0; j < 2; ++j)
        acc[i][j] = __builtin_amdgcn_mfma_f32_16x16x32_f16(af[i], bf[j], acc[i][j], 0, 0, 0);
  }
  const float* Bn = Bg + n * 128;
#pragma unroll
  for (int j = 0; j < 2; ++j) {
    int o = wave * 32 + j * 16 + fm;
    float bias = Bn[o];
#pragma unroll
    for (int i = 0; i < 2; ++i)
#pragma unroll
      for (int r = 0; r < 4; ++r) {
        int b = i * 16 + fg * 4 + r;
        float s = 1.f / (1.f + __expf(-(acc[i][j][r] + bias)));
        size_t base = (size_t)n * 2048 + b * 64;
        if (o < 64) zh[base + o] = __float2half(s * h32[base + o]);
        else        rbuf[base + o - 64] = s;
      }
  }
}

// ---------------- upd L0: hc = tanh([zh|x | Azh|Ax] @ Wt + B); h = r*h + (1-r)*hc ----------------
__global__ __launch_bounds__(256) void upd0_kernel(
    const __half* __restrict__ zh, const __half* __restrict__ YA2,
    const float* __restrict__ src, const __half* __restrict__ Axt, int tstep,
    const __half* __restrict__ Wtg, const float* __restrict__ Bu,
    const float* __restrict__ rbuf, float* __restrict__ h32, __half* __restrict__ h16) {
  constexpr int KIP = 160, STRIDE = 168;
  __shared__ __align__(16) _Float16 Xs[32 * STRIDE];
  int n = blockIdx.x;
  int t = threadIdx.x;
#pragma unroll
  for (int u = 0; u < 2; ++u) {
    int idx = t + u * 256;
    int b = idx >> 4, part = (idx >> 3) & 1, ch = idx & 7;
    const _Float16* s = part ? (const _Float16*)YA2 + (size_t)n * 4096 + b * 64 + ch * 8
                             : (const _Float16*)zh + (size_t)n * 2048 + b * 64 + ch * 8;
    *(f16x8*)&Xs[b * STRIDE + part * 80 + ch * 8] = *(const f16x8*)s;
  }
  if (t < 32) {
    int b = t;
    float2 xv = *(const float2*)(src + ((size_t)(b * 12 + tstep) * 1024 + n) * 2);
    Xs[b * STRIDE + 64] = (_Float16)xv.x;
    Xs[b * STRIDE + 65] = (_Float16)xv.y;
    const _Float16* ax = (const _Float16*)Axt + (size_t)n * 768 + tstep * 64 + b * 2;
    Xs[b * STRIDE + 144] = ax[0];
    Xs[b * STRIDE + 145] = ax[1];
  }
  for (int idx = t; idx < 896; idx += 256) {
    int b = idx / 28, jj = idx % 28;
    int col = (jj < 14) ? 66 + jj : 132 + jj;
    Xs[b * STRIDE + col] = (_Float16)0.f;
  }
  __syncthreads();
  int wave = t >> 6, lane = t & 63;
  int fm = lane & 15, fg = lane >> 4;
  f32x4 acc[2] = {};
  const _Float16* Wn = (const _Float16*)Wtg + ((size_t)n * 64 + wave * 16) * KIP;
#pragma unroll
  for (int kc = 0; kc < KIP / 32; ++kc) {
    f16x8 bf = *(const f16x8*)(Wn + (size_t)fm * KIP + kc * 32 + fg * 8);
#pragma unroll
    for (int i = 0; i < 2; ++i) {
      f16x8 af = *(const f16x8*)&Xs[(i * 16 + fm) * STRIDE + kc * 32 + fg * 8];
      acc[i] = __builtin_amdgcn_mfma_f32_16x16x32_f16(af, bf, acc[i], 0, 0, 0);
    }
  }
  int o = wave * 16 + fm;
  float bias = Bu[n * 64 + o];
#pragma unroll
  for (int i = 0; i < 2; ++i)
#pragma unroll
    for (int r = 0; r < 4; ++r) {
      int b = i * 16 + fg * 4 + r;
      float x = acc[i][r] + bias;
      x = fminf(fmaxf(x, -15.f), 15.f);
      float e = __expf(2.f * x);
      float hc = (e - 1.f) / (e + 1.f);
      size_t base = (size_t)n * 2048 + b * 64;
      float rr = rbuf[base + o];
      float hnew = rr * h32[base + o] + (1.f - rr) * hc;
      h32[base + o] = hnew;
      h16[base + o] = __float2half(hnew);
    }
}

// ---------------- gate L1: zr = sigmoid([h1|h2 | Ah1|Ah2] @ Wt + B) ----------------
__global__ __launch_bounds__(256) void gate1_kernel(
    const __half* __restrict__ h1_16, const __half* __restrict__ h2_16,
    const __half* __restrict__ YB, const __half* __restrict__ YA2,
    const __half* __restrict__ Wtg, const float* __restrict__ Bg,
    const float* __restrict__ h32, __half* __restrict__ zh, float* __restrict__ rbuf) {
  constexpr int KIP = 256, STRIDE = 264;
  __shared__ __align__(16) _Float16 Xs[32 * STRIDE];
  int n = blockIdx.x;
  int t = threadIdx.x;
#pragma unroll
  for (int u = 0; u < 4; ++u) {
    int idx = t + u * 256;
    int b = idx >> 5, q = idx & 31;
    const _Float16* s;
    if (q < 8)       s = (const _Float16*)h1_16 + (size_t)n * 2048 + b * 64 + q * 8;
    else if (q < 16) s = (const _Float16*)h2_16 + (size_t)n * 2048 + b * 64 + (q - 8) * 8;
    else if (q < 24) s = (const _Float16*)YB + (size_t)n * 2048 + b * 64 + (q - 16) * 8;
    else             s = (const _Float16*)YA2 + (size_t)n * 4096 + 2048 + b * 64 + (q - 24) * 8;
    *(f16x8*)&Xs[b * STRIDE + q * 8] = *(const f16x8*)s;
  }
  __syncthreads();
  int wave = t >> 6, lane = t & 63;
  int fm = lane & 15, fg = lane >> 4;
  f32x4 acc[2][2] = {};
  const _Float16* Wn = (const _Float16*)Wtg + ((size_t)n * 128 + wave * 32) * KIP;
#pragma unroll
  for (int kc = 0; kc < KIP / 32; ++kc) {
    f16x8 af[2], bf[2];
#pragma unroll
    for (int i = 0; i < 2; ++i)
      af[i] = *(const f16x8*)&Xs[(i * 16 + fm) * STRIDE + kc * 32 + fg * 8];
#pragma unroll
    for (int j = 0; j < 2; ++j)
      bf[j] = *(const f16x8*)(Wn + (size_t)(j * 16 + fm) * KIP + kc * 32 + fg * 8);
#pragma unroll
    for (int i = 0; i < 2; ++i)
#pragma unroll
      for (int j = 0; j < 2; ++j)
        acc[i][j] = __builtin_amdgcn_mfma_f32_16x16x32_f16(af[i], bf[j], acc[i][j], 0, 0, 0);
  }
  const float* Bn = Bg + n * 128;
#pragma unroll
  for (int j = 0; j < 2; ++j) {
    int o = wave * 32 + j * 16 + fm;
    float bias = Bn[o];
#pragma unroll
    for (int i = 0; i < 2; ++i)
#pragma unroll
      for (int r = 0; r < 4; ++r) {
        int b = i * 16 + fg * 4 + r;
        float s = 1.f / (1.f + __expf(-(acc[i][j][r] + bias)));
        size_t base = (size_t)n * 2048 + b * 64;
        if (o < 64) zh[base + o] = __float2half(s * h32[base + o]);
        else        rbuf[base + o - 64] = s;
      }
  }
}

// ---------------- upd L1: hc = tanh([h1|zh | Ah1|Azh] @ Wt + B); h2 = r*h2 + (1-r)*hc ----------------
__global__ __launch_bounds__(256) void upd1_kernel(
    const __half* __restrict__ h1_16, const __half* __restrict__ zh,
    const __half* __restrict__ YB, const __half* __restrict__ YC,
    const __half* __restrict__ Wtg, const float* __restrict__ Bu,
    const float* __restrict__ rbuf, float* __restrict__ h32, __half* __restrict__ h16) {
  constexpr int KIP = 256, STRIDE = 264;
  __shared__ __align__(16) _Float16 Xs[32 * STRIDE];
  int n = blockIdx.x;
  int t = threadIdx.x;
#pragma unroll
  for (int u = 0; u < 4; ++u) {
    int idx = t + u * 256;
    int b = idx >> 5, q = idx & 31;
    const _Float16* s;
    if (q < 8)       s = (const _Float16*)h1_16 + (size_t)n * 2048 + b * 64 + q * 8;
    else if (q < 16) s = (const _Float16*)zh + (size_t)n * 2048 + b * 64 + (q - 8) * 8;
    else if (q < 24) s = (const _Float16*)YB + (size_t)n * 2048 + b * 64 + (q - 16) * 8;
    else             s = (const _Float16*)YC + (size_t)n * 2048 + b * 64 + (q - 24) * 8;
    *(f16x8*)&Xs[b * STRIDE + q * 8] = *(const f16x8*)s;
  }
  __syncthreads();
  int wave = t >> 6, lane = t & 63;
  int fm = lane & 15, fg = lane >> 4;
  f32x4 acc[2] = {};
  const _Float16* Wn = (const _Float16*)Wtg + ((size_t)n * 64 + wave * 16) * KIP;
#pragma unroll
  for (int kc = 0; kc < KIP / 32; ++kc) {
    f16x8 bf = *(const f16x8*)(Wn + (size_t)fm * KIP + kc * 32 + fg * 8);
#pragma unroll
    for (int i = 0; i < 2; ++i) {
      f16x8 af = *(const f16x8*)&Xs[(i * 16 + fm) * STRIDE + kc * 32 + fg * 8];
      acc[i] = __builtin_amdgcn_mfma_f32_16x16x32_f16(af, bf, acc[i], 0, 0, 0);
    }
  }
  int o = wave * 16 + fm;
  float bias = Bu[n * 64 + o];
#pragma unroll
  for (int i = 0; i < 2; ++i)
#pragma unroll
    for (int r = 0; r < 4; ++r) {
      int b = i * 16 + fg * 4 + r;
      float x = acc[i][r] + bias;
      x = fminf(fmaxf(x, -15.f), 15.f);
      float e = __expf(2.f * x);
      float hc = (e - 1.f) / (e + 1.f);
      size_t base = (size_t)n * 2048 + b * 64;
      float rr = rbuf[base + o];
      float hnew = rr * h32[base + o] + (1.f - rr) * hc;
      h32[base + o] = hnew;
      h16[base + o] = __float2half(hnew);
    }
}

// ---------------- out[b,o,n] = h2[n,b,:] . conv_w[o,:] + conv_b[o] ----------------
__global__ void final_conv_kernel(const float* __restrict__ h2, const float* __restrict__ cw,
                                  const float* __restrict__ cb, float* __restrict__ out) {
  int tid = blockIdx.x * 256 + threadIdx.x;
  if (tid >= 32 * 1024) return;
  int n = tid & 1023, b = tid >> 10;
  const float* hp = h2 + ((size_t)n * 32 + b) * 64;
  float hv[64];
#pragma unroll
  for (int i = 0; i < 64; ++i) hv[i] = hp[i];
#pragma unroll
  for (int o = 0; o < 12; ++o) {
    float acc = cb[o];
#pragma unroll
    for (int i = 0; i < 64; ++i) acc += hv[i] * cw[o * 64 + i];
    out[((size_t)b * 12 + o) * 1024 + n] = acc;
  }
}

extern "C" void kernel_launch(void* const* d_in, const int* in_sizes, int n_in,
                              void* d_out, int out_size, void* d_ws, size_t ws_size,
                              hipStream_t stream) {
  const float* src = (const float*)d_in[0];
  const float* E   = (const float*)d_in[1];
  const float* gw0 = (const float*)d_in[2];
  const float* gb0 = (const float*)d_in[3];
  const float* uw0 = (const float*)d_in[4];
  const float* ub0 = (const float*)d_in[5];
  const float* gw1 = (const float*)d_in[6];
  const float* gb1 = (const float*)d_in[7];
  const float* uw1 = (const float*)d_in[8];
  const float* ub1 = (const float*)d_in[9];
  const float* cw  = (const float*)d_in[10];
  const float* cb  = (const float*)d_in[11];
  float* out = (float*)d_out;
  (void)in_sizes; (void)n_in; (void)out_size; (void)ws_size;

  char* base = (char*)d_ws;
  size_t off = 0;
  auto alloc = [&](size_t bytes) -> void* {
    void* p = base + off; off += (bytes + 511) & ~(size_t)511; return p;
  };
  __half* Ah   = (__half*)alloc((size_t)1024 * 1024 * 2);           //   2.1 MB
  __half* WtG0 = (__half*)alloc((size_t)1024 * 128 * 160 * 2);      //  41.9 MB
  __half* WtU0 = (__half*)alloc((size_t)1024 * 64 * 160 * 2);       //  21.0 MB
  __half* WtG1 = (__half*)alloc((size_t)1024 * 128 * 256 * 2);      //  67.1 MB
  __half* WtU1 = (__half*)alloc((size_t)1024 * 64 * 256 * 2);       //  33.6 MB
  float*  Bg0  = (float*) alloc((size_t)1024 * 128 * 4);
  float*  Bu0  = (float*) alloc((size_t)1024 * 64 * 4);
  float*  Bg1  = (float*) alloc((size_t)1024 * 128 * 4);
  float*  Bu1  = (float*) alloc((size_t)1024 * 64 * 4);
  // zero-initialized region (contiguous): h1_32, h2_32, h1_16, h2_16, YB
  float*  h1_32 = (float*)alloc((size_t)1024 * 2048 * 4);           //   8.4 MB
  float*  h2_32 = (float*)alloc((size_t)1024 * 2048 * 4);           //   8.4 MB
  __half* h1_16 = (__half*)alloc((size_t)1024 * 2048 * 2);          //   4.2 MB
  __half* h2_16 = (__half*)alloc((size_t)1024 * 2048 * 2);          //   4.2 MB
  __half* YB   = (__half*)alloc((size_t)1024 * 2048 * 2);           //   4.2 MB (A@h1)
  __half* zh   = (__half*)alloc((size_t)1024 * 2048 * 2);           //   4.2 MB
  __half* YA2  = (__half*)alloc((size_t)1024 * 4096 * 2);           //   8.4 MB ([A@zh0 | A@h2])
  __half* YC   = (__half*)alloc((size_t)1024 * 2048 * 2);           //   4.2 MB (A@zh1)
  __half* Axt  = (__half*)alloc((size_t)1024 * 768 * 2);            //   1.5 MB (A@x all t)
  float*  rbuf = (float*) alloc((size_t)1024 * 2048 * 4);           //   8.4 MB (+ prelude scratch)
  // prelude-only overlays on rbuf: poolT16 (5.1 MB) + E16 (64 KB) + x16 (1.5 MB)
  __half* poolT16 = (__half*)rbuf;
  __half* E16  = poolT16 + (size_t)79872 * 32;
  __half* x16  = E16 + (size_t)1024 * 32;
  // total ~221 MB

  // ---- prelude (8 dispatches) ----
  compute_A_kernel<<<1024, 256, 0, stream>>>(E, Ah);
  build_e16_kernel<<<(1024 * 32 + 255) / 256, 256, 0, stream>>>(E, E16);
  pool_t16_kernel<<<(79872 * 32 + 255) / 256, 256, 0, stream>>>(gw0, uw0, gw1, uw1, poolT16);
  make_wt_mfma_kernel<<<dim3(312, 16), 256, 0, stream>>>(E16, poolT16, WtG0, WtU0, WtG1, WtU1);
  make_b_all_kernel<<<(1024 * 384 + 255) / 256, 256, 0, stream>>>(E, gb0, ub0, gb1, ub1,
                                                                  Bg0, Bu0, Bg1, Bu1);
  build_x16_kernel<<<384, 256, 0, stream>>>(src, x16);
  gemm_nt_kernel<<<dim3(12, 16), 256, 0, stream>>>(Ah, (__half*)x16, (__half*)x16, Axt,
                                                   768, 768, 768);
  zero_kernel<<<(7340032 + 255) / 256, 256, 0, stream>>>(h1_32, 7340032);

  // ---- 12 GRU steps (7 dispatches each) ----
  for (int t = 0; t < 12; ++t) {
    gate0_kernel<<<1024, 256, 0, stream>>>(h1_16, YB, src, Axt, t, WtG0, Bg0, h1_32, zh, rbuf);
    gemm_nt_kernel<<<dim3(64, 16), 256, 0, stream>>>(Ah, zh, h2_16, YA2, 4096, 2048, 2048);
    upd0_kernel<<<1024, 256, 0, stream>>>(zh, YA2, src, Axt, t, WtU0, Bu0, rbuf, h1_32, h1_16);
    gemm_nt_kernel<<<dim3(32, 16), 256, 0, stream>>>(Ah, h1_16, h1_16, YB, 2048, 2048, 2048);
    gate1_kernel<<<1024, 256, 0, stream>>>(h1_16, h2_16, YB, YA2, WtG1, Bg1, h2_32, zh, rbuf);
    gemm_nt_kernel<<<dim3(32, 16), 256, 0, stream>>>(Ah, zh, zh, YC, 2048, 2048, 2048);
    upd1_kernel<<<1024, 256, 0, stream>>>(h1_16, zh, YB, YC, WtU1, Bu1, rbuf, h2_32, h2_16);
  }

  final_conv_kernel<<<(32 * 1024 + 255) / 256, 256, 0, stream>>>(h2_32, cw, cb, out);
}

// Round 9
// 1446.100 us; speedup vs baseline: 4.6614x; 1.0487x over previous
//
#include <hip/hip_runtime.h>
#include <hip/hip_fp16.h>

// AGCRN: B=32 T=12 N=1024 C=2 D=16 H=64 K=2 OUT=12
// Node-major activations [n][(b,f)], fp16 on GEMM paths; h fp32 master + fp16 mirror.
// Per-layer gate buffers (zh0/zh1, r0/r1). upd1(t) fused with gate0(t+1) (node-local).
// gemm_nt: 64x64 tile (2048-col); gemm_nt128: 64x128 tile (4096-col YA2).
// Steady-state step (6 dispatches):
//   gemm(A@[zh0|h2],4096) -> upd0 -> gemm(A@h1->YB) -> gate1 -> gemm(A@zh1->YC) -> upd1+gate0'

typedef _Float16 f16x8 __attribute__((ext_vector_type(8)));
typedef _Float16 f16x4 __attribute__((ext_vector_type(4)));
typedef float f32x4 __attribute__((ext_vector_type(4)));

// ---------------- A = softmax(relu(E E^T)) -> fp16 ----------------
__global__ __launch_bounds__(256) void compute_A_kernel(const float* __restrict__ E,
                                                        __half* __restrict__ Ah) {
  int n = blockIdx.x;
  int tid = threadIdx.x;
  __shared__ float red[256];
  float en[16];
#pragma unroll
  for (int d = 0; d < 16; ++d) en[d] = E[n * 16 + d];
  float v[4];
#pragma unroll
  for (int q = 0; q < 4; ++q) {
    int m = tid + q * 256;
    const float* Em = E + m * 16;
    float dot = 0.f;
#pragma unroll
    for (int d = 0; d < 16; ++d) dot += en[d] * Em[d];
    v[q] = fmaxf(dot, 0.f);
  }
  float mx = fmaxf(fmaxf(v[0], v[1]), fmaxf(v[2], v[3]));
  red[tid] = mx; __syncthreads();
  for (int s = 128; s > 0; s >>= 1) { if (tid < s) red[tid] = fmaxf(red[tid], red[tid + s]); __syncthreads(); }
  mx = red[0];
  __syncthreads();
  float e[4], sum = 0.f;
#pragma unroll
  for (int q = 0; q < 4; ++q) { e[q] = expf(v[q] - mx); sum += e[q]; }
  red[tid] = sum; __syncthreads();
  for (int s = 128; s > 0; s >>= 1) { if (tid < s) red[tid] += red[tid + s]; __syncthreads(); }
  float inv = 1.f / red[0];
#pragma unroll
  for (int q = 0; q < 4; ++q) Ah[(size_t)n * 1024 + tid + q * 256] = __float2half(e[q] * inv);
}

// ---------------- E16[n][d] fp16, d padded 16->32 with zeros ----------------
__global__ void build_e16_kernel(const float* __restrict__ E, __half* __restrict__ E16) {
  int t = blockIdx.x * 256 + threadIdx.x;
  if (t >= 1024 * 32) return;
  int d = t & 31;
  E16[t] = (d < 16) ? __float2half(E[(t >> 5) * 16 + d]) : __half(0);
}

// ---------------- poolT16[j][d]: K-contiguous fp16 pool, j = (seg, o, kip) ----------------
__global__ void pool_t16_kernel(const float* __restrict__ gw0, const float* __restrict__ uw0,
                                const float* __restrict__ gw1, const float* __restrict__ uw1,
                                __half* __restrict__ poolT16) {
  int t = blockIdx.x * 256 + threadIdx.x;
  if (t >= 79872 * 32) return;
  int d = t & 31, j = t >> 5;
  if (d >= 16) { poolT16[t] = __half(0); return; }
  const float* pool; int F, Fp, O, loc;
  if (j < 20480)      { pool = gw0; F = 66;  Fp = 80;  O = 128; loc = j; }
  else if (j < 30720) { pool = uw0; F = 66;  Fp = 80;  O = 64;  loc = j - 20480; }
  else if (j < 63488) { pool = gw1; F = 128; Fp = 128; O = 128; loc = j - 30720; }
  else                { pool = uw1; F = 128; Fp = 128; O = 64;  loc = j - 63488; }
  int KIp = 2 * Fp;
  int o = loc / KIp, kip = loc - o * KIp;
  int kk = (kip >= Fp) ? 1 : 0;
  int jj = kip - kk * Fp;
  int i;
  if (F == Fp) i = jj;
  else i = (jj < 64) ? jj + 2 : (jj < 66 ? jj - 64 : -1);
  poolT16[t] = (i >= 0) ? __float2half(pool[(((size_t)d * 2 + kk) * F + i) * O + o]) : __half(0);
}

// ---------------- Wt via MFMA: Wt[n][j] = sum_d E16[n,d] * poolT16[j,d] ----------------
__global__ __launch_bounds__(256) void make_wt_mfma_kernel(
    const __half* __restrict__ E16g, const __half* __restrict__ poolT16g,
    __half* __restrict__ WtG0, __half* __restrict__ WtU0,
    __half* __restrict__ WtG1, __half* __restrict__ WtU1) {
  __shared__ __align__(16) _Float16 Es[64][40];
  __shared__ __align__(16) _Float16 wbuf[64][264];
  const _Float16* E16 = (const _Float16*)E16g;
  const _Float16* pT = (const _Float16*)poolT16g;
  int bx = blockIdx.x;
  __half* Wt; int OK, jbase;
  if (bx < 80)       { Wt = WtG0; OK = 128 * 160; jbase = bx * 256; }
  else if (bx < 120) { Wt = WtU0; OK = 64 * 160;  jbase = (bx - 80) * 256; }
  else if (bx < 248) { Wt = WtG1; OK = 128 * 256; jbase = (bx - 120) * 256; }
  else               { Wt = WtU1; OK = 64 * 256;  jbase = (bx - 248) * 256; }
  int jglob0 = bx * 256;
  int n0 = blockIdx.y * 64;
  {
    int r = threadIdx.x >> 2, ch = (threadIdx.x & 3) * 8;
    *(f16x8*)&Es[r][ch] = *(const f16x8*)(E16 + (size_t)(n0 + r) * 32 + ch);
  }
  __syncthreads();
  int wave = threadIdx.x >> 6, lane = threadIdx.x & 63;
  int fm = lane & 15, fg = lane >> 4;
  f16x8 af[4];
#pragma unroll
  for (int i = 0; i < 4; ++i) af[i] = *(const f16x8*)&Es[i * 16 + fm][fg * 8];
  f32x4 acc[4][4] = {};
#pragma unroll
  for (int j = 0; j < 4; ++j) {
    int jc = jglob0 + wave * 64 + j * 16 + fm;
    f16x8 bf = *(const f16x8*)(pT + (size_t)jc * 32 + fg * 8);
#pragma unroll
    for (int i = 0; i < 4; ++i)
      acc[i][j] = __builtin_amdgcn_mfma_f32_16x16x32_f16(af[i], bf, acc[i][j], 0, 0, 0);
  }
#pragma unroll
  for (int i = 0; i < 4; ++i)
#pragma unroll
    for (int j = 0; j < 4; ++j)
#pragma unroll
      for (int r = 0; r < 4; ++r)
        wbuf[i * 16 + fg * 4 + r][wave * 64 + j * 16 + fm] = (_Float16)acc[i][j][r];
  __syncthreads();
  for (int idx = threadIdx.x; idx < 64 * 32; idx += 256) {
    int nsub = idx >> 5, pos = (idx & 31) * 8;
    *(float4*)(Wt + (size_t)(n0 + nsub) * OK + jbase + pos) = *(float4*)&wbuf[nsub][pos];
  }
}

// ---------------- merged per-node biases ----------------
__global__ void make_b_all_kernel(const float* __restrict__ E,
                                  const float* __restrict__ gb0, const float* __restrict__ ub0,
                                  const float* __restrict__ gb1, const float* __restrict__ ub1,
                                  float* __restrict__ Bg0, float* __restrict__ Bu0,
                                  float* __restrict__ Bg1, float* __restrict__ Bu1) {
  int tid = blockIdx.x * 256 + threadIdx.x;
  if (tid >= 1024 * 384) return;
  int n = tid / 384, c = tid - n * 384;
  const float* pool; float* outp; int O, o;
  if (c < 128)      { pool = gb0; outp = Bg0; O = 128; o = c; }
  else if (c < 192) { pool = ub0; outp = Bu0; O = 64;  o = c - 128; }
  else if (c < 320) { pool = gb1; outp = Bg1; O = 128; o = c - 192; }
  else              { pool = ub1; outp = Bu1; O = 64;  o = c - 320; }
  const float* En = E + n * 16;
  float a = 0.f;
#pragma unroll
  for (int d = 0; d < 16; ++d) a += En[d] * pool[d * O + o];
  outp[n * O + o] = a;
}

__global__ void zero_kernel(float* __restrict__ p, int count) {
  int i = blockIdx.x * 256 + threadIdx.x;
  if (i < count) p[i] = 0.f;
}

// ---------------- x16[n][t*64+b*2+cc] = src[b][t][n][cc], fp16 node-major ----------------
__global__ void build_x16_kernel(const float* __restrict__ src, __half* __restrict__ x16) {
  int bid = blockIdx.x; int t = bid >> 5, b = bid & 31;
  const float* s = src + (size_t)(b * 12 + t) * 2048;
  __half* dst = x16 + t * 64 + b * 2;
  for (int n = threadIdx.x; n < 1024; n += 256) {
    float2 v = *(const float2*)(s + n * 2);
    *(__half2*)(dst + (size_t)n * 768) = __floats2half2_rn(v.x, v.y);
  }
}

// ---------------- gemm_nt: Y[1024 x Nc] = Ah @ X (64x64 tile, K=128/stage) ----------------
__global__ __launch_bounds__(256) void gemm_nt_kernel(
    const __half* __restrict__ Ahg, const __half* __restrict__ X0g,
    const __half* __restrict__ X1g, __half* __restrict__ Yg,
    int Nc, int cstride, int split) {
  __shared__ __align__(16) _Float16 As[64][136];
  __shared__ __align__(16) _Float16 Bs[64][144];
  const _Float16* __restrict__ Ah = (const _Float16*)Ahg;
  _Float16* __restrict__ Y = (_Float16*)Yg;
  int tid = threadIdx.x;
  int row0 = blockIdx.y * 64;
  int col0 = blockIdx.x * 64;
  const _Float16* __restrict__ Xsrc =
      (col0 < split) ? (const _Float16*)X0g : (const _Float16*)X1g;
  int colg = (col0 < split) ? col0 : col0 - split;
  int wave = tid >> 6, lane = tid & 63;
  int wm = wave & 1, wn = wave >> 1;
  int fm = lane & 15, fg = lane >> 4;

  int sr = tid >> 2, sc = (tid & 3) * 32;
  const _Float16* pa = Ah + (size_t)(row0 + sr) * 1024 + sc;
  int kq = tid & 31, cg = tid >> 5;
  int kb = 4 * kq;
  const _Float16* pb = Xsrc + (size_t)kb * cstride + colg + cg * 8;
  int chunk = kq >> 1;
  int kin = (kq & 1) * 4;

  f16x8 ra[4], rb[4];
#pragma unroll
  for (int c = 0; c < 4; ++c) ra[c] = *(const f16x8*)(pa + c * 8);
#pragma unroll
  for (int r = 0; r < 4; ++r) rb[r] = *(const f16x8*)(pb + (size_t)r * cstride);

  f32x4 acc[2][2] = {};
  for (int k0 = 0; k0 < 1024; k0 += 128) {
#pragma unroll
    for (int c = 0; c < 4; ++c) *(f16x8*)&As[sr][sc + c * 8] = ra[c];
#pragma unroll
    for (int i = 0; i < 8; ++i) {
      int c = cg * 8 + i;
      f16x4 p;
      p[0] = rb[0][i]; p[1] = rb[1][i]; p[2] = rb[2][i]; p[3] = rb[3][i];
      *(f16x4*)&Bs[c][((chunk ^ (c & 7)) << 3) + kin] = p;
    }
    __syncthreads();
    if (k0 + 128 < 1024) {
#pragma unroll
      for (int c = 0; c < 4; ++c) ra[c] = *(const f16x8*)(pa + k0 + 128 + c * 8);
#pragma unroll
      for (int r = 0; r < 4; ++r)
        rb[r] = *(const f16x8*)(pb + (size_t)(k0 + 128 + r) * cstride);
    }
#pragma unroll
    for (int kc = 0; kc < 4; ++kc) {
      int ck = kc * 4 + fg;
      f16x8 af[2], bf[2];
#pragma unroll
      for (int i = 0; i < 2; ++i)
        af[i] = *(const f16x8*)&As[wm * 32 + i * 16 + fm][kc * 32 + fg * 8];
#pragma unroll
      for (int j = 0; j < 2; ++j) {
        int cl = wn * 32 + j * 16 + fm;
        bf[j] = *(const f16x8*)&Bs[cl][(ck ^ (cl & 7)) << 3];
      }
#pragma unroll
      for (int i = 0; i < 2; ++i)
#pragma unroll
        for (int j = 0; j < 2; ++j)
          acc[i][j] = __builtin_amdgcn_mfma_f32_16x16x32_f16(af[i], bf[j], acc[i][j], 0, 0, 0);
    }
    __syncthreads();
  }
#pragma unroll
  for (int i = 0; i < 2; ++i) {
#pragma unroll
    for (int j = 0; j < 2; ++j) {
      int col = col0 + wn * 32 + j * 16 + fm;
      int rbase = row0 + wm * 32 + i * 16 + fg * 4;
#pragma unroll
      for (int r = 0; r < 4; ++r)
        Y[(size_t)(rbase + r) * Nc + col] = (_Float16)acc[i][j][r];
    }
  }
}

// ---------------- gemm_nt128: Y = Ah @ X, 64(M) x 128(N) tile, K=128/stage ----------------
// 4 waves, wave wn owns 32 cols (2 frags), af[4] covers all 64 rows. 6 LDS reads / 8 MFMA.
__global__ __launch_bounds__(256) void gemm_nt128_kernel(
    const __half* __restrict__ Ahg, const __half* __restrict__ X0g,
    const __half* __restrict__ X1g, __half* __restrict__ Yg,
    int Nc, int cstride, int split) {
  __shared__ __align__(16) _Float16 As[64][136];
  __shared__ __align__(16) _Float16 Bs[128][144];
  const _Float16* __restrict__ Ah = (const _Float16*)Ahg;
  _Float16* __restrict__ Y = (_Float16*)Yg;
  int tid = threadIdx.x;
  int row0 = blockIdx.y * 64;
  int col0 = blockIdx.x * 128;
  const _Float16* __restrict__ Xsrc =
      (col0 < split) ? (const _Float16*)X0g : (const _Float16*)X1g;
  int colg = (col0 < split) ? col0 : col0 - split;
  int wave = tid >> 6, lane = tid & 63;
  int fm = lane & 15, fg = lane >> 4;

  int sr = tid >> 2, sc = (tid & 3) * 32;
  const _Float16* pa = Ah + (size_t)(row0 + sr) * 1024 + sc;
  int kq = tid & 31, cg = tid >> 5;       // rows 4kq..+3, cols cg*16..+15
  int kb = 4 * kq;
  const _Float16* pb = Xsrc + (size_t)kb * cstride + colg + cg * 16;
  int chunk = kq >> 1;
  int kin = (kq & 1) * 4;

  f16x8 ra[4], rb[4][2];
#pragma unroll
  for (int c = 0; c < 4; ++c) ra[c] = *(const f16x8*)(pa + c * 8);
#pragma unroll
  for (int r = 0; r < 4; ++r)
#pragma unroll
    for (int h = 0; h < 2; ++h)
      rb[r][h] = *(const f16x8*)(pb + (size_t)r * cstride + h * 8);

  f32x4 acc[4][2] = {};
  for (int k0 = 0; k0 < 1024; k0 += 128) {
#pragma unroll
    for (int c = 0; c < 4; ++c) *(f16x8*)&As[sr][sc + c * 8] = ra[c];
#pragma unroll
    for (int h = 0; h < 2; ++h)
#pragma unroll
      for (int i = 0; i < 8; ++i) {
        int c = cg * 16 + h * 8 + i;
        f16x4 p;
        p[0] = rb[0][h][i]; p[1] = rb[1][h][i]; p[2] = rb[2][h][i]; p[3] = rb[3][h][i];
        *(f16x4*)&Bs[c][((chunk ^ (c & 7)) << 3) + kin] = p;
      }
    __syncthreads();
    if (k0 + 128 < 1024) {
#pragma unroll
      for (int c = 0; c < 4; ++c) ra[c] = *(const f16x8*)(pa + k0 + 128 + c * 8);
#pragma unroll
      for (int r = 0; r < 4; ++r)
#pragma unroll
        for (int h = 0; h < 2; ++h)
          rb[r][h] = *(const f16x8*)(pb + (size_t)(k0 + 128 + r) * cstride + h * 8);
    }
#pragma unroll
    for (int kc = 0; kc < 4; ++kc) {
      int ck = kc * 4 + fg;
      f16x8 af[4], bf[2];
#pragma unroll
      for (int i = 0; i < 4; ++i)
        af[i] = *(const f16x8*)&As[i * 16 + fm][kc * 32 + fg * 8];
#pragma unroll
      for (int j = 0; j < 2; ++j) {
        int cl = wave * 32 + j * 16 + fm;
        bf[j] = *(const f16x8*)&Bs[cl][(ck ^ (cl & 7)) << 3];
      }
#pragma unroll
      for (int i = 0; i < 4; ++i)
#pragma unroll
        for (int j = 0; j < 2; ++j)
          acc[i][j] = __builtin_amdgcn_mfma_f32_16x16x32_f16(af[i], bf[j], acc[i][j], 0, 0, 0);
    }
    __syncthreads();
  }
#pragma unroll
  for (int i = 0; i < 4; ++i) {
#pragma unroll
    for (int j = 0; j < 2; ++j) {
      int col = col0 + wave * 32 + j * 16 + fm;
      int rbase = row0 + i * 16 + fg * 4;
#pragma unroll
      for (int r = 0; r < 4; ++r)
        Y[(size_t)(rbase + r) * Nc + col] = (_Float16)acc[i][j][r];
    }
  }
}

// ---------------- gate0 body (device): zr=sigmoid([h1|x|Ah1|Ax]@WtG0+Bg0); zh0=z*h1; r0 ----------------
__device__ __forceinline__ void gate0_body(
    _Float16* Xs, int n, int t,
    const __half* __restrict__ h16, const __half* __restrict__ YB,
    const float* __restrict__ src, const __half* __restrict__ Axt, int tstep,
    const __half* __restrict__ Wtg, const float* __restrict__ Bg,
    const float* __restrict__ h32, __half* __restrict__ zh0, float* __restrict__ r0) {
  constexpr int KIP = 160, STRIDE = 168;
#pragma unroll
  for (int u = 0; u < 2; ++u) {
    int idx = t + u * 256;
    int b = idx >> 4, part = (idx >> 3) & 1, ch = idx & 7;
    const _Float16* s = part ? (const _Float16*)YB + (size_t)n * 2048 + b * 64 + ch * 8
                             : (const _Float16*)h16 + (size_t)n * 2048 + b * 64 + ch * 8;
    *(f16x8*)&Xs[b * STRIDE + part * 80 + ch * 8] = *(const f16x8*)s;
  }
  if (t < 32) {
    int b = t;
    float2 xv = *(const float2*)(src + ((size_t)(b * 12 + tstep) * 1024 + n) * 2);
    Xs[b * STRIDE + 64] = (_Float16)xv.x;
    Xs[b * STRIDE + 65] = (_Float16)xv.y;
    const _Float16* ax = (const _Float16*)Axt + (size_t)n * 768 + tstep * 64 + b * 2;
    Xs[b * STRIDE + 144] = ax[0];
    Xs[b * STRIDE + 145] = ax[1];
  }
  for (int idx = t; idx < 896; idx += 256) {
    int b = idx / 28, jj = idx % 28;
    int col = (jj < 14) ? 66 + jj : 132 + jj;
    Xs[b * STRIDE + col] = (_Float16)0.f;
  }
  __syncthreads();
  int wave = t >> 6, lane = t & 63;
  int fm = lane & 15, fg = lane >> 4;
  f32x4 acc[2][2] = {};
  const _Float16* Wn = (const _Float16*)Wtg + ((size_t)n * 128 + wave * 32) * KIP;
#pragma unroll
  for (int kc = 0; kc < KIP / 32; ++kc) {
    f16x8 af[2], bf[2];
#pragma unroll
    for (int i = 0; i < 2; ++i)
      af[i] = *(const f16x8*)&Xs[(i * 16 + fm) * STRIDE + kc * 32 + fg * 8];
#pragma unroll
    for (int j = 0; j < 2; ++j)
      bf[j] = *(const f16x8*)(Wn + (size_t)(j * 16 + fm) * KIP + kc * 32 + fg * 8);
#pragma unroll
    for (int i = 0; i < 2; ++i)
#pragma unroll
      for (int j = 0; j < 2; ++j)
        acc[i][j] = __builtin_amdgcn_mfma_f32_16x16x32_f16(af[i], bf[j], acc[i][j], 0, 0, 0);
  }
  const float* Bn = Bg + n * 128;
#pragma unroll
  for (int j = 0; j < 2; ++j) {
    int o = wave * 32 + j * 16 + fm;
    float bias = Bn[o];
#pragma unroll
    for (int i = 0; i < 2; ++i)
#pragma unroll
      for (int r = 0; r < 4; ++r) {
        int b = i * 16 + fg * 4 + r;
        float s = 1.f / (1.f + __expf(-(acc[i][j][r] + bias)));
        size_t base = (size_t)n * 2048 + b * 64;
        if (o < 64) zh0[base + o] = __float2half(s * h32[base + o]);
        else        r0[base + o - 64] = s;
      }
  }
}

// ---------------- standalone gate0 (t=0) ----------------
__global__ __launch_bounds__(256) void gate0_kernel(
    const __half* __restrict__ h16, const __half* __restrict__ YB,
    const float* __restrict__ src, const __half* __restrict__ Axt, int tstep,
    const __half* __restrict__ Wtg, const float* __restrict__ Bg,
    const float* __restrict__ h32, __half* __restrict__ zh0, float* __restrict__ r0) {
  __shared__ __align__(16) _Float16 Xs[32 * 168];
  gate0_body(Xs, blockIdx.x, threadIdx.x, h16, YB, src, Axt, tstep, Wtg, Bg, h32, zh0, r0);
}

// ---------------- upd L0: hc = tanh([zh0|x | Azh0|Ax] @ Wt + B); h1 = r0*h1 + (1-r0)*hc ----------------
__global__ __launch_bounds__(256) void upd0_kernel(
    const __half* __restrict__ zh0, const __half* __restrict__ YA2,
    const float* __restrict__ src, const __half* __restrict__ Axt, int tstep,
    const __half* __restrict__ Wtg, const float* __restrict__ Bu,
    const float* __restrict__ r0, float* __restrict__ h32, __half* __restrict__ h16) {
  constexpr int KIP = 160, STRIDE = 168;
  __shared__ __align__(16) _Float16 Xs[32 * STRIDE];
  int n = blockIdx.x;
  int t = threadIdx.x;
#pragma unroll
  for (int u = 0; u < 2; ++u) {
    int idx = t + u * 256;
    int b = idx >> 4, part = (idx >> 3) & 1, ch = idx & 7;
    const _Float16* s = part ? (const _Float16*)YA2 + (size_t)n * 4096 + b * 64 + ch * 8
                             : (const _Float16*)zh0 + (size_t)n * 2048 + b * 64 + ch * 8;
    *(f16x8*)&Xs[b * STRIDE + part * 80 + ch * 8] = *(const f16x8*)s;
  }
  if (t < 32) {
    int b = t;
    float2 xv = *(const float2*)(src + ((size_t)(b * 12 + tstep) * 1024 + n) * 2);
    Xs[b * STRIDE + 64] = (_Float16)xv.x;
    Xs[b * STRIDE + 65] = (_Float16)xv.y;
    const _Float16* ax = (const _Float16*)Axt + (size_t)n * 768 + tstep * 64 + b * 2;
    Xs[b * STRIDE + 144] = ax[0];
    Xs[b * STRIDE + 145] = ax[1];
  }
  for (int idx = t; idx < 896; idx += 256) {
    int b = idx / 28, jj = idx % 28;
    int col = (jj < 14) ? 66 + jj : 132 + jj;
    Xs[b * STRIDE + col] = (_Float16)0.f;
  }
  __syncthreads();
  int wave = t >> 6, lane = t & 63;
  int fm = lane & 15, fg = lane >> 4;
  f32x4 acc[2] = {};
  const _Float16* Wn = (const _Float16*)Wtg + ((size_t)n * 64 + wave * 16) * KIP;
#pragma unroll
  for (int kc = 0; kc < KIP / 32; ++kc) {
    f16x8 bf = *(const f16x8*)(Wn + (size_t)fm * KIP + kc * 32 + fg * 8);
#pragma unroll
    for (int i = 0; i < 2; ++i) {
      f16x8 af = *(const f16x8*)&Xs[(i * 16 + fm) * STRIDE + kc * 32 + fg * 8];
      acc[i] = __builtin_amdgcn_mfma_f32_16x16x32_f16(af, bf, acc[i], 0, 0, 0);
    }
  }
  int o = wave * 16 + fm;
  float bias = Bu[n * 64 + o];
#pragma unroll
  for (int i = 0; i < 2; ++i)
#pragma unroll
    for (int r = 0; r < 4; ++r) {
      int b = i * 16 + fg * 4 + r;
      float x = acc[i][r] + bias;
      x = fminf(fmaxf(x, -15.f), 15.f);
      float e = __expf(2.f * x);
      float hc = (e - 1.f) / (e + 1.f);
      size_t base = (size_t)n * 2048 + b * 64;
      float rr = r0[base + o];
      float hnew = rr * h32[base + o] + (1.f - rr) * hc;
      h32[base + o] = hnew;
      h16[base + o] = __float2half(hnew);
    }
}

// ---------------- gate L1: zr = sigmoid([h1|h2 | Ah1|Ah2] @ Wt + B); zh1=z*h2; r1 ----------------
__global__ __launch_bounds__(256) void gate1_kernel(
    const __half* __restrict__ h1_16, const __half* __restrict__ h2_16,
    const __half* __restrict__ YB, const __half* __restrict__ YA2,
    const __half* __restrict__ Wtg, const float* __restrict__ Bg,
    const float* __restrict__ h32, __half* __restrict__ zh1, float* __restrict__ r1) {
  constexpr int KIP = 256, STRIDE = 264;
  __shared__ __align__(16) _Float16 Xs[32 * STRIDE];
  int n = blockIdx.x;
  int t = threadIdx.x;
#pragma unroll
  for (int u = 0; u < 4; ++u) {
    int idx = t + u * 256;
    int b = idx >> 5, q = idx & 31;
    const _Float16* s;
    if (q < 8)       s = (const _Float16*)h1_16 + (size_t)n * 2048 + b * 64 + q * 8;
    else if (q < 16) s = (const _Float16*)h2_16 + (size_t)n * 2048 + b * 64 + (q - 8) * 8;
    else if (q < 24) s = (const _Float16*)YB + (size_t)n * 2048 + b * 64 + (q - 16) * 8;
    else             s = (const _Float16*)YA2 + (size_t)n * 4096 + 2048 + b * 64 + (q - 24) * 8;
    *(f16x8*)&Xs[b * STRIDE + q * 8] = *(const f16x8*)s;
  }
  __syncthreads();
  int wave = t >> 6, lane = t & 63;
  int fm = lane & 15, fg = lane >> 4;
  f32x4 acc[2][2] = {};
  const _Float16* Wn = (const _Float16*)Wtg + ((size_t)n * 128 + wave * 32) * KIP;
#pragma unroll
  for (int kc = 0; kc < KIP / 32; ++kc) {
    f16x8 af[2], bf[2];
#pragma unroll
    for (int i = 0; i < 2; ++i)
      af[i] = *(const f16x8*)&Xs[(i * 16 + fm) * STRIDE + kc * 32 + fg * 8];
#pragma unroll
    for (int j = 0; j < 2; ++j)
      bf[j] = *(const f16x8*)(Wn + (size_t)(j * 16 + fm) * KIP + kc * 32 + fg * 8);
#pragma unroll
    for (int i = 0; i < 2; ++i)
#pragma unroll
      for (int j = 0; j < 2; ++j)
        acc[i][j] = __builtin_amdgcn_mfma_f32_16x16x32_f16(af[i], bf[j], acc[i][j], 0, 0, 0);
  }
  const float* Bn = Bg + n * 128;
#pragma unroll
  for (int j = 0; j < 2; ++j) {
    int o = wave * 32 + j * 16 + fm;
    float bias = Bn[o];
#pragma unroll
    for (int i = 0; i < 2; ++i)
#pragma unroll
      for (int r = 0; r < 4; ++r) {
        int b = i * 16 + fg * 4 + r;
        float s = 1.f / (1.f + __expf(-(acc[i][j][r] + bias)));
        size_t base = (size_t)n * 2048 + b * 64;
        if (o < 64) zh1[base + o] = __float2half(s * h32[base + o]);
        else        r1[base + o - 64] = s;
      }
  }
}

// ---------------- fused upd1(t) + gate0(t+1) ----------------
__global__ __launch_bounds__(256) void upd1_gate0_kernel(
    const __half* __restrict__ h1_16, const __half* __restrict__ zh1,
    const __half* __restrict__ YB, const __half* __restrict__ YC,
    const __half* __restrict__ WtU1, const float* __restrict__ Bu1,
    const float* __restrict__ r1, float* __restrict__ h2_32, __half* __restrict__ h2_16,
    // gate0(t+1) part:
    const float* __restrict__ src, const __half* __restrict__ Axt, int tnext,
    const __half* __restrict__ WtG0, const float* __restrict__ Bg0,
    const float* __restrict__ h1_32, __half* __restrict__ zh0, float* __restrict__ r0,
    int do_gate0) {
  constexpr int KIP = 256, STRIDE = 264;
  __shared__ __align__(16) _Float16 Xs[32 * STRIDE];
  int n = blockIdx.x;
  int t = threadIdx.x;
  // ---- phase 1: upd1 ----
#pragma unroll
  for (int u = 0; u < 4; ++u) {
    int idx = t + u * 256;
    int b = idx >> 5, q = idx & 31;
    const _Float16* s;
    if (q < 8)       s = (const _Float16*)h1_16 + (size_t)n * 2048 + b * 64 + q * 8;
    else if (q < 16) s = (const _Float16*)zh1 + (size_t)n * 2048 + b * 64 + (q - 8) * 8;
    else if (q < 24) s = (const _Float16*)YB + (size_t)n * 2048 + b * 64 + (q - 16) * 8;
    else             s = (const _Float16*)YC + (size_t)n * 2048 + b * 64 + (q - 24) * 8;
    *(f16x8*)&Xs[b * STRIDE + q * 8] = *(const f16x8*)s;
  }
  __syncthreads();
  int wave = t >> 6, lane = t & 63;
  int fm = lane & 15, fg = lane >> 4;
  {
    f32x4 acc[2] = {};
    const _Float16* Wn = (const _Float16*)WtU1 + ((size_t)n * 64 + wave * 16) * KIP;
#pragma unroll
    for (int kc = 0; kc < KIP / 32; ++kc) {
      f16x8 bf = *(const f16x8*)(Wn + (size_t)fm * KIP + kc * 32 + fg * 8);
#pragma unroll
      for (int i = 0; i < 2; ++i) {
        f16x8 af = *(const f16x8*)&Xs[(i * 16 + fm) * STRIDE + kc * 32 + fg * 8];
        acc[i] = __builtin_amdgcn_mfma_f32_16x16x32_f16(af, bf, acc[i], 0, 0, 0);
      }
    }
    int o = wave * 16 + fm;
    float bias = Bu1[n * 64 + o];
#pragma unroll
    for (int i = 0; i < 2; ++i)
#pragma unroll
      for (int r = 0; r < 4; ++r) {
        int b = i * 16 + fg * 4 + r;
        float x = acc[i][r] + bias;
        x = fminf(fmaxf(x, -15.f), 15.f);
        float e = __expf(2.f * x);
        float hc = (e - 1.f) / (e + 1.f);
        size_t base = (size_t)n * 2048 + b * 64;
        float rr = r1[base + o];
        float hnew = rr * h2_32[base + o] + (1.f - rr) * hc;
        h2_32[base + o] = hnew;
        h2_16[base + o] = __float2half(hnew);
      }
  }
  if (!do_gate0) return;
  __syncthreads();   // all Xs reads of phase 1 done before re-staging
  // ---- phase 2: gate0 at t+1 (node-local inputs already final) ----
  gate0_body(Xs, n, t, h1_16, YB, src, Axt, tnext, WtG0, Bg0, h1_32, zh0, r0);
}

// ---------------- out[b,o,n] = h2[n,b,:] . conv_w[o,:] + conv_b[o] ----------------
__global__ void final_conv_kernel(const float* __restrict__ h2, const float* __restrict__ cw,
                                  const float* __restrict__ cb, float* __restrict__ out) {
  int tid = blockIdx.x * 256 + threadIdx.x;
  if (tid >= 32 * 1024) return;
  int n = tid & 1023, b = tid >> 10;
  const float* hp = h2 + ((size_t)n * 32 + b) * 64;
  float hv[64];
#pragma unroll
  for (int i = 0; i < 64; ++i) hv[i] = hp[i];
#pragma unroll
  for (int o = 0; o < 12; ++o) {
    float acc = cb[o];
#pragma unroll
    for (int i = 0; i < 64; ++i) acc += hv[i] * cw[o * 64 + i];
    out[((size_t)b * 12 + o) * 1024 + n] = acc;
  }
}

extern "C" void kernel_launch(void* const* d_in, const int* in_sizes, int n_in,
                              void* d_out, int out_size, void* d_ws, size_t ws_size,
                              hipStream_t stream) {
  const float* src = (const float*)d_in[0];
  const float* E   = (const float*)d_in[1];
  const float* gw0 = (const float*)d_in[2];
  const float* gb0 = (const float*)d_in[3];
  const float* uw0 = (const float*)d_in[4];
  const float* ub0 = (const float*)d_in[5];
  const float* gw1 = (const float*)d_in[6];
  const float* gb1 = (const float*)d_in[7];
  const float* uw1 = (const float*)d_in[8];
  const float* ub1 = (const float*)d_in[9];
  const float* cw  = (const float*)d_in[10];
  const float* cb  = (const float*)d_in[11];
  float* out = (float*)d_out;
  (void)in_sizes; (void)n_in; (void)out_size; (void)ws_size;

  char* base = (char*)d_ws;
  size_t off = 0;
  auto alloc = [&](size_t bytes) -> void* {
    void* p = base + off; off += (bytes + 511) & ~(size_t)511; return p;
  };
  __half* Ah   = (__half*)alloc((size_t)1024 * 1024 * 2);           //   2.1 MB
  __half* WtG0 = (__half*)alloc((size_t)1024 * 128 * 160 * 2);      //  41.9 MB
  __half* WtU0 = (__half*)alloc((size_t)1024 * 64 * 160 * 2);       //  21.0 MB
  __half* WtG1 = (__half*)alloc((size_t)1024 * 128 * 256 * 2);      //  67.1 MB
  __half* WtU1 = (__half*)alloc((size_t)1024 * 64 * 256 * 2);       //  33.6 MB
  float*  Bg0  = (float*) alloc((size_t)1024 * 128 * 4);
  float*  Bu0  = (float*) alloc((size_t)1024 * 64 * 4);
  float*  Bg1  = (float*) alloc((size_t)1024 * 128 * 4);
  float*  Bu1  = (float*) alloc((size_t)1024 * 64 * 4);
  // zero-initialized region (contiguous): h1_32, h2_32, h1_16, h2_16, YB
  float*  h1_32 = (float*)alloc((size_t)1024 * 2048 * 4);           //   8.4 MB
  float*  h2_32 = (float*)alloc((size_t)1024 * 2048 * 4);           //   8.4 MB
  __half* h1_16 = (__half*)alloc((size_t)1024 * 2048 * 2);          //   4.2 MB
  __half* h2_16 = (__half*)alloc((size_t)1024 * 2048 * 2);          //   4.2 MB
  __half* YB   = (__half*)alloc((size_t)1024 * 2048 * 2);           //   4.2 MB (A@h1)
  __half* zh0  = (__half*)alloc((size_t)1024 * 2048 * 2);           //   4.2 MB
  __half* zh1  = (__half*)alloc((size_t)1024 * 2048 * 2);           //   4.2 MB
  __half* YA2  = (__half*)alloc((size_t)1024 * 4096 * 2);           //   8.4 MB ([A@zh0 | A@h2])
  __half* YC   = (__half*)alloc((size_t)1024 * 2048 * 2);           //   4.2 MB (A@zh1)
  __half* Axt  = (__half*)alloc((size_t)1024 * 768 * 2);            //   1.5 MB (A@x all t)
  float*  r1   = (float*) alloc((size_t)1024 * 2048 * 4);           //   8.4 MB
  float*  r0   = (float*) alloc((size_t)1024 * 2048 * 4);           //   8.4 MB (+ prelude scratch)
  // prelude-only overlays on r0: poolT16 (5.1 MB) + E16 (64 KB) + x16 (1.5 MB)
  __half* poolT16 = (__half*)r0;
  __half* E16  = poolT16 + (size_t)79872 * 32;
  __half* x16  = E16 + (size_t)1024 * 32;
  // total ~234 MB

  // ---- prelude (9 dispatches incl. gate0(0)) ----
  compute_A_kernel<<<1024, 256, 0, stream>>>(E, Ah);
  build_e16_kernel<<<(1024 * 32 + 255) / 256, 256, 0, stream>>>(E, E16);
  pool_t16_kernel<<<(79872 * 32 + 255) / 256, 256, 0, stream>>>(gw0, uw0, gw1, uw1, poolT16);
  make_wt_mfma_kernel<<<dim3(312, 16), 256, 0, stream>>>(E16, poolT16, WtG0, WtU0, WtG1, WtU1);
  make_b_all_kernel<<<(1024 * 384 + 255) / 256, 256, 0, stream>>>(E, gb0, ub0, gb1, ub1,
                                                                  Bg0, Bu0, Bg1, Bu1);
  build_x16_kernel<<<384, 256, 0, stream>>>(src, x16);
  gemm_nt_kernel<<<dim3(12, 16), 256, 0, stream>>>(Ah, (__half*)x16, (__half*)x16, Axt,
                                                   768, 768, 768);
  // zero h1_32,h2_32,h1_16,h2_16,YB (contiguous, 7340032 float-units)
  zero_kernel<<<(7340032 + 255) / 256, 256, 0, stream>>>(h1_32, 7340032);
  gate0_kernel<<<1024, 256, 0, stream>>>(h1_16, YB, src, Axt, 0, WtG0, Bg0, h1_32, zh0, r0);

  // ---- 12 GRU steps (6 dispatches each; gate0 of step t+1 fused into upd1 of step t) ----
  for (int t = 0; t < 12; ++t) {
    gemm_nt128_kernel<<<dim3(32, 16), 256, 0, stream>>>(Ah, zh0, h2_16, YA2, 4096, 2048, 2048);
    upd0_kernel<<<1024, 256, 0, stream>>>(zh0, YA2, src, Axt, t, WtU0, Bu0, r0, h1_32, h1_16);
    gemm_nt_kernel<<<dim3(32, 16), 256, 0, stream>>>(Ah, h1_16, h1_16, YB, 2048, 2048, 2048);
    gate1_kernel<<<1024, 256, 0, stream>>>(h1_16, h2_16, YB, YA2, WtG1, Bg1, h2_32, zh1, r1);
    gemm_nt_kernel<<<dim3(32, 16), 256, 0, stream>>>(Ah, zh1, zh1, YC, 2048, 2048, 2048);
    upd1_gate0_kernel<<<1024, 256, 0, stream>>>(h1_16, zh1, YB, YC, WtU1, Bu1, r1, h2_32, h2_16,
                                                src, Axt, t + 1, WtG0, Bg0, h1_32, zh0, r0,
                                                (t < 11) ? 1 : 0);
  }

  final_conv_kernel<<<(32 * 1024 + 255) / 256, 256, 0, stream>>>(h2_32, cw, cb, out);
}

// Round 10
// 1398.487 us; speedup vs baseline: 4.8201x; 1.0340x over previous
//
#include <hip/hip_runtime.h>
#include <hip/hip_fp16.h>

// AGCRN: B=32 T=12 N=1024 C=2 D=16 H=64 K=2 OUT=12
// Node-major activations [n][(b,f)], fp16 on GEMM paths; h fp32 master + fp16 mirror.
// Cross-layer software pipeline: per loop iter t handles layer1(t) + layer0(t+1):
//   G1: A@[h1(t)|h2(t-1)] -> YBD     F1: gate1(t)+gate0(t+1)
//   G2: A@[zh1(t)|zh0(t+1)] -> YCE   F2: upd1(t)+upd0(t+1)
// All per-output accumulation orders identical to round 9 -> bitwise-identical results.

typedef _Float16 f16x8 __attribute__((ext_vector_type(8)));
typedef _Float16 f16x4 __attribute__((ext_vector_type(4)));
typedef float f32x4 __attribute__((ext_vector_type(4)));

// ---------------- A = softmax(relu(E E^T)) -> fp16 ----------------
__global__ __launch_bounds__(256) void compute_A_kernel(const float* __restrict__ E,
                                                        __half* __restrict__ Ah) {
  int n = blockIdx.x;
  int tid = threadIdx.x;
  __shared__ float red[256];
  float en[16];
#pragma unroll
  for (int d = 0; d < 16; ++d) en[d] = E[n * 16 + d];
  float v[4];
#pragma unroll
  for (int q = 0; q < 4; ++q) {
    int m = tid + q * 256;
    const float* Em = E + m * 16;
    float dot = 0.f;
#pragma unroll
    for (int d = 0; d < 16; ++d) dot += en[d] * Em[d];
    v[q] = fmaxf(dot, 0.f);
  }
  float mx = fmaxf(fmaxf(v[0], v[1]), fmaxf(v[2], v[3]));
  red[tid] = mx; __syncthreads();
  for (int s = 128; s > 0; s >>= 1) { if (tid < s) red[tid] = fmaxf(red[tid], red[tid + s]); __syncthreads(); }
  mx = red[0];
  __syncthreads();
  float e[4], sum = 0.f;
#pragma unroll
  for (int q = 0; q < 4; ++q) { e[q] = expf(v[q] - mx); sum += e[q]; }
  red[tid] = sum; __syncthreads();
  for (int s = 128; s > 0; s >>= 1) { if (tid < s) red[tid] += red[tid + s]; __syncthreads(); }
  float inv = 1.f / red[0];
#pragma unroll
  for (int q = 0; q < 4; ++q) Ah[(size_t)n * 1024 + tid + q * 256] = __float2half(e[q] * inv);
}

// ---------------- E16[n][d] fp16, d padded 16->32 with zeros ----------------
__global__ void build_e16_kernel(const float* __restrict__ E, __half* __restrict__ E16) {
  int t = blockIdx.x * 256 + threadIdx.x;
  if (t >= 1024 * 32) return;
  int d = t & 31;
  E16[t] = (d < 16) ? __float2half(E[(t >> 5) * 16 + d]) : __half(0);
}

// ---------------- poolT16[j][d]: K-contiguous fp16 pool, j = (seg, o, kip) ----------------
__global__ void pool_t16_kernel(const float* __restrict__ gw0, const float* __restrict__ uw0,
                                const float* __restrict__ gw1, const float* __restrict__ uw1,
                                __half* __restrict__ poolT16) {
  int t = blockIdx.x * 256 + threadIdx.x;
  if (t >= 79872 * 32) return;
  int d = t & 31, j = t >> 5;
  if (d >= 16) { poolT16[t] = __half(0); return; }
  const float* pool; int F, Fp, O, loc;
  if (j < 20480)      { pool = gw0; F = 66;  Fp = 80;  O = 128; loc = j; }
  else if (j < 30720) { pool = uw0; F = 66;  Fp = 80;  O = 64;  loc = j - 20480; }
  else if (j < 63488) { pool = gw1; F = 128; Fp = 128; O = 128; loc = j - 30720; }
  else                { pool = uw1; F = 128; Fp = 128; O = 64;  loc = j - 63488; }
  int KIp = 2 * Fp;
  int o = loc / KIp, kip = loc - o * KIp;
  int kk = (kip >= Fp) ? 1 : 0;
  int jj = kip - kk * Fp;
  int i;
  if (F == Fp) i = jj;
  else i = (jj < 64) ? jj + 2 : (jj < 66 ? jj - 64 : -1);
  poolT16[t] = (i >= 0) ? __float2half(pool[(((size_t)d * 2 + kk) * F + i) * O + o]) : __half(0);
}

// ---------------- Wt via MFMA: Wt[n][j] = sum_d E16[n,d] * poolT16[j,d] ----------------
__global__ __launch_bounds__(256) void make_wt_mfma_kernel(
    const __half* __restrict__ E16g, const __half* __restrict__ poolT16g,
    __half* __restrict__ WtG0, __half* __restrict__ WtU0,
    __half* __restrict__ WtG1, __half* __restrict__ WtU1) {
  __shared__ __align__(16) _Float16 Es[64][40];
  __shared__ __align__(16) _Float16 wbuf[64][264];
  const _Float16* E16 = (const _Float16*)E16g;
  const _Float16* pT = (const _Float16*)poolT16g;
  int bx = blockIdx.x;
  __half* Wt; int OK, jbase;
  if (bx < 80)       { Wt = WtG0; OK = 128 * 160; jbase = bx * 256; }
  else if (bx < 120) { Wt = WtU0; OK = 64 * 160;  jbase = (bx - 80) * 256; }
  else if (bx < 248) { Wt = WtG1; OK = 128 * 256; jbase = (bx - 120) * 256; }
  else               { Wt = WtU1; OK = 64 * 256;  jbase = (bx - 248) * 256; }
  int jglob0 = bx * 256;
  int n0 = blockIdx.y * 64;
  {
    int r = threadIdx.x >> 2, ch = (threadIdx.x & 3) * 8;
    *(f16x8*)&Es[r][ch] = *(const f16x8*)(E16 + (size_t)(n0 + r) * 32 + ch);
  }
  __syncthreads();
  int wave = threadIdx.x >> 6, lane = threadIdx.x & 63;
  int fm = lane & 15, fg = lane >> 4;
  f16x8 af[4];
#pragma unroll
  for (int i = 0; i < 4; ++i) af[i] = *(const f16x8*)&Es[i * 16 + fm][fg * 8];
  f32x4 acc[4][4] = {};
#pragma unroll
  for (int j = 0; j < 4; ++j) {
    int jc = jglob0 + wave * 64 + j * 16 + fm;
    f16x8 bf = *(const f16x8*)(pT + (size_t)jc * 32 + fg * 8);
#pragma unroll
    for (int i = 0; i < 4; ++i)
      acc[i][j] = __builtin_amdgcn_mfma_f32_16x16x32_f16(af[i], bf, acc[i][j], 0, 0, 0);
  }
#pragma unroll
  for (int i = 0; i < 4; ++i)
#pragma unroll
    for (int j = 0; j < 4; ++j)
#pragma unroll
      for (int r = 0; r < 4; ++r)
        wbuf[i * 16 + fg * 4 + r][wave * 64 + j * 16 + fm] = (_Float16)acc[i][j][r];
  __syncthreads();
  for (int idx = threadIdx.x; idx < 64 * 32; idx += 256) {
    int nsub = idx >> 5, pos = (idx & 31) * 8;
    *(float4*)(Wt + (size_t)(n0 + nsub) * OK + jbase + pos) = *(float4*)&wbuf[nsub][pos];
  }
}

// ---------------- merged per-node biases ----------------
__global__ void make_b_all_kernel(const float* __restrict__ E,
                                  const float* __restrict__ gb0, const float* __restrict__ ub0,
                                  const float* __restrict__ gb1, const float* __restrict__ ub1,
                                  float* __restrict__ Bg0, float* __restrict__ Bu0,
                                  float* __restrict__ Bg1, float* __restrict__ Bu1) {
  int tid = blockIdx.x * 256 + threadIdx.x;
  if (tid >= 1024 * 384) return;
  int n = tid / 384, c = tid - n * 384;
  const float* pool; float* outp; int O, o;
  if (c < 128)      { pool = gb0; outp = Bg0; O = 128; o = c; }
  else if (c < 192) { pool = ub0; outp = Bu0; O = 64;  o = c - 128; }
  else if (c < 320) { pool = gb1; outp = Bg1; O = 128; o = c - 192; }
  else              { pool = ub1; outp = Bu1; O = 64;  o = c - 320; }
  const float* En = E + n * 16;
  float a = 0.f;
#pragma unroll
  for (int d = 0; d < 16; ++d) a += En[d] * pool[d * O + o];
  outp[n * O + o] = a;
}

__global__ void zero_kernel(float* __restrict__ p, int count) {
  int i = blockIdx.x * 256 + threadIdx.x;
  if (i < count) p[i] = 0.f;
}

// ---------------- x16[n][t*64+b*2+cc] = src[b][t][n][cc], fp16 node-major ----------------
__global__ void build_x16_kernel(const float* __restrict__ src, __half* __restrict__ x16) {
  int bid = blockIdx.x; int t = bid >> 5, b = bid & 31;
  const float* s = src + (size_t)(b * 12 + t) * 2048;
  __half* dst = x16 + t * 64 + b * 2;
  for (int n = threadIdx.x; n < 1024; n += 256) {
    float2 v = *(const float2*)(s + n * 2);
    *(__half2*)(dst + (size_t)n * 768) = __floats2half2_rn(v.x, v.y);
  }
}

// ---------------- gemm_nt: Y[1024 x Nc] = Ah @ X (64x64 tile, K=128/stage) — prelude Axt ----
__global__ __launch_bounds__(256) void gemm_nt_kernel(
    const __half* __restrict__ Ahg, const __half* __restrict__ X0g,
    const __half* __restrict__ X1g, __half* __restrict__ Yg,
    int Nc, int cstride, int split) {
  __shared__ __align__(16) _Float16 As[64][136];
  __shared__ __align__(16) _Float16 Bs[64][144];
  const _Float16* __restrict__ Ah = (const _Float16*)Ahg;
  _Float16* __restrict__ Y = (_Float16*)Yg;
  int tid = threadIdx.x;
  int row0 = blockIdx.y * 64;
  int col0 = blockIdx.x * 64;
  const _Float16* __restrict__ Xsrc =
      (col0 < split) ? (const _Float16*)X0g : (const _Float16*)X1g;
  int colg = (col0 < split) ? col0 : col0 - split;
  int wave = tid >> 6, lane = tid & 63;
  int wm = wave & 1, wn = wave >> 1;
  int fm = lane & 15, fg = lane >> 4;

  int sr = tid >> 2, sc = (tid & 3) * 32;
  const _Float16* pa = Ah + (size_t)(row0 + sr) * 1024 + sc;
  int kq = tid & 31, cg = tid >> 5;
  int kb = 4 * kq;
  const _Float16* pb = Xsrc + (size_t)kb * cstride + colg + cg * 8;
  int chunk = kq >> 1;
  int kin = (kq & 1) * 4;

  f16x8 ra[4], rb[4];
#pragma unroll
  for (int c = 0; c < 4; ++c) ra[c] = *(const f16x8*)(pa + c * 8);
#pragma unroll
  for (int r = 0; r < 4; ++r) rb[r] = *(const f16x8*)(pb + (size_t)r * cstride);

  f32x4 acc[2][2] = {};
  for (int k0 = 0; k0 < 1024; k0 += 128) {
#pragma unroll
    for (int c = 0; c < 4; ++c) *(f16x8*)&As[sr][sc + c * 8] = ra[c];
#pragma unroll
    for (int i = 0; i < 8; ++i) {
      int c = cg * 8 + i;
      f16x4 p;
      p[0] = rb[0][i]; p[1] = rb[1][i]; p[2] = rb[2][i]; p[3] = rb[3][i];
      *(f16x4*)&Bs[c][((chunk ^ (c & 7)) << 3) + kin] = p;
    }
    __syncthreads();
    if (k0 + 128 < 1024) {
#pragma unroll
      for (int c = 0; c < 4; ++c) ra[c] = *(const f16x8*)(pa + k0 + 128 + c * 8);
#pragma unroll
      for (int r = 0; r < 4; ++r)
        rb[r] = *(const f16x8*)(pb + (size_t)(k0 + 128 + r) * cstride);
    }
#pragma unroll
    for (int kc = 0; kc < 4; ++kc) {
      int ck = kc * 4 + fg;
      f16x8 af[2], bf[2];
#pragma unroll
      for (int i = 0; i < 2; ++i)
        af[i] = *(const f16x8*)&As[wm * 32 + i * 16 + fm][kc * 32 + fg * 8];
#pragma unroll
      for (int j = 0; j < 2; ++j) {
        int cl = wn * 32 + j * 16 + fm;
        bf[j] = *(const f16x8*)&Bs[cl][(ck ^ (cl & 7)) << 3];
      }
#pragma unroll
      for (int i = 0; i < 2; ++i)
#pragma unroll
        for (int j = 0; j < 2; ++j)
          acc[i][j] = __builtin_amdgcn_mfma_f32_16x16x32_f16(af[i], bf[j], acc[i][j], 0, 0, 0);
    }
    __syncthreads();
  }
#pragma unroll
  for (int i = 0; i < 2; ++i) {
#pragma unroll
    for (int j = 0; j < 2; ++j) {
      int col = col0 + wn * 32 + j * 16 + fm;
      int rbase = row0 + wm * 32 + i * 16 + fg * 4;
#pragma unroll
      for (int r = 0; r < 4; ++r)
        Y[(size_t)(rbase + r) * Nc + col] = (_Float16)acc[i][j][r];
    }
  }
}

// ---------------- gemm_nt128: Y = Ah @ X, 64(M) x 128(N) tile, K=128/stage ----------------
__global__ __launch_bounds__(256) void gemm_nt128_kernel(
    const __half* __restrict__ Ahg, const __half* __restrict__ X0g,
    const __half* __restrict__ X1g, __half* __restrict__ Yg,
    int Nc, int cstride, int split) {
  __shared__ __align__(16) _Float16 As[64][136];
  __shared__ __align__(16) _Float16 Bs[128][144];
  const _Float16* __restrict__ Ah = (const _Float16*)Ahg;
  _Float16* __restrict__ Y = (_Float16*)Yg;
  int tid = threadIdx.x;
  int row0 = blockIdx.y * 64;
  int col0 = blockIdx.x * 128;
  const _Float16* __restrict__ Xsrc =
      (col0 < split) ? (const _Float16*)X0g : (const _Float16*)X1g;
  int colg = (col0 < split) ? col0 : col0 - split;
  int wave = tid >> 6, lane = tid & 63;
  int fm = lane & 15, fg = lane >> 4;

  int sr = tid >> 2, sc = (tid & 3) * 32;
  const _Float16* pa = Ah + (size_t)(row0 + sr) * 1024 + sc;
  int kq = tid & 31, cg = tid >> 5;
  int kb = 4 * kq;
  const _Float16* pb = Xsrc + (size_t)kb * cstride + colg + cg * 16;
  int chunk = kq >> 1;
  int kin = (kq & 1) * 4;

  f16x8 ra[4], rb[4][2];
#pragma unroll
  for (int c = 0; c < 4; ++c) ra[c] = *(const f16x8*)(pa + c * 8);
#pragma unroll
  for (int r = 0; r < 4; ++r)
#pragma unroll
    for (int h = 0; h < 2; ++h)
      rb[r][h] = *(const f16x8*)(pb + (size_t)r * cstride + h * 8);

  f32x4 acc[4][2] = {};
  for (int k0 = 0; k0 < 1024; k0 += 128) {
#pragma unroll
    for (int c = 0; c < 4; ++c) *(f16x8*)&As[sr][sc + c * 8] = ra[c];
#pragma unroll
    for (int h = 0; h < 2; ++h)
#pragma unroll
      for (int i = 0; i < 8; ++i) {
        int c = cg * 16 + h * 8 + i;
        f16x4 p;
        p[0] = rb[0][h][i]; p[1] = rb[1][h][i]; p[2] = rb[2][h][i]; p[3] = rb[3][h][i];
        *(f16x4*)&Bs[c][((chunk ^ (c & 7)) << 3) + kin] = p;
      }
    __syncthreads();
    if (k0 + 128 < 1024) {
#pragma unroll
      for (int c = 0; c < 4; ++c) ra[c] = *(const f16x8*)(pa + k0 + 128 + c * 8);
#pragma unroll
      for (int r = 0; r < 4; ++r)
#pragma unroll
        for (int h = 0; h < 2; ++h)
          rb[r][h] = *(const f16x8*)(pb + (size_t)(k0 + 128 + r) * cstride + h * 8);
    }
#pragma unroll
    for (int kc = 0; kc < 4; ++kc) {
      int ck = kc * 4 + fg;
      f16x8 af[4], bf[2];
#pragma unroll
      for (int i = 0; i < 4; ++i)
        af[i] = *(const f16x8*)&As[i * 16 + fm][kc * 32 + fg * 8];
#pragma unroll
      for (int j = 0; j < 2; ++j) {
        int cl = wave * 32 + j * 16 + fm;
        bf[j] = *(const f16x8*)&Bs[cl][(ck ^ (cl & 7)) << 3];
      }
#pragma unroll
      for (int i = 0; i < 4; ++i)
#pragma unroll
        for (int j = 0; j < 2; ++j)
          acc[i][j] = __builtin_amdgcn_mfma_f32_16x16x32_f16(af[i], bf[j], acc[i][j], 0, 0, 0);
    }
    __syncthreads();
  }
#pragma unroll
  for (int i = 0; i < 4; ++i) {
#pragma unroll
    for (int j = 0; j < 2; ++j) {
      int col = col0 + wave * 32 + j * 16 + fm;
      int rbase = row0 + i * 16 + fg * 4;
#pragma unroll
      for (int r = 0; r < 4; ++r)
        Y[(size_t)(rbase + r) * Nc + col] = (_Float16)acc[i][j][r];
    }
  }
}

// ---------------- gate0 body: zr=sigmoid([h1|x|Ah1|Ax]@WtG0+Bg0); zh0=z*h1; r0 ----------------
// YBD row stride 4096 (A@h1 = cols 0..2047).
__device__ __forceinline__ void gate0_body(
    _Float16* Xs, int n, int t,
    const __half* __restrict__ h16, const __half* __restrict__ YBD,
    const float* __restrict__ src, const __half* __restrict__ Axt, int tstep,
    const __half* __restrict__ Wtg, const float* __restrict__ Bg,
    const float* __restrict__ h32, __half* __restrict__ zh0, float* __restrict__ r0) {
  constexpr int KIP = 160, STRIDE = 168;
#pragma unroll
  for (int u = 0; u < 2; ++u) {
    int idx = t + u * 256;
    int b = idx >> 4, part = (idx >> 3) & 1, ch = idx & 7;
    const _Float16* s = part ? (const _Float16*)YBD + (size_t)n * 4096 + b * 64 + ch * 8
                             : (const _Float16*)h16 + (size_t)n * 2048 + b * 64 + ch * 8;
    *(f16x8*)&Xs[b * STRIDE + part * 80 + ch * 8] = *(const f16x8*)s;
  }
  if (t < 32) {
    int b = t;
    float2 xv = *(const float2*)(src + ((size_t)(b * 12 + tstep) * 1024 + n) * 2);
    Xs[b * STRIDE + 64] = (_Float16)xv.x;
    Xs[b * STRIDE + 65] = (_Float16)xv.y;
    const _Float16* ax = (const _Float16*)Axt + (size_t)n * 768 + tstep * 64 + b * 2;
    Xs[b * STRIDE + 144] = ax[0];
    Xs[b * STRIDE + 145] = ax[1];
  }
  for (int idx = t; idx < 896; idx += 256) {
    int b = idx / 28, jj = idx % 28;
    int col = (jj < 14) ? 66 + jj : 132 + jj;
    Xs[b * STRIDE + col] = (_Float16)0.f;
  }
  __syncthreads();
  int wave = t >> 6, lane = t & 63;
  int fm = lane & 15, fg = lane >> 4;
  f32x4 acc[2][2] = {};
  const _Float16* Wn = (const _Float16*)Wtg + ((size_t)n * 128 + wave * 32) * KIP;
#pragma unroll
  for (int kc = 0; kc < KIP / 32; ++kc) {
    f16x8 af[2], bf[2];
#pragma unroll
    for (int i = 0; i < 2; ++i)
      af[i] = *(const f16x8*)&Xs[(i * 16 + fm) * STRIDE + kc * 32 + fg * 8];
#pragma unroll
    for (int j = 0; j < 2; ++j)
      bf[j] = *(const f16x8*)(Wn + (size_t)(j * 16 + fm) * KIP + kc * 32 + fg * 8);
#pragma unroll
    for (int i = 0; i < 2; ++i)
#pragma unroll
      for (int j = 0; j < 2; ++j)
        acc[i][j] = __builtin_amdgcn_mfma_f32_16x16x32_f16(af[i], bf[j], acc[i][j], 0, 0, 0);
  }
  const float* Bn = Bg + n * 128;
#pragma unroll
  for (int j = 0; j < 2; ++j) {
    int o = wave * 32 + j * 16 + fm;
    float bias = Bn[o];
#pragma unroll
    for (int i = 0; i < 2; ++i)
#pragma unroll
      for (int r = 0; r < 4; ++r) {
        int b = i * 16 + fg * 4 + r;
        float s = 1.f / (1.f + __expf(-(acc[i][j][r] + bias)));
        size_t base = (size_t)n * 2048 + b * 64;
        if (o < 64) zh0[base + o] = __float2half(s * h32[base + o]);
        else        r0[base + o - 64] = s;
      }
  }
}

// ---------------- upd0 body: hc=tanh([zh0|x|Azh0|Ax]@WtU0+Bu0); h1 = r0*h1+(1-r0)*hc --------
// A@zh0 lives in YCE cols 2048..4095 (row stride 4096).
__device__ __forceinline__ void upd0_body(
    _Float16* Xs, int n, int t,
    const __half* __restrict__ zh0, const __half* __restrict__ YCE,
    const float* __restrict__ src, const __half* __restrict__ Axt, int tstep,
    const __half* __restrict__ Wtg, const float* __restrict__ Bu,
    const float* __restrict__ r0, float* __restrict__ h32, __half* __restrict__ h16) {
  constexpr int KIP = 160, STRIDE = 168;
#pragma unroll
  for (int u = 0; u < 2; ++u) {
    int idx = t + u * 256;
    int b = idx >> 4, part = (idx >> 3) & 1, ch = idx & 7;
    const _Float16* s = part ? (const _Float16*)YCE + (size_t)n * 4096 + 2048 + b * 64 + ch * 8
                             : (const _Float16*)zh0 + (size_t)n * 2048 + b * 64 + ch * 8;
    *(f16x8*)&Xs[b * STRIDE + part * 80 + ch * 8] = *(const f16x8*)s;
  }
  if (t < 32) {
    int b = t;
    float2 xv = *(const float2*)(src + ((size_t)(b * 12 + tstep) * 1024 + n) * 2);
    Xs[b * STRIDE + 64] = (_Float16)xv.x;
    Xs[b * STRIDE + 65] = (_Float16)xv.y;
    const _Float16* ax = (const _Float16*)Axt + (size_t)n * 768 + tstep * 64 + b * 2;
    Xs[b * STRIDE + 144] = ax[0];
    Xs[b * STRIDE + 145] = ax[1];
  }
  for (int idx = t; idx < 896; idx += 256) {
    int b = idx / 28, jj = idx % 28;
    int col = (jj < 14) ? 66 + jj : 132 + jj;
    Xs[b * STRIDE + col] = (_Float16)0.f;
  }
  __syncthreads();
  int wave = t >> 6, lane = t & 63;
  int fm = lane & 15, fg = lane >> 4;
  f32x4 acc[2] = {};
  const _Float16* Wn = (const _Float16*)Wtg + ((size_t)n * 64 + wave * 16) * KIP;
#pragma unroll
  for (int kc = 0; kc < KIP / 32; ++kc) {
    f16x8 bf = *(const f16x8*)(Wn + (size_t)fm * KIP + kc * 32 + fg * 8);
#pragma unroll
    for (int i = 0; i < 2; ++i) {
      f16x8 af = *(const f16x8*)&Xs[(i * 16 + fm) * STRIDE + kc * 32 + fg * 8];
      acc[i] = __builtin_amdgcn_mfma_f32_16x16x32_f16(af, bf, acc[i], 0, 0, 0);
    }
  }
  int o = wave * 16 + fm;
  float bias = Bu[n * 64 + o];
#pragma unroll
  for (int i = 0; i < 2; ++i)
#pragma unroll
    for (int r = 0; r < 4; ++r) {
      int b = i * 16 + fg * 4 + r;
      float x = acc[i][r] + bias;
      x = fminf(fmaxf(x, -15.f), 15.f);
      float e = __expf(2.f * x);
      float hc = (e - 1.f) / (e + 1.f);
      size_t base = (size_t)n * 2048 + b * 64;
      float rr = r0[base + o];
      float hnew = rr * h32[base + o] + (1.f - rr) * hc;
      h32[base + o] = hnew;
      h16[base + o] = __float2half(hnew);
    }
}

// ---------------- standalone gate0 / upd0 (prologue) ----------------
__global__ __launch_bounds__(256) void gate0_kernel(
    const __half* __restrict__ h16, const __half* __restrict__ YBD,
    const float* __restrict__ src, const __half* __restrict__ Axt, int tstep,
    const __half* __restrict__ Wtg, const float* __restrict__ Bg,
    const float* __restrict__ h32, __half* __restrict__ zh0, float* __restrict__ r0) {
  __shared__ __align__(16) _Float16 Xs[32 * 168];
  gate0_body(Xs, blockIdx.x, threadIdx.x, h16, YBD, src, Axt, tstep, Wtg, Bg, h32, zh0, r0);
}

__global__ __launch_bounds__(256) void upd0_kernel(
    const __half* __restrict__ zh0, const __half* __restrict__ YCE,
    const float* __restrict__ src, const __half* __restrict__ Axt, int tstep,
    const __half* __restrict__ Wtg, const float* __restrict__ Bu,
    const float* __restrict__ r0, float* __restrict__ h32, __half* __restrict__ h16) {
  __shared__ __align__(16) _Float16 Xs[32 * 168];
  upd0_body(Xs, blockIdx.x, threadIdx.x, zh0, YCE, src, Axt, tstep, Wtg, Bu, r0, h32, h16);
}

// ---------------- F1: gate1(t) + gate0(t+1) ----------------
// gate1: zr = sigmoid([h1|h2 | Ah1|Ah2] @ WtG1 + Bg1); zh1 = z*h2; r1.  Ah1/Ah2 from YBD.
__global__ __launch_bounds__(256) void gate1_gate0_kernel(
    const __half* __restrict__ h1_16, const __half* __restrict__ h2_16,
    const __half* __restrict__ YBD,
    const __half* __restrict__ WtG1, const float* __restrict__ Bg1,
    const float* __restrict__ h2_32, __half* __restrict__ zh1, float* __restrict__ r1,
    const float* __restrict__ src, const __half* __restrict__ Axt, int tnext,
    const __half* __restrict__ WtG0, const float* __restrict__ Bg0,
    const float* __restrict__ h1_32, __half* __restrict__ zh0, float* __restrict__ r0,
    int do_gate0) {
  constexpr int KIP = 256, STRIDE = 264;
  __shared__ __align__(16) _Float16 Xs[32 * STRIDE];
  int n = blockIdx.x;
  int t = threadIdx.x;
  // phase 1: gate1(t)
#pragma unroll
  for (int u = 0; u < 4; ++u) {
    int idx = t + u * 256;
    int b = idx >> 5, q = idx & 31;
    const _Float16* s;
    if (q < 8)       s = (const _Float16*)h1_16 + (size_t)n * 2048 + b * 64 + q * 8;
    else if (q < 16) s = (const _Float16*)h2_16 + (size_t)n * 2048 + b * 64 + (q - 8) * 8;
    else if (q < 24) s = (const _Float16*)YBD + (size_t)n * 4096 + b * 64 + (q - 16) * 8;
    else             s = (const _Float16*)YBD + (size_t)n * 4096 + 2048 + b * 64 + (q - 24) * 8;
    *(f16x8*)&Xs[b * STRIDE + q * 8] = *(const f16x8*)s;
  }
  __syncthreads();
  int wave = t >> 6, lane = t & 63;
  int fm = lane & 15, fg = lane >> 4;
  {
    f32x4 acc[2][2] = {};
    const _Float16* Wn = (const _Float16*)WtG1 + ((size_t)n * 128 + wave * 32) * KIP;
#pragma unroll
    for (int kc = 0; kc < KIP / 32; ++kc) {
      f16x8 af[2], bf[2];
#pragma unroll
      for (int i = 0; i < 2; ++i)
        af[i] = *(const f16x8*)&Xs[(i * 16 + fm) * STRIDE + kc * 32 + fg * 8];
#pragma unroll
      for (int j = 0; j < 2; ++j)
        bf[j] = *(const f16x8*)(Wn + (size_t)(j * 16 + fm) * KIP + kc * 32 + fg * 8);
#pragma unroll
      for (int i = 0; i < 2; ++i)
#pragma unroll
        for (int j = 0; j < 2; ++j)
          acc[i][j] = __builtin_amdgcn_mfma_f32_16x16x32_f16(af[i], bf[j], acc[i][j], 0, 0, 0);
    }
    const float* Bn = Bg1 + n * 128;
#pragma unroll
    for (int j = 0; j < 2; ++j) {
      int o = wave * 32 + j * 16 + fm;
      float bias = Bn[o];
#pragma unroll
      for (int i = 0; i < 2; ++i)
#pragma unroll
        for (int r = 0; r < 4; ++r) {
          int b = i * 16 + fg * 4 + r;
          float s = 1.f / (1.f + __expf(-(acc[i][j][r] + bias)));
          size_t base = (size_t)n * 2048 + b * 64;
          if (o < 64) zh1[base + o] = __float2half(s * h2_32[base + o]);
          else        r1[base + o - 64] = s;
        }
    }
  }
  if (!do_gate0) return;
  __syncthreads();
  // phase 2: gate0(t+1) — node-local inputs (h1, YBD, x) already final
  gate0_body(Xs, n, t, h1_16, YBD, src, Axt, tnext, WtG0, Bg0, h1_32, zh0, r0);
}

// ---------------- F2: upd1(t) + upd0(t+1) ----------------
// upd1: hc = tanh([h1|zh1 | Ah1|Azh1] @ WtU1 + Bu1); h2 = r1*h2 + (1-r1)*hc.
__global__ __launch_bounds__(256) void upd1_upd0_kernel(
    const __half* __restrict__ h1_16, const __half* __restrict__ zh1,
    const __half* __restrict__ YBD, const __half* __restrict__ YCE,
    const __half* __restrict__ WtU1, const float* __restrict__ Bu1,
    const float* __restrict__ r1, float* __restrict__ h2_32, __half* __restrict__ h2_16,
    const __half* __restrict__ zh0,
    const float* __restrict__ src, const __half* __restrict__ Axt, int tnext,
    const __half* __restrict__ WtU0, const float* __restrict__ Bu0,
    const float* __restrict__ r0, float* __restrict__ h1_32, __half* __restrict__ h1_16w,
    int do_upd0) {
  constexpr int KIP = 256, STRIDE = 264;
  __shared__ __align__(16) _Float16 Xs[32 * STRIDE];
  int n = blockIdx.x;
  int t = threadIdx.x;
  // phase 1: upd1(t)
#pragma unroll
  for (int u = 0; u < 4; ++u) {
    int idx = t + u * 256;
    int b = idx >> 5, q = idx & 31;
    const _Float16* s;
    if (q < 8)       s = (const _Float16*)h1_16 + (size_t)n * 2048 + b * 64 + q * 8;
    else if (q < 16) s = (const _Float16*)zh1 + (size_t)n * 2048 + b * 64 + (q - 8) * 8;
    else if (q < 24) s = (const _Float16*)YBD + (size_t)n * 4096 + b * 64 + (q - 16) * 8;
    else             s = (const _Float16*)YCE + (size_t)n * 4096 + b * 64 + (q - 24) * 8;
    *(f16x8*)&Xs[b * STRIDE + q * 8] = *(const f16x8*)s;
  }
  __syncthreads();
  int wave = t >> 6, lane = t & 63;
  int fm = lane & 15, fg = lane >> 4;
  {
    f32x4 acc[2] = {};
    const _Float16* Wn = (const _Float16*)WtU1 + ((size_t)n * 64 + wave * 16) * KIP;
#pragma unroll
    for (int kc = 0; kc < KIP / 32; ++kc) {
      f16x8 bf = *(const f16x8*)(Wn + (size_t)fm * KIP + kc * 32 + fg * 8);
#pragma unroll
      for (int i = 0; i < 2; ++i) {
        f16x8 af = *(const f16x8*)&Xs[(i * 16 + fm) * STRIDE + kc * 32 + fg * 8];
        acc[i] = __builtin_amdgcn_mfma_f32_16x16x32_f16(af, bf, acc[i], 0, 0, 0);
      }
    }
    int o = wave * 16 + fm;
    float bias = Bu1[n * 64 + o];
#pragma unroll
    for (int i = 0; i < 2; ++i)
#pragma unroll
      for (int r = 0; r < 4; ++r) {
        int b = i * 16 + fg * 4 + r;
        float x = acc[i][r] + bias;
        x = fminf(fmaxf(x, -15.f), 15.f);
        float e = __expf(2.f * x);
        float hc = (e - 1.f) / (e + 1.f);
        size_t base = (size_t)n * 2048 + b * 64;
        float rr = r1[base + o];
        float hnew = rr * h2_32[base + o] + (1.f - rr) * hc;
        h2_32[base + o] = hnew;
        h2_16[base + o] = __float2half(hnew);
      }
  }
  if (!do_upd0) return;
  __syncthreads();
  // phase 2: upd0(t+1) — reads zh0(t+1), YCE(A@zh0), x(t+1); writes h1 (node-local)
  upd0_body(Xs, n, t, zh0, YCE, src, Axt, tnext, WtU0, Bu0, r0, h1_32, h1_16w);
}

// ---------------- out[b,o,n] = h2[n,b,:] . conv_w[o,:] + conv_b[o] ----------------
__global__ void final_conv_kernel(const float* __restrict__ h2, const float* __restrict__ cw,
                                  const float* __restrict__ cb, float* __restrict__ out) {
  int tid = blockIdx.x * 256 + threadIdx.x;
  if (tid >= 32 * 1024) return;
  int n = tid & 1023, b = tid >> 10;
  const float* hp = h2 + ((size_t)n * 32 + b) * 64;
  float hv[64];
#pragma unroll
  for (int i = 0; i < 64; ++i) hv[i] = hp[i];
#pragma unroll
  for (int o = 0; o < 12; ++o) {
    float acc = cb[o];
#pragma unroll
    for (int i = 0; i < 64; ++i) acc += hv[i] * cw[o * 64 + i];
    out[((size_t)b * 12 + o) * 1024 + n] = acc;
  }
}

extern "C" void kernel_launch(void* const* d_in, const int* in_sizes, int n_in,
                              void* d_out, int out_size, void* d_ws, size_t ws_size,
                              hipStream_t stream) {
  const float* src = (const float*)d_in[0];
  const float* E   = (const float*)d_in[1];
  const float* gw0 = (const float*)d_in[2];
  const float* gb0 = (const float*)d_in[3];
  const float* uw0 = (const float*)d_in[4];
  const float* ub0 = (const float*)d_in[5];
  const float* gw1 = (const float*)d_in[6];
  const float* gb1 = (const float*)d_in[7];
  const float* uw1 = (const float*)d_in[8];
  const float* ub1 = (const float*)d_in[9];
  const float* cw  = (const float*)d_in[10];
  const float* cb  = (const float*)d_in[11];
  float* out = (float*)d_out;
  (void)in_sizes; (void)n_in; (void)out_size; (void)ws_size;

  char* base = (char*)d_ws;
  size_t off = 0;
  auto alloc = [&](size_t bytes) -> void* {
    void* p = base + off; off += (bytes + 511) & ~(size_t)511; return p;
  };
  __half* Ah   = (__half*)alloc((size_t)1024 * 1024 * 2);           //   2.1 MB
  __half* WtG0 = (__half*)alloc((size_t)1024 * 128 * 160 * 2);      //  41.9 MB
  __half* WtU0 = (__half*)alloc((size_t)1024 * 64 * 160 * 2);       //  21.0 MB
  __half* WtG1 = (__half*)alloc((size_t)1024 * 128 * 256 * 2);      //  67.1 MB
  __half* WtU1 = (__half*)alloc((size_t)1024 * 64 * 256 * 2);       //  33.6 MB
  float*  Bg0  = (float*) alloc((size_t)1024 * 128 * 4);
  float*  Bu0  = (float*) alloc((size_t)1024 * 64 * 4);
  float*  Bg1  = (float*) alloc((size_t)1024 * 128 * 4);
  float*  Bu1  = (float*) alloc((size_t)1024 * 64 * 4);
  // zero-init region (contiguous): h1_32, h2_32, h1_16, h2_16, YBD  (8388608 floats)
  float*  h1_32 = (float*)alloc((size_t)1024 * 2048 * 4);           //   8.4 MB
  float*  h2_32 = (float*)alloc((size_t)1024 * 2048 * 4);           //   8.4 MB
  __half* h1_16 = (__half*)alloc((size_t)1024 * 2048 * 2);          //   4.2 MB
  __half* h2_16 = (__half*)alloc((size_t)1024 * 2048 * 2);          //   4.2 MB
  __half* YBD  = (__half*)alloc((size_t)1024 * 4096 * 2);           //   8.4 MB [A@h1 | A@h2]
  __half* YCE  = (__half*)alloc((size_t)1024 * 4096 * 2);           //   8.4 MB [A@zh1 | A@zh0]
  __half* zh0  = (__half*)alloc((size_t)1024 * 2048 * 2);           //   4.2 MB
  __half* zh1  = (__half*)alloc((size_t)1024 * 2048 * 2);           //   4.2 MB
  __half* Axt  = (__half*)alloc((size_t)1024 * 768 * 2);            //   1.5 MB (A@x all t)
  float*  r1   = (float*) alloc((size_t)1024 * 2048 * 4);           //   8.4 MB
  float*  r0   = (float*) alloc((size_t)1024 * 2048 * 4);           //   8.4 MB (+ prelude scratch)
  // prelude-only overlays on r0: poolT16 (5.1 MB) + E16 (64 KB) + x16 (1.5 MB)
  __half* poolT16 = (__half*)r0;
  __half* E16  = poolT16 + (size_t)79872 * 32;
  __half* x16  = E16 + (size_t)1024 * 32;
  // total ~235 MB

  // ---- prelude (8 dispatches) ----
  compute_A_kernel<<<1024, 256, 0, stream>>>(E, Ah);
  build_e16_kernel<<<(1024 * 32 + 255) / 256, 256, 0, stream>>>(E, E16);
  pool_t16_kernel<<<(79872 * 32 + 255) / 256, 256, 0, stream>>>(gw0, uw0, gw1, uw1, poolT16);
  make_wt_mfma_kernel<<<dim3(312, 16), 256, 0, stream>>>(E16, poolT16, WtG0, WtU0, WtG1, WtU1);
  make_b_all_kernel<<<(1024 * 384 + 255) / 256, 256, 0, stream>>>(E, gb0, ub0, gb1, ub1,
                                                                  Bg0, Bu0, Bg1, Bu1);
  build_x16_kernel<<<384, 256, 0, stream>>>(src, x16);
  gemm_nt_kernel<<<dim3(12, 16), 256, 0, stream>>>(Ah, (__half*)x16, (__half*)x16, Axt,
                                                   768, 768, 768);
  zero_kernel<<<(8388608 + 255) / 256, 256, 0, stream>>>(h1_32, 8388608);

  // ---- prologue: layer-0 step 0 ----
  gate0_kernel<<<1024, 256, 0, stream>>>(h1_16, YBD, src, Axt, 0, WtG0, Bg0, h1_32, zh0, r0);
  gemm_nt128_kernel<<<dim3(16, 16), 256, 0, stream>>>(Ah, zh0, zh0, YCE + 2048,
                                                      4096, 2048, 2048);  // YE = A@zh0(0)
  upd0_kernel<<<1024, 256, 0, stream>>>(zh0, YCE, src, Axt, 0, WtU0, Bu0, r0, h1_32, h1_16);

  // ---- 12 pipelined iterations (4 dispatches each) ----
  for (int t = 0; t < 12; ++t) {
    int more = (t < 11) ? 1 : 0;
    gemm_nt128_kernel<<<dim3(32, 16), 256, 0, stream>>>(Ah, h1_16, h2_16, YBD,
                                                        4096, 2048, 2048);   // G1
    gate1_gate0_kernel<<<1024, 256, 0, stream>>>(h1_16, h2_16, YBD, WtG1, Bg1, h2_32, zh1, r1,
                                                 src, Axt, t + 1, WtG0, Bg0, h1_32, zh0, r0,
                                                 more);                       // F1
    gemm_nt128_kernel<<<dim3(32, 16), 256, 0, stream>>>(Ah, zh1, zh0, YCE,
                                                        4096, 2048, 2048);   // G2
    upd1_upd0_kernel<<<1024, 256, 0, stream>>>(h1_16, zh1, YBD, YCE, WtU1, Bu1, r1,
                                               h2_32, h2_16, zh0, src, Axt, t + 1,
                                               WtU0, Bu0, r0, h1_32, h1_16, more);  // F2
  }

  final_conv_kernel<<<(32 * 1024 + 255) / 256, 256, 0, stream>>>(h2_32, cw, cb, out);
}